// Round 5
// baseline (390.166 us; speedup 1.0000x reference)
//
#include <hip/hip_runtime.h>

constexpr float EPS = 1e-5f;

#define NPB_LOG 9
#define NPB 512

typedef __attribute__((ext_vector_type(8))) __bf16 bf16x8;
typedef __attribute__((ext_vector_type(4))) float f32x4;

// ---------- bf16 helpers ----------
__device__ __forceinline__ float blo(unsigned u) { return __uint_as_float(u << 16); }
__device__ __forceinline__ float bhi(unsigned u) { return __uint_as_float(u & 0xffff0000u); }
__device__ __forceinline__ unsigned bf1(float f) {
    unsigned u = __float_as_uint(f);
    return (u + 0x7fffu + ((u >> 16) & 1u)) >> 16;
}
__device__ __forceinline__ unsigned pack2(float a, float b) { return bf1(a) | (bf1(b) << 16); }

// ---------------- CSR build (locality-aware) ----------------

__global__ void bucket_hist_kernel(const int* __restrict__ dst, int* __restrict__ bcnt,
                                   int E, int B) {
    __shared__ int h[256];
    int t = threadIdx.x;
    h[t] = 0;
    __syncthreads();
    for (int e = blockIdx.x * blockDim.x + t; e < E; e += gridDim.x * blockDim.x)
        atomicAdd(&h[dst[e] >> NPB_LOG], 1);
    __syncthreads();
    if (t < B && h[t]) atomicAdd(&bcnt[t], h[t]);
}

__global__ void bucket_scan_kernel(const int* __restrict__ bcnt, int* __restrict__ bstart,
                                   int* __restrict__ cursorB, int B, int E) {
    __shared__ int tmp[256];
    int t = threadIdx.x;
    int v = (t < B) ? bcnt[t] : 0;
    tmp[t] = v;
    __syncthreads();
    for (int off = 1; off < 256; off <<= 1) {
        int x = tmp[t];
        if (t >= off) x += tmp[t - off];
        __syncthreads();
        tmp[t] = x;
        __syncthreads();
    }
    if (t < B) {
        int ex = tmp[t] - v;
        bstart[t] = ex;
        cursorB[t] = ex;
    }
    if (t == 0) bstart[B] = E;
}

__global__ __launch_bounds__(256) void partition_kernel(
    const int* __restrict__ src, const int* __restrict__ dst,
    int* __restrict__ cursorB, unsigned* __restrict__ ebuf, int E, int B) {
    __shared__ int hist[256];
    __shared__ int base[256];
    int t = threadIdx.x;
    hist[t] = 0;
    __syncthreads();
    int e0 = blockIdx.x * 4096;
    int e1 = min(e0 + 4096, E);
    for (int e = e0 + t; e < e1; e += 256)
        atomicAdd(&hist[dst[e] >> NPB_LOG], 1);
    __syncthreads();
    int h = hist[t];
    if (t < B && h) base[t] = atomicAdd(&cursorB[t], h);
    __syncthreads();
    hist[t] = 0;
    __syncthreads();
    for (int e = e0 + t; e < e1; e += 256) {
        int d = dst[e];
        int b = d >> NPB_LOG;
        int off = atomicAdd(&hist[b], 1);
        ebuf[base[b] + off] = ((unsigned)src[e] << NPB_LOG) | (unsigned)(d & (NPB - 1));
    }
}

__global__ __launch_bounds__(256) void build_csr_kernel(
    const unsigned* __restrict__ ebuf, const int* __restrict__ bstart,
    int* __restrict__ rowptr, float* __restrict__ degInv, int* __restrict__ csr,
    int N, int B) {
    __shared__ int cnt[NPB];
    __shared__ int cur[NPB];
    __shared__ int ps[256];
    int b = blockIdx.x;
    int t = threadIdx.x;
    int nbase = b << NPB_LOG;
    int nn = min(NPB, N - nbase);
    cnt[t] = 0;
    cnt[t + 256] = 0;
    __syncthreads();
    int ebeg = bstart[b], eend = bstart[b + 1];
    for (int e = ebeg + t; e < eend; e += 256)
        atomicAdd(&cnt[ebuf[e] & (NPB - 1)], 1);
    __syncthreads();
    int c0 = cnt[2 * t], c1 = cnt[2 * t + 1];
    int pair = c0 + c1;
    ps[t] = pair;
    __syncthreads();
    for (int off = 1; off < 256; off <<= 1) {
        int x = ps[t];
        if (t >= off) x += ps[t - off];
        __syncthreads();
        ps[t] = x;
        __syncthreads();
    }
    int exPair = ps[t] - pair;
    int g0 = ebeg + exPair;
    int g1 = g0 + c0;
    cur[2 * t] = g0;
    cur[2 * t + 1] = g1;
    if (2 * t < nn) {
        rowptr[nbase + 2 * t] = g0;
        degInv[nbase + 2 * t] = 1.0f / (float)max(c0, 1);
    }
    if (2 * t + 1 < nn) {
        rowptr[nbase + 2 * t + 1] = g1;
        degInv[nbase + 2 * t + 1] = 1.0f / (float)max(c1, 1);
    }
    if (b == B - 1 && t == 0) rowptr[N] = eend;
    __syncthreads();
    for (int e = ebeg + t; e < eend; e += 256) {
        unsigned p = ebuf[e];
        int pos = atomicAdd(&cur[p & (NPB - 1)], 1);
        csr[pos] = (int)(p >> NPB_LOG);
    }
}

// ---------------- f32 -> bf16 slice-major conversion ----------------
// out layout: [8][n][16] bf16. idx = sl*n + v (v fastest -> coalesced writes).
__global__ void cvt_slices_kernel(const float* __restrict__ in, unsigned short* __restrict__ out,
                                  int n) {
    int idx = blockIdx.x * blockDim.x + threadIdx.x;
    if (idx >= n * 8) return;
    int sl = idx / n;
    int v = idx - sl * n;
    const float4* p = reinterpret_cast<const float4*>(in + (size_t)v * 128 + sl * 16);
    float4 f0 = p[0], f1 = p[1], f2 = p[2], f3 = p[3];
    uint4 a, b;
    a.x = pack2(f0.x, f0.y); a.y = pack2(f0.z, f0.w);
    a.z = pack2(f1.x, f1.y); a.w = pack2(f1.z, f1.w);
    b.x = pack2(f2.x, f2.y); b.y = pack2(f2.z, f2.w);
    b.z = pack2(f3.x, f3.y); b.w = pack2(f3.z, f3.w);
    uint4* q = reinterpret_cast<uint4*>(out) + (size_t)idx * 2;
    q[0] = a;
    q[1] = b;
}

// ---------------- weight swizzle into MFMA fragment order ----------------
__global__ void swizzleW_kernel(const float* __restrict__ Wl, const float* __restrict__ Wr,
                                unsigned short* __restrict__ out,
                                int Khalf, int Ktotal, int DOUT) {
    int CT = DOUT >> 4;
    int total = (Ktotal >> 5) * CT * 64;
    int id = blockIdx.x * blockDim.x + threadIdx.x;
    if (id >= total) return;
    int lane = id & 63;
    int ctkt = id >> 6;
    int ct = ctkt % CT;
    int kt = ctkt / CT;
    int col = ct * 16 + (lane & 15);
    int k0 = kt * 32 + (lane >> 4) * 8;
#pragma unroll
    for (int i = 0; i < 8; ++i) {
        int k = k0 + i;
        float w = (k < Khalf) ? Wl[(size_t)k * DOUT + col] : Wr[(size_t)(k - Khalf) * DOUT + col];
        out[(size_t)id * 8 + i] = (unsigned short)bf1(w);
    }
}

// ---------------- fold BN into per-column affine: y = A*acc + B ----------------
__global__ void bnprep_kernel(const float* __restrict__ bl, const float* __restrict__ g,
                              const float* __restrict__ b, const float* __restrict__ m,
                              const float* __restrict__ v,
                              float* __restrict__ scaleA, float* __restrict__ biasB, int D) {
    int c = blockIdx.x * blockDim.x + threadIdx.x;
    if (c < D) {
        float A = g[c] * rsqrtf(v[c] + EPS);
        scaleA[c] = A;
        biasB[c] = (bl[c] - m[c]) * A + b[c];
    }
}

// ---------------- XCD-sharded mean aggregation ----------------
// slice = blockIdx % 8 (round-robin block->XCD keeps each 3.2MB slice in one L2).
// 4 lanes per node, 8 B (uint2) per lane = one 32-B slice row per edge.
__global__ __launch_bounds__(256) void aggregate_sliced_kernel(
    const unsigned short* __restrict__ Xs, const int* __restrict__ rowptr,
    const int* __restrict__ csr, const float* __restrict__ degInv,
    unsigned short* __restrict__ As, int n) {
    int sl = blockIdx.x & 7;
    int chunk = blockIdx.x >> 3;
    int tid = threadIdx.x;
    int v = chunk * 64 + (tid >> 2);
    int t = tid & 3;
    if (v >= n) return;
    const uint2* X2 = reinterpret_cast<const uint2*>(Xs + (size_t)sl * n * 16);
    uint2* A2 = reinterpret_cast<uint2*>(As + (size_t)sl * n * 16);
    int beg = rowptr[v], end = rowptr[v + 1];
    float s0 = 0.f, s1 = 0.f, s2 = 0.f, s3 = 0.f;
    int e = beg;
    for (; e + 2 <= end; e += 2) {
        int u0 = csr[e], u1 = csr[e + 1];
        uint2 a = X2[(size_t)u0 * 4 + t];
        uint2 b = X2[(size_t)u1 * 4 + t];
        s0 += blo(a.x) + blo(b.x);
        s1 += bhi(a.x) + bhi(b.x);
        s2 += blo(a.y) + blo(b.y);
        s3 += bhi(a.y) + bhi(b.y);
    }
    if (e < end) {
        int u = csr[e];
        uint2 a = X2[(size_t)u * 4 + t];
        s0 += blo(a.x); s1 += bhi(a.x); s2 += blo(a.y); s3 += bhi(a.y);
    }
    float di = degInv[v];
    uint2 o;
    o.x = pack2(s0 * di, s1 * di);
    o.y = pack2(s2 * di, s3 * di);
    A2[(size_t)v * 4 + t] = o;
}

// ---------------- MFMA dual-GEMM + affine-BN + ReLU, DOUT=128, K=256 ----------------
// A operands in slice-major [8][n][16]; B pre-swizzled; no LDS.
__global__ __launch_bounds__(256) void gemm128_kernel(
    const unsigned short* __restrict__ A0, const unsigned short* __restrict__ A1,
    const unsigned short* __restrict__ Wsw,
    const float* __restrict__ scaleA, const float* __restrict__ biasB,
    unsigned short* __restrict__ OUT, int n) {
    int tid = threadIdx.x;
    int lane = tid & 63;
    int wave = tid >> 6;
    int wr = wave >> 1, wc = wave & 1;
    int row0 = blockIdx.x * 64 + wr * 32;
    int rlo = lane & 15, kq = lane >> 4;

    f32x4 acc[2][4];
#pragma unroll
    for (int rt = 0; rt < 2; ++rt)
#pragma unroll
        for (int c4 = 0; c4 < 4; ++c4)
#pragma unroll
            for (int k = 0; k < 4; ++k) acc[rt][c4][k] = 0.f;

    int r0 = row0 + rlo;
    int r1 = row0 + 16 + rlo;

    for (int kt = 0; kt < 8; ++kt) {
        const unsigned short* Aarr = (kt < 4) ? A0 : A1;
        int kb = (kt & 3) * 32 + kq * 8;          // 0..127 within feature dim
        int sl = kb >> 4;
        int rem = kb & 8;
        const unsigned short* base = Aarr + (size_t)sl * n * 16 + rem;
        bf16x8 a0, a1;
#pragma unroll
        for (int i = 0; i < 8; ++i) { a0[i] = (__bf16)0.f; a1[i] = (__bf16)0.f; }
        if (r0 < n) a0 = *reinterpret_cast<const bf16x8*>(base + (size_t)r0 * 16);
        if (r1 < n) a1 = *reinterpret_cast<const bf16x8*>(base + (size_t)r1 * 16);
#pragma unroll
        for (int c4 = 0; c4 < 4; ++c4) {
            int ct = wc * 4 + c4;
            bf16x8 b = *reinterpret_cast<const bf16x8*>(Wsw + ((size_t)(kt * 8 + ct) * 64 + lane) * 8);
            acc[0][c4] = __builtin_amdgcn_mfma_f32_16x16x32_bf16(a0, b, acc[0][c4], 0, 0, 0);
            acc[1][c4] = __builtin_amdgcn_mfma_f32_16x16x32_bf16(a1, b, acc[1][c4], 0, 0, 0);
        }
    }

#pragma unroll
    for (int rt = 0; rt < 2; ++rt)
#pragma unroll
        for (int c4 = 0; c4 < 4; ++c4) {
            int col = wc * 64 + c4 * 16 + rlo;
            int sl = col >> 4;
            float sA = scaleA[col];
            float sB = biasB[col];
#pragma unroll
            for (int i = 0; i < 4; ++i) {
                int r = row0 + rt * 16 + kq * 4 + i;
                if (r < n) {
                    float y = fmaxf(acc[rt][c4][i] * sA + sB, 0.f);
                    OUT[(size_t)sl * n * 16 + (size_t)r * 16 + rlo] = (unsigned short)bf1(y);
                }
            }
        }
}

// ---------------- layer 2: H@Wl2 -> tmpL (bf16 row-major), H@Wr2 + bl2 -> tmpR (f32) ----------------
__global__ __launch_bounds__(256) void dual64_kernel(
    const unsigned short* __restrict__ H,
    const unsigned short* __restrict__ WswL, const unsigned short* __restrict__ WswR,
    const float* __restrict__ bl,
    unsigned short* __restrict__ tmpL, float* __restrict__ tmpR, int n) {
    int tid = threadIdx.x;
    int lane = tid & 63;
    int wave = tid >> 6;
    int wr = wave >> 1, wc = wave & 1;
    int row0 = blockIdx.x * 64 + wr * 32;
    int rlo = lane & 15, kq = lane >> 4;

    f32x4 aL[2][2], aR[2][2];
#pragma unroll
    for (int rt = 0; rt < 2; ++rt)
#pragma unroll
        for (int c2 = 0; c2 < 2; ++c2)
#pragma unroll
            for (int k = 0; k < 4; ++k) { aL[rt][c2][k] = 0.f; aR[rt][c2][k] = 0.f; }

    int r0 = row0 + rlo;
    int r1 = row0 + 16 + rlo;

    for (int kt = 0; kt < 4; ++kt) {
        int kb = kt * 32 + kq * 8;
        int sl = kb >> 4;
        int rem = kb & 8;
        const unsigned short* base = H + (size_t)sl * n * 16 + rem;
        bf16x8 a0, a1;
#pragma unroll
        for (int i = 0; i < 8; ++i) { a0[i] = (__bf16)0.f; a1[i] = (__bf16)0.f; }
        if (r0 < n) a0 = *reinterpret_cast<const bf16x8*>(base + (size_t)r0 * 16);
        if (r1 < n) a1 = *reinterpret_cast<const bf16x8*>(base + (size_t)r1 * 16);
#pragma unroll
        for (int c2 = 0; c2 < 2; ++c2) {
            int ct = wc * 2 + c2;
            bf16x8 bL = *reinterpret_cast<const bf16x8*>(WswL + ((size_t)(kt * 4 + ct) * 64 + lane) * 8);
            bf16x8 bR = *reinterpret_cast<const bf16x8*>(WswR + ((size_t)(kt * 4 + ct) * 64 + lane) * 8);
            aL[0][c2] = __builtin_amdgcn_mfma_f32_16x16x32_bf16(a0, bL, aL[0][c2], 0, 0, 0);
            aL[1][c2] = __builtin_amdgcn_mfma_f32_16x16x32_bf16(a1, bL, aL[1][c2], 0, 0, 0);
            aR[0][c2] = __builtin_amdgcn_mfma_f32_16x16x32_bf16(a0, bR, aR[0][c2], 0, 0, 0);
            aR[1][c2] = __builtin_amdgcn_mfma_f32_16x16x32_bf16(a1, bR, aR[1][c2], 0, 0, 0);
        }
    }

#pragma unroll
    for (int rt = 0; rt < 2; ++rt)
#pragma unroll
        for (int c2 = 0; c2 < 2; ++c2) {
            int col = wc * 32 + c2 * 16 + rlo;
            float bv = bl[col];
#pragma unroll
            for (int i = 0; i < 4; ++i) {
                int r = row0 + rt * 16 + kq * 4 + i;
                if (r < n) {
                    tmpL[(size_t)r * 64 + col] = (unsigned short)bf1(aL[rt][c2][i]);
                    tmpR[(size_t)r * 64 + col] = aR[rt][c2][i] + bv;
                }
            }
        }
}

// ---------------- final: out = log_softmax( mean-agg(tmpL) + tmpR ) ----------------
__global__ void agg64_lsm_kernel(const unsigned short* __restrict__ tmpL,
                                 const float* __restrict__ tmpR,
                                 const int* __restrict__ rowptr, const int* __restrict__ csr,
                                 const float* __restrict__ degInv,
                                 float* __restrict__ out, int n) {
    int idx = blockIdx.x * blockDim.x + threadIdx.x;
    int v = idx >> 4;
    int t = idx & 15;
    if (v >= n) return;
    int beg = rowptr[v], end = rowptr[v + 1];
    const uint2* L2p = reinterpret_cast<const uint2*>(tmpL);
    float s0 = 0.f, s1 = 0.f, s2 = 0.f, s3 = 0.f;
    int e = beg;
    for (; e + 4 <= end; e += 4) {
        int u0 = csr[e + 0], u1 = csr[e + 1], u2 = csr[e + 2], u3 = csr[e + 3];
        uint2 a = L2p[(size_t)u0 * 16 + t];
        uint2 b = L2p[(size_t)u1 * 16 + t];
        uint2 c = L2p[(size_t)u2 * 16 + t];
        uint2 d = L2p[(size_t)u3 * 16 + t];
        s0 += blo(a.x) + blo(b.x) + blo(c.x) + blo(d.x);
        s1 += bhi(a.x) + bhi(b.x) + bhi(c.x) + bhi(d.x);
        s2 += blo(a.y) + blo(b.y) + blo(c.y) + blo(d.y);
        s3 += bhi(a.y) + bhi(b.y) + bhi(c.y) + bhi(d.y);
    }
    for (; e < end; ++e) {
        int u = csr[e];
        uint2 a = L2p[(size_t)u * 16 + t];
        s0 += blo(a.x); s1 += bhi(a.x); s2 += blo(a.y); s3 += bhi(a.y);
    }
    float di = degInv[v];
    float4 r4 = reinterpret_cast<const float4*>(tmpR)[(size_t)v * 16 + t];
    float y0 = s0 * di + r4.x;
    float y1 = s1 * di + r4.y;
    float y2 = s2 * di + r4.z;
    float y3 = s3 * di + r4.w;

    float mx = fmaxf(fmaxf(y0, y1), fmaxf(y2, y3));
#pragma unroll
    for (int o = 1; o < 16; o <<= 1) mx = fmaxf(mx, __shfl_xor(mx, o));
    float s = __expf(y0 - mx) + __expf(y1 - mx) + __expf(y2 - mx) + __expf(y3 - mx);
#pragma unroll
    for (int o = 1; o < 16; o <<= 1) s += __shfl_xor(s, o);
    float lse = mx + __logf(s);

    float4 o4;
    o4.x = y0 - lse; o4.y = y1 - lse; o4.z = y2 - lse; o4.w = y3 - lse;
    reinterpret_cast<float4*>(out)[(size_t)v * 16 + t] = o4;
}

// ---------------- launch ----------------

extern "C" void kernel_launch(void* const* d_in, const int* in_sizes, int n_in,
                              void* d_out, int out_size, void* d_ws, size_t ws_size,
                              hipStream_t stream) {
    const float* x   = (const float*)d_in[0];
    const int*   ei  = (const int*)d_in[1];
    const float* Wl0 = (const float*)d_in[2];
    const float* bl0 = (const float*)d_in[3];
    const float* Wr0 = (const float*)d_in[4];
    const float* g0  = (const float*)d_in[5];
    const float* b0  = (const float*)d_in[6];
    const float* m0  = (const float*)d_in[7];
    const float* v0  = (const float*)d_in[8];
    const float* Wl1 = (const float*)d_in[9];
    const float* bl1 = (const float*)d_in[10];
    const float* Wr1 = (const float*)d_in[11];
    const float* g1  = (const float*)d_in[12];
    const float* b1  = (const float*)d_in[13];
    const float* m1  = (const float*)d_in[14];
    const float* v1  = (const float*)d_in[15];
    const float* Wl2 = (const float*)d_in[16];
    const float* bl2 = (const float*)d_in[17];
    const float* Wr2 = (const float*)d_in[18];
    float* out = (float*)d_out;

    const int N = in_sizes[0] / 128;
    const int E = in_sizes[1] / 2;
    const int B = (N + NPB - 1) >> NPB_LOG;
    const int* src = ei;
    const int* dst = ei + E;

    char* ws = (char*)d_ws;
    size_t off = 0;
    auto alloc = [&](size_t bytes) -> void* {
        void* p = ws + off;
        off += (bytes + 255) & ~(size_t)255;
        return p;
    };
    int*   bcnt    = (int*)alloc(256 * 4);
    int*   bstart  = (int*)alloc(257 * 4);
    int*   cursorB = (int*)alloc(256 * 4);
    int*   rowptr  = (int*)alloc((size_t)(N + 1) * 4);
    float* degInv  = (float*)alloc((size_t)N * 4);
    int*   csr     = (int*)alloc((size_t)E * 4);
    unsigned* ebuf = (unsigned*)alloc((size_t)E * 4);
    unsigned short* x16   = (unsigned short*)alloc((size_t)N * 128 * 2);  // [8][N][16]
    unsigned short* agg16 = (unsigned short*)alloc((size_t)N * 128 * 2);  // [8][N][16]
    unsigned short* hA16  = (unsigned short*)alloc((size_t)N * 128 * 2);  // [8][N][16]
    unsigned short* hB16  = (unsigned short*)alloc((size_t)N * 128 * 2);  // [8][N][16]
    unsigned short* tmpL  = (unsigned short*)alloc((size_t)N * 64 * 2);   // row-major
    float* tmpR  = (float*)alloc((size_t)N * 64 * 4);                     // row-major
    unsigned short* Wsw0  = (unsigned short*)alloc(8 * 8 * 64 * 8 * 2);
    unsigned short* Wsw1  = (unsigned short*)alloc(8 * 8 * 64 * 8 * 2);
    unsigned short* WswL2 = (unsigned short*)alloc(4 * 4 * 64 * 8 * 2);
    unsigned short* WswR2 = (unsigned short*)alloc(4 * 4 * 64 * 8 * 2);
    float* bnA0 = (float*)alloc(128 * 4);
    float* bnB0 = (float*)alloc(128 * 4);
    float* bnA1 = (float*)alloc(128 * 4);
    float* bnB1 = (float*)alloc(128 * 4);

    hipMemsetAsync(bcnt, 0, 256 * 4, stream);

    // CSR build
    bucket_hist_kernel<<<512, 256, 0, stream>>>(dst, bcnt, E, B);
    bucket_scan_kernel<<<1, 256, 0, stream>>>(bcnt, bstart, cursorB, B, E);
    partition_kernel<<<(E + 4095) / 4096, 256, 0, stream>>>(src, dst, cursorB, ebuf, E, B);
    build_csr_kernel<<<B, 256, 0, stream>>>(ebuf, bstart, rowptr, degInv, csr, N, B);

    // prep: x -> bf16 slice-major, weight swizzles, BN folds
    cvt_slices_kernel<<<(N * 8 + 255) / 256, 256, 0, stream>>>(x, x16, N);
    swizzleW_kernel<<<16, 256, 0, stream>>>(Wl0, Wr0, Wsw0, 128, 256, 128);
    swizzleW_kernel<<<16, 256, 0, stream>>>(Wl1, Wr1, Wsw1, 128, 256, 128);
    swizzleW_kernel<<<4, 256, 0, stream>>>(Wl2, nullptr, WswL2, 128, 128, 64);
    swizzleW_kernel<<<4, 256, 0, stream>>>(Wr2, nullptr, WswR2, 128, 128, 64);
    bnprep_kernel<<<1, 128, 0, stream>>>(bl0, g0, b0, m0, v0, bnA0, bnB0, 128);
    bnprep_kernel<<<1, 128, 0, stream>>>(bl1, g1, b1, m1, v1, bnA1, bnB1, 128);

    int aggGridS = 8 * ((N + 63) / 64);
    int gemmGrid = (N + 63) / 64;

    // layer 0
    aggregate_sliced_kernel<<<aggGridS, 256, 0, stream>>>(x16, rowptr, csr, degInv, agg16, N);
    gemm128_kernel<<<gemmGrid, 256, 0, stream>>>(agg16, x16, Wsw0, bnA0, bnB0, hA16, N);
    // layer 1
    aggregate_sliced_kernel<<<aggGridS, 256, 0, stream>>>(hA16, rowptr, csr, degInv, agg16, N);
    gemm128_kernel<<<gemmGrid, 256, 0, stream>>>(agg16, hA16, Wsw1, bnA1, bnB1, hB16, N);
    // layer 2: transform-then-aggregate + fused log_softmax
    dual64_kernel<<<gemmGrid, 256, 0, stream>>>(hB16, WswL2, WswR2, bl2, tmpL, tmpR, N);
    agg64_lsm_kernel<<<(int)(((size_t)N * 16 + 255) / 256), 256, 0, stream>>>(
        tmpL, tmpR, rowptr, csr, degInv, out, N);
}

// Round 6
// 341.773 us; speedup vs baseline: 1.1416x; 1.1416x over previous
//
#include <hip/hip_runtime.h>

constexpr float EPS = 1e-5f;

#define NPB_LOG 9
#define NPB 512
#define ECH 4096

typedef __attribute__((ext_vector_type(8))) __bf16 bf16x8;
typedef __attribute__((ext_vector_type(4))) float f32x4;

// ---------- bf16 helpers ----------
__device__ __forceinline__ float blo(unsigned u) { return __uint_as_float(u << 16); }
__device__ __forceinline__ float bhi(unsigned u) { return __uint_as_float(u & 0xffff0000u); }
__device__ __forceinline__ unsigned bf1(float f) {
    unsigned u = __float_as_uint(f);
    return (u + 0x7fffu + ((u >> 16) & 1u)) >> 16;
}
__device__ __forceinline__ unsigned pack2(float a, float b) { return bf1(a) | (bf1(b) << 16); }

// ---------------- CSR build (locality-aware) ----------------

__global__ void bucket_hist_kernel(const int* __restrict__ dst, int* __restrict__ bcnt,
                                   int E, int B) {
    __shared__ int h[256];
    int t = threadIdx.x;
    h[t] = 0;
    __syncthreads();
    for (int e = blockIdx.x * blockDim.x + t; e < E; e += gridDim.x * blockDim.x)
        atomicAdd(&h[dst[e] >> NPB_LOG], 1);
    __syncthreads();
    if (t < B && h[t]) atomicAdd(&bcnt[t], h[t]);
}

__global__ void bucket_scan_kernel(const int* __restrict__ bcnt, int* __restrict__ bstart,
                                   int* __restrict__ cursorB, int B, int E) {
    __shared__ int tmp[256];
    int t = threadIdx.x;
    int v = (t < B) ? bcnt[t] : 0;
    tmp[t] = v;
    __syncthreads();
    for (int off = 1; off < 256; off <<= 1) {
        int x = tmp[t];
        if (t >= off) x += tmp[t - off];
        __syncthreads();
        tmp[t] = x;
        __syncthreads();
    }
    if (t < B) {
        int ex = tmp[t] - v;
        bstart[t] = ex;
        cursorB[t] = ex;
    }
    if (t == 0) bstart[B] = E;
}

__global__ __launch_bounds__(256) void partition_kernel(
    const int* __restrict__ src, const int* __restrict__ dst,
    int* __restrict__ cursorB, unsigned* __restrict__ ebuf, int E, int B) {
    __shared__ int hist[256];
    __shared__ int base[256];
    int t = threadIdx.x;
    hist[t] = 0;
    __syncthreads();
    int e0 = blockIdx.x * 4096;
    int e1 = min(e0 + 4096, E);
    for (int e = e0 + t; e < e1; e += 256)
        atomicAdd(&hist[dst[e] >> NPB_LOG], 1);
    __syncthreads();
    int h = hist[t];
    if (t < B && h) base[t] = atomicAdd(&cursorB[t], h);
    __syncthreads();
    hist[t] = 0;
    __syncthreads();
    for (int e = e0 + t; e < e1; e += 256) {
        int d = dst[e];
        int b = d >> NPB_LOG;
        int off = atomicAdd(&hist[b], 1);
        ebuf[base[b] + off] = ((unsigned)src[e] << NPB_LOG) | (unsigned)(d & (NPB - 1));
    }
}

__global__ __launch_bounds__(256) void build_csr_kernel(
    const unsigned* __restrict__ ebuf, const int* __restrict__ bstart,
    int* __restrict__ rowptr, float* __restrict__ degInv, int* __restrict__ csr,
    int N, int B) {
    __shared__ int cnt[NPB];
    __shared__ int cur[NPB];
    __shared__ int ps[256];
    int b = blockIdx.x;
    int t = threadIdx.x;
    int nbase = b << NPB_LOG;
    int nn = min(NPB, N - nbase);
    cnt[t] = 0;
    cnt[t + 256] = 0;
    __syncthreads();
    int ebeg = bstart[b], eend = bstart[b + 1];
    for (int e = ebeg + t; e < eend; e += 256)
        atomicAdd(&cnt[ebuf[e] & (NPB - 1)], 1);
    __syncthreads();
    int c0 = cnt[2 * t], c1 = cnt[2 * t + 1];
    int pair = c0 + c1;
    ps[t] = pair;
    __syncthreads();
    for (int off = 1; off < 256; off <<= 1) {
        int x = ps[t];
        if (t >= off) x += ps[t - off];
        __syncthreads();
        ps[t] = x;
        __syncthreads();
    }
    int exPair = ps[t] - pair;
    int g0 = ebeg + exPair;
    int g1 = g0 + c0;
    cur[2 * t] = g0;
    cur[2 * t + 1] = g1;
    if (2 * t < nn) {
        rowptr[nbase + 2 * t] = g0;
        degInv[nbase + 2 * t] = 1.0f / (float)max(c0, 1);
    }
    if (2 * t + 1 < nn) {
        rowptr[nbase + 2 * t + 1] = g1;
        degInv[nbase + 2 * t + 1] = 1.0f / (float)max(c1, 1);
    }
    if (b == B - 1 && t == 0) rowptr[N] = eend;
    __syncthreads();
    for (int e = ebeg + t; e < eend; e += 256) {
        unsigned p = ebuf[e];
        int pos = atomicAdd(&cur[p & (NPB - 1)], 1);
        csr[pos] = (int)(p >> NPB_LOG);
    }
}

// ---------------- f32 -> bf16 slice-major conversion ----------------
__global__ void cvt_slices_kernel(const float* __restrict__ in, unsigned short* __restrict__ out,
                                  int n) {
    int idx = blockIdx.x * blockDim.x + threadIdx.x;
    if (idx >= n * 8) return;
    int sl = idx / n;
    int v = idx - sl * n;
    const float4* p = reinterpret_cast<const float4*>(in + (size_t)v * 128 + sl * 16);
    float4 f0 = p[0], f1 = p[1], f2 = p[2], f3 = p[3];
    uint4 a, b;
    a.x = pack2(f0.x, f0.y); a.y = pack2(f0.z, f0.w);
    a.z = pack2(f1.x, f1.y); a.w = pack2(f1.z, f1.w);
    b.x = pack2(f2.x, f2.y); b.y = pack2(f2.z, f2.w);
    b.z = pack2(f3.x, f3.y); b.w = pack2(f3.z, f3.w);
    uint4* q = reinterpret_cast<uint4*>(out) + (size_t)idx * 2;
    q[0] = a;
    q[1] = b;
}

// ---------------- weight swizzle into MFMA fragment order ----------------
__global__ void swizzleW_kernel(const float* __restrict__ Wl, const float* __restrict__ Wr,
                                unsigned short* __restrict__ out,
                                int Khalf, int Ktotal, int DOUT) {
    int CT = DOUT >> 4;
    int total = (Ktotal >> 5) * CT * 64;
    int id = blockIdx.x * blockDim.x + threadIdx.x;
    if (id >= total) return;
    int lane = id & 63;
    int ctkt = id >> 6;
    int ct = ctkt % CT;
    int kt = ctkt / CT;
    int col = ct * 16 + (lane & 15);
    int k0 = kt * 32 + (lane >> 4) * 8;
#pragma unroll
    for (int i = 0; i < 8; ++i) {
        int k = k0 + i;
        float w = (k < Khalf) ? Wl[(size_t)k * DOUT + col] : Wr[(size_t)(k - Khalf) * DOUT + col];
        out[(size_t)id * 8 + i] = (unsigned short)bf1(w);
    }
}

// ---------------- fold BN into per-column affine: y = A*acc + B ----------------
__global__ void bnprep_kernel(const float* __restrict__ bl, const float* __restrict__ g,
                              const float* __restrict__ b, const float* __restrict__ m,
                              const float* __restrict__ v,
                              float* __restrict__ scaleA, float* __restrict__ biasB, int D) {
    int c = blockIdx.x * blockDim.x + threadIdx.x;
    if (c < D) {
        float A = g[c] * rsqrtf(v[c] + EPS);
        scaleA[c] = A;
        biasB[c] = (bl[c] - m[c]) * A + b[c];
    }
}

// ---------------- XCD-sharded mean aggregation, LDS-staged edge indices ----------------
// slice = blockIdx % 8 (round-robin block->XCD pins each 3.2MB slice in one L2).
// Block = 64 nodes x 4 lanes. Node range's edges are CONTIGUOUS (bucket-ordered CSR):
// stage them into LDS once, then gather with x4-unrolled independent 8B loads.
__global__ __launch_bounds__(256) void aggregate_sliced_kernel(
    const unsigned short* __restrict__ Xs, const int* __restrict__ rowptr,
    const int* __restrict__ csr, const float* __restrict__ degInv,
    unsigned short* __restrict__ As, int n) {
    __shared__ int eidx[ECH];
    int sl = blockIdx.x & 7;
    int chunk = blockIdx.x >> 3;
    int tid = threadIdx.x;
    int v0 = chunk * 64;
    int vend = min(v0 + 64, n);
    int ebeg_b = rowptr[v0];
    int eend_b = rowptr[vend];
    int v = v0 + (tid >> 2);
    int t = tid & 3;
    int beg = 0, end = 0;
    if (v < n) { beg = rowptr[v]; end = rowptr[v + 1]; }
    const uint2* X2 = reinterpret_cast<const uint2*>(Xs + (size_t)sl * n * 16);
    float s0 = 0.f, s1 = 0.f, s2 = 0.f, s3 = 0.f;

    for (int base = ebeg_b; base < eend_b; base += ECH) {
        int cnt = min(ECH, eend_b - base);
        __syncthreads();
        for (int i = tid; i < cnt; i += 256) eidx[i] = csr[base + i];
        __syncthreads();
        int lo = max(beg, base) - base;
        int hi = min(end, base + cnt) - base;
        int e = lo;
        for (; e + 4 <= hi; e += 4) {
            int u0 = eidx[e + 0], u1 = eidx[e + 1], u2 = eidx[e + 2], u3 = eidx[e + 3];
            uint2 a = X2[(size_t)u0 * 4 + t];
            uint2 b = X2[(size_t)u1 * 4 + t];
            uint2 c = X2[(size_t)u2 * 4 + t];
            uint2 d = X2[(size_t)u3 * 4 + t];
            s0 += blo(a.x) + blo(b.x) + blo(c.x) + blo(d.x);
            s1 += bhi(a.x) + bhi(b.x) + bhi(c.x) + bhi(d.x);
            s2 += blo(a.y) + blo(b.y) + blo(c.y) + blo(d.y);
            s3 += bhi(a.y) + bhi(b.y) + bhi(c.y) + bhi(d.y);
        }
        for (; e < hi; ++e) {
            int u = eidx[e];
            uint2 a = X2[(size_t)u * 4 + t];
            s0 += blo(a.x); s1 += bhi(a.x); s2 += blo(a.y); s3 += bhi(a.y);
        }
    }

    if (v < n) {
        float di = degInv[v];
        uint2 o;
        o.x = pack2(s0 * di, s1 * di);
        o.y = pack2(s2 * di, s3 * di);
        reinterpret_cast<uint2*>(As + (size_t)sl * n * 16)[(size_t)v * 4 + t] = o;
    }
}

// ---------------- MFMA dual-GEMM + affine-BN + ReLU, DOUT=128, K=256 ----------------
__global__ __launch_bounds__(256) void gemm128_kernel(
    const unsigned short* __restrict__ A0, const unsigned short* __restrict__ A1,
    const unsigned short* __restrict__ Wsw,
    const float* __restrict__ scaleA, const float* __restrict__ biasB,
    unsigned short* __restrict__ OUT, int n) {
    int tid = threadIdx.x;
    int lane = tid & 63;
    int wave = tid >> 6;
    int wr = wave >> 1, wc = wave & 1;
    int row0 = blockIdx.x * 64 + wr * 32;
    int rlo = lane & 15, kq = lane >> 4;

    f32x4 acc[2][4];
#pragma unroll
    for (int rt = 0; rt < 2; ++rt)
#pragma unroll
        for (int c4 = 0; c4 < 4; ++c4)
#pragma unroll
            for (int k = 0; k < 4; ++k) acc[rt][c4][k] = 0.f;

    int r0 = row0 + rlo;
    int r1 = row0 + 16 + rlo;

    for (int kt = 0; kt < 8; ++kt) {
        const unsigned short* Aarr = (kt < 4) ? A0 : A1;
        int kb = (kt & 3) * 32 + kq * 8;
        int sl = kb >> 4;
        int rem = kb & 8;
        const unsigned short* base = Aarr + (size_t)sl * n * 16 + rem;
        bf16x8 a0, a1;
#pragma unroll
        for (int i = 0; i < 8; ++i) { a0[i] = (__bf16)0.f; a1[i] = (__bf16)0.f; }
        if (r0 < n) a0 = *reinterpret_cast<const bf16x8*>(base + (size_t)r0 * 16);
        if (r1 < n) a1 = *reinterpret_cast<const bf16x8*>(base + (size_t)r1 * 16);
#pragma unroll
        for (int c4 = 0; c4 < 4; ++c4) {
            int ct = wc * 4 + c4;
            bf16x8 b = *reinterpret_cast<const bf16x8*>(Wsw + ((size_t)(kt * 8 + ct) * 64 + lane) * 8);
            acc[0][c4] = __builtin_amdgcn_mfma_f32_16x16x32_bf16(a0, b, acc[0][c4], 0, 0, 0);
            acc[1][c4] = __builtin_amdgcn_mfma_f32_16x16x32_bf16(a1, b, acc[1][c4], 0, 0, 0);
        }
    }

#pragma unroll
    for (int rt = 0; rt < 2; ++rt)
#pragma unroll
        for (int c4 = 0; c4 < 4; ++c4) {
            int col = wc * 64 + c4 * 16 + rlo;
            int sl = col >> 4;
            float sA = scaleA[col];
            float sB = biasB[col];
#pragma unroll
            for (int i = 0; i < 4; ++i) {
                int r = row0 + rt * 16 + kq * 4 + i;
                if (r < n) {
                    float y = fmaxf(acc[rt][c4][i] * sA + sB, 0.f);
                    OUT[(size_t)sl * n * 16 + (size_t)r * 16 + rlo] = (unsigned short)bf1(y);
                }
            }
        }
}

// ---------------- layer 2: H@Wl2 -> tmpL (bf16 row-major), H@Wr2 + bl2 -> tmpR (f32) ----------------
__global__ __launch_bounds__(256) void dual64_kernel(
    const unsigned short* __restrict__ H,
    const unsigned short* __restrict__ WswL, const unsigned short* __restrict__ WswR,
    const float* __restrict__ bl,
    unsigned short* __restrict__ tmpL, float* __restrict__ tmpR, int n) {
    int tid = threadIdx.x;
    int lane = tid & 63;
    int wave = tid >> 6;
    int wr = wave >> 1, wc = wave & 1;
    int row0 = blockIdx.x * 64 + wr * 32;
    int rlo = lane & 15, kq = lane >> 4;

    f32x4 aL[2][2], aR[2][2];
#pragma unroll
    for (int rt = 0; rt < 2; ++rt)
#pragma unroll
        for (int c2 = 0; c2 < 2; ++c2)
#pragma unroll
            for (int k = 0; k < 4; ++k) { aL[rt][c2][k] = 0.f; aR[rt][c2][k] = 0.f; }

    int r0 = row0 + rlo;
    int r1 = row0 + 16 + rlo;

    for (int kt = 0; kt < 4; ++kt) {
        int kb = kt * 32 + kq * 8;
        int sl = kb >> 4;
        int rem = kb & 8;
        const unsigned short* base = H + (size_t)sl * n * 16 + rem;
        bf16x8 a0, a1;
#pragma unroll
        for (int i = 0; i < 8; ++i) { a0[i] = (__bf16)0.f; a1[i] = (__bf16)0.f; }
        if (r0 < n) a0 = *reinterpret_cast<const bf16x8*>(base + (size_t)r0 * 16);
        if (r1 < n) a1 = *reinterpret_cast<const bf16x8*>(base + (size_t)r1 * 16);
#pragma unroll
        for (int c2 = 0; c2 < 2; ++c2) {
            int ct = wc * 2 + c2;
            bf16x8 bL = *reinterpret_cast<const bf16x8*>(WswL + ((size_t)(kt * 4 + ct) * 64 + lane) * 8);
            bf16x8 bR = *reinterpret_cast<const bf16x8*>(WswR + ((size_t)(kt * 4 + ct) * 64 + lane) * 8);
            aL[0][c2] = __builtin_amdgcn_mfma_f32_16x16x32_bf16(a0, bL, aL[0][c2], 0, 0, 0);
            aL[1][c2] = __builtin_amdgcn_mfma_f32_16x16x32_bf16(a1, bL, aL[1][c2], 0, 0, 0);
            aR[0][c2] = __builtin_amdgcn_mfma_f32_16x16x32_bf16(a0, bR, aR[0][c2], 0, 0, 0);
            aR[1][c2] = __builtin_amdgcn_mfma_f32_16x16x32_bf16(a1, bR, aR[1][c2], 0, 0, 0);
        }
    }

#pragma unroll
    for (int rt = 0; rt < 2; ++rt)
#pragma unroll
        for (int c2 = 0; c2 < 2; ++c2) {
            int col = wc * 32 + c2 * 16 + rlo;
            float bv = bl[col];
#pragma unroll
            for (int i = 0; i < 4; ++i) {
                int r = row0 + rt * 16 + kq * 4 + i;
                if (r < n) {
                    tmpL[(size_t)r * 64 + col] = (unsigned short)bf1(aL[rt][c2][i]);
                    tmpR[(size_t)r * 64 + col] = aR[rt][c2][i] + bv;
                }
            }
        }
}

// ---------------- final: out = log_softmax( mean-agg(tmpL) + tmpR ) ----------------
__global__ void agg64_lsm_kernel(const unsigned short* __restrict__ tmpL,
                                 const float* __restrict__ tmpR,
                                 const int* __restrict__ rowptr, const int* __restrict__ csr,
                                 const float* __restrict__ degInv,
                                 float* __restrict__ out, int n) {
    int idx = blockIdx.x * blockDim.x + threadIdx.x;
    int v = idx >> 4;
    int t = idx & 15;
    if (v >= n) return;
    int beg = rowptr[v], end = rowptr[v + 1];
    const uint2* L2p = reinterpret_cast<const uint2*>(tmpL);
    float s0 = 0.f, s1 = 0.f, s2 = 0.f, s3 = 0.f;
    int e = beg;
    for (; e + 4 <= end; e += 4) {
        int u0 = csr[e + 0], u1 = csr[e + 1], u2 = csr[e + 2], u3 = csr[e + 3];
        uint2 a = L2p[(size_t)u0 * 16 + t];
        uint2 b = L2p[(size_t)u1 * 16 + t];
        uint2 c = L2p[(size_t)u2 * 16 + t];
        uint2 d = L2p[(size_t)u3 * 16 + t];
        s0 += blo(a.x) + blo(b.x) + blo(c.x) + blo(d.x);
        s1 += bhi(a.x) + bhi(b.x) + bhi(c.x) + bhi(d.x);
        s2 += blo(a.y) + blo(b.y) + blo(c.y) + blo(d.y);
        s3 += bhi(a.y) + bhi(b.y) + bhi(c.y) + bhi(d.y);
    }
    for (; e < end; ++e) {
        int u = csr[e];
        uint2 a = L2p[(size_t)u * 16 + t];
        s0 += blo(a.x); s1 += bhi(a.x); s2 += blo(a.y); s3 += bhi(a.y);
    }
    float di = degInv[v];
    float4 r4 = reinterpret_cast<const float4*>(tmpR)[(size_t)v * 16 + t];
    float y0 = s0 * di + r4.x;
    float y1 = s1 * di + r4.y;
    float y2 = s2 * di + r4.z;
    float y3 = s3 * di + r4.w;

    float mx = fmaxf(fmaxf(y0, y1), fmaxf(y2, y3));
#pragma unroll
    for (int o = 1; o < 16; o <<= 1) mx = fmaxf(mx, __shfl_xor(mx, o));
    float s = __expf(y0 - mx) + __expf(y1 - mx) + __expf(y2 - mx) + __expf(y3 - mx);
#pragma unroll
    for (int o = 1; o < 16; o <<= 1) s += __shfl_xor(s, o);
    float lse = mx + __logf(s);

    float4 o4;
    o4.x = y0 - lse; o4.y = y1 - lse; o4.z = y2 - lse; o4.w = y3 - lse;
    reinterpret_cast<float4*>(out)[(size_t)v * 16 + t] = o4;
}

// ---------------- launch ----------------

extern "C" void kernel_launch(void* const* d_in, const int* in_sizes, int n_in,
                              void* d_out, int out_size, void* d_ws, size_t ws_size,
                              hipStream_t stream) {
    const float* x   = (const float*)d_in[0];
    const int*   ei  = (const int*)d_in[1];
    const float* Wl0 = (const float*)d_in[2];
    const float* bl0 = (const float*)d_in[3];
    const float* Wr0 = (const float*)d_in[4];
    const float* g0  = (const float*)d_in[5];
    const float* b0  = (const float*)d_in[6];
    const float* m0  = (const float*)d_in[7];
    const float* v0  = (const float*)d_in[8];
    const float* Wl1 = (const float*)d_in[9];
    const float* bl1 = (const float*)d_in[10];
    const float* Wr1 = (const float*)d_in[11];
    const float* g1  = (const float*)d_in[12];
    const float* b1  = (const float*)d_in[13];
    const float* m1  = (const float*)d_in[14];
    const float* v1  = (const float*)d_in[15];
    const float* Wl2 = (const float*)d_in[16];
    const float* bl2 = (const float*)d_in[17];
    const float* Wr2 = (const float*)d_in[18];
    float* out = (float*)d_out;

    const int N = in_sizes[0] / 128;
    const int E = in_sizes[1] / 2;
    const int B = (N + NPB - 1) >> NPB_LOG;
    const int* src = ei;
    const int* dst = ei + E;

    char* ws = (char*)d_ws;
    size_t off = 0;
    auto alloc = [&](size_t bytes) -> void* {
        void* p = ws + off;
        off += (bytes + 255) & ~(size_t)255;
        return p;
    };
    int*   bcnt    = (int*)alloc(256 * 4);
    int*   bstart  = (int*)alloc(257 * 4);
    int*   cursorB = (int*)alloc(256 * 4);
    int*   rowptr  = (int*)alloc((size_t)(N + 1) * 4);
    float* degInv  = (float*)alloc((size_t)N * 4);
    int*   csr     = (int*)alloc((size_t)E * 4);
    unsigned* ebuf = (unsigned*)alloc((size_t)E * 4);
    unsigned short* x16   = (unsigned short*)alloc((size_t)N * 128 * 2);  // [8][N][16]
    unsigned short* agg16 = (unsigned short*)alloc((size_t)N * 128 * 2);  // [8][N][16]
    unsigned short* hA16  = (unsigned short*)alloc((size_t)N * 128 * 2);  // [8][N][16]
    unsigned short* hB16  = (unsigned short*)alloc((size_t)N * 128 * 2);  // [8][N][16]
    unsigned short* tmpL  = (unsigned short*)alloc((size_t)N * 64 * 2);   // row-major
    float* tmpR  = (float*)alloc((size_t)N * 64 * 4);                     // row-major
    unsigned short* Wsw0  = (unsigned short*)alloc(8 * 8 * 64 * 8 * 2);
    unsigned short* Wsw1  = (unsigned short*)alloc(8 * 8 * 64 * 8 * 2);
    unsigned short* WswL2 = (unsigned short*)alloc(4 * 4 * 64 * 8 * 2);
    unsigned short* WswR2 = (unsigned short*)alloc(4 * 4 * 64 * 8 * 2);
    float* bnA0 = (float*)alloc(128 * 4);
    float* bnB0 = (float*)alloc(128 * 4);
    float* bnA1 = (float*)alloc(128 * 4);
    float* bnB1 = (float*)alloc(128 * 4);

    hipMemsetAsync(bcnt, 0, 256 * 4, stream);

    // CSR build
    bucket_hist_kernel<<<512, 256, 0, stream>>>(dst, bcnt, E, B);
    bucket_scan_kernel<<<1, 256, 0, stream>>>(bcnt, bstart, cursorB, B, E);
    partition_kernel<<<(E + 4095) / 4096, 256, 0, stream>>>(src, dst, cursorB, ebuf, E, B);
    build_csr_kernel<<<B, 256, 0, stream>>>(ebuf, bstart, rowptr, degInv, csr, N, B);

    // prep: x -> bf16 slice-major, weight swizzles, BN folds
    cvt_slices_kernel<<<(N * 8 + 255) / 256, 256, 0, stream>>>(x, x16, N);
    swizzleW_kernel<<<16, 256, 0, stream>>>(Wl0, Wr0, Wsw0, 128, 256, 128);
    swizzleW_kernel<<<16, 256, 0, stream>>>(Wl1, Wr1, Wsw1, 128, 256, 128);
    swizzleW_kernel<<<4, 256, 0, stream>>>(Wl2, nullptr, WswL2, 128, 128, 64);
    swizzleW_kernel<<<4, 256, 0, stream>>>(Wr2, nullptr, WswR2, 128, 128, 64);
    bnprep_kernel<<<1, 128, 0, stream>>>(bl0, g0, b0, m0, v0, bnA0, bnB0, 128);
    bnprep_kernel<<<1, 128, 0, stream>>>(bl1, g1, b1, m1, v1, bnA1, bnB1, 128);

    int aggGridS = 8 * ((N + 63) / 64);
    int gemmGrid = (N + 63) / 64;

    // layer 0
    aggregate_sliced_kernel<<<aggGridS, 256, 0, stream>>>(x16, rowptr, csr, degInv, agg16, N);
    gemm128_kernel<<<gemmGrid, 256, 0, stream>>>(agg16, x16, Wsw0, bnA0, bnB0, hA16, N);
    // layer 1
    aggregate_sliced_kernel<<<aggGridS, 256, 0, stream>>>(hA16, rowptr, csr, degInv, agg16, N);
    gemm128_kernel<<<gemmGrid, 256, 0, stream>>>(agg16, hA16, Wsw1, bnA1, bnB1, hB16, N);
    // layer 2: transform-then-aggregate + fused log_softmax
    dual64_kernel<<<gemmGrid, 256, 0, stream>>>(hB16, WswL2, WswR2, bl2, tmpL, tmpR, N);
    agg64_lsm_kernel<<<(int)(((size_t)N * 16 + 255) / 256), 256, 0, stream>>>(
        tmpL, tmpR, rowptr, csr, degInv, out, N);
}

// Round 7
// 339.058 us; speedup vs baseline: 1.1507x; 1.0080x over previous
//
#include <hip/hip_runtime.h>

constexpr float EPS = 1e-5f;

#define NPB_LOG 9
#define NPB 512
#define ECH 4096

typedef __attribute__((ext_vector_type(8))) __bf16 bf16x8;
typedef __attribute__((ext_vector_type(4))) float f32x4;

// ---------- bf16 helpers ----------
__device__ __forceinline__ float blo(unsigned u) { return __uint_as_float(u << 16); }
__device__ __forceinline__ float bhi(unsigned u) { return __uint_as_float(u & 0xffff0000u); }
__device__ __forceinline__ unsigned bf1(float f) {
    unsigned u = __float_as_uint(f);
    return (u + 0x7fffu + ((u >> 16) & 1u)) >> 16;
}
__device__ __forceinline__ unsigned pack2(float a, float b) { return bf1(a) | (bf1(b) << 16); }

// ---------------- CSR build (locality-aware) ----------------

__global__ void bucket_hist_kernel(const int* __restrict__ dst, int* __restrict__ bcnt,
                                   int E, int B) {
    __shared__ int h[256];
    int t = threadIdx.x;
    h[t] = 0;
    __syncthreads();
    for (int e = blockIdx.x * blockDim.x + t; e < E; e += gridDim.x * blockDim.x)
        atomicAdd(&h[dst[e] >> NPB_LOG], 1);
    __syncthreads();
    if (t < B && h[t]) atomicAdd(&bcnt[t], h[t]);
}

__global__ void bucket_scan_kernel(const int* __restrict__ bcnt, int* __restrict__ bstart,
                                   int* __restrict__ cursorB, int B, int E) {
    __shared__ int tmp[256];
    int t = threadIdx.x;
    int v = (t < B) ? bcnt[t] : 0;
    tmp[t] = v;
    __syncthreads();
    for (int off = 1; off < 256; off <<= 1) {
        int x = tmp[t];
        if (t >= off) x += tmp[t - off];
        __syncthreads();
        tmp[t] = x;
        __syncthreads();
    }
    if (t < B) {
        int ex = tmp[t] - v;
        bstart[t] = ex;
        cursorB[t] = ex;
    }
    if (t == 0) bstart[B] = E;
}

__global__ __launch_bounds__(256) void partition_kernel(
    const int* __restrict__ src, const int* __restrict__ dst,
    int* __restrict__ cursorB, unsigned* __restrict__ ebuf, int E, int B) {
    __shared__ int hist[256];
    __shared__ int base[256];
    int t = threadIdx.x;
    hist[t] = 0;
    __syncthreads();
    int e0 = blockIdx.x * 4096;
    int e1 = min(e0 + 4096, E);
    for (int e = e0 + t; e < e1; e += 256)
        atomicAdd(&hist[dst[e] >> NPB_LOG], 1);
    __syncthreads();
    int h = hist[t];
    if (t < B && h) base[t] = atomicAdd(&cursorB[t], h);
    __syncthreads();
    hist[t] = 0;
    __syncthreads();
    for (int e = e0 + t; e < e1; e += 256) {
        int d = dst[e];
        int b = d >> NPB_LOG;
        int off = atomicAdd(&hist[b], 1);
        ebuf[base[b] + off] = ((unsigned)src[e] << NPB_LOG) | (unsigned)(d & (NPB - 1));
    }
}

__global__ __launch_bounds__(256) void build_csr_kernel(
    const unsigned* __restrict__ ebuf, const int* __restrict__ bstart,
    int* __restrict__ rowptr, float* __restrict__ degInv, int* __restrict__ csr,
    int N, int B) {
    __shared__ int cnt[NPB];
    __shared__ int cur[NPB];
    __shared__ int ps[256];
    int b = blockIdx.x;
    int t = threadIdx.x;
    int nbase = b << NPB_LOG;
    int nn = min(NPB, N - nbase);
    cnt[t] = 0;
    cnt[t + 256] = 0;
    __syncthreads();
    int ebeg = bstart[b], eend = bstart[b + 1];
    for (int e = ebeg + t; e < eend; e += 256)
        atomicAdd(&cnt[ebuf[e] & (NPB - 1)], 1);
    __syncthreads();
    int c0 = cnt[2 * t], c1 = cnt[2 * t + 1];
    int pair = c0 + c1;
    ps[t] = pair;
    __syncthreads();
    for (int off = 1; off < 256; off <<= 1) {
        int x = ps[t];
        if (t >= off) x += ps[t - off];
        __syncthreads();
        ps[t] = x;
        __syncthreads();
    }
    int exPair = ps[t] - pair;
    int g0 = ebeg + exPair;
    int g1 = g0 + c0;
    cur[2 * t] = g0;
    cur[2 * t + 1] = g1;
    if (2 * t < nn) {
        rowptr[nbase + 2 * t] = g0;
        degInv[nbase + 2 * t] = 1.0f / (float)max(c0, 1);
    }
    if (2 * t + 1 < nn) {
        rowptr[nbase + 2 * t + 1] = g1;
        degInv[nbase + 2 * t + 1] = 1.0f / (float)max(c1, 1);
    }
    if (b == B - 1 && t == 0) rowptr[N] = eend;
    __syncthreads();
    for (int e = ebeg + t; e < eend; e += 256) {
        unsigned p = ebuf[e];
        int pos = atomicAdd(&cur[p & (NPB - 1)], 1);
        csr[pos] = (int)(p >> NPB_LOG);
    }
}

// ---------------- f32 -> bf16 slice-major conversion ----------------
__global__ void cvt_slices_kernel(const float* __restrict__ in, unsigned short* __restrict__ out,
                                  int n) {
    int idx = blockIdx.x * blockDim.x + threadIdx.x;
    if (idx >= n * 8) return;
    int sl = idx / n;
    int v = idx - sl * n;
    const float4* p = reinterpret_cast<const float4*>(in + (size_t)v * 128 + sl * 16);
    float4 f0 = p[0], f1 = p[1], f2 = p[2], f3 = p[3];
    uint4 a, b;
    a.x = pack2(f0.x, f0.y); a.y = pack2(f0.z, f0.w);
    a.z = pack2(f1.x, f1.y); a.w = pack2(f1.z, f1.w);
    b.x = pack2(f2.x, f2.y); b.y = pack2(f2.z, f2.w);
    b.z = pack2(f3.x, f3.y); b.w = pack2(f3.z, f3.w);
    uint4* q = reinterpret_cast<uint4*>(out) + (size_t)idx * 2;
    q[0] = a;
    q[1] = b;
}

// ---------------- weight swizzle into MFMA fragment order ----------------
__global__ void swizzleW_kernel(const float* __restrict__ Wl, const float* __restrict__ Wr,
                                unsigned short* __restrict__ out,
                                int Khalf, int Ktotal, int DOUT) {
    int CT = DOUT >> 4;
    int total = (Ktotal >> 5) * CT * 64;
    int id = blockIdx.x * blockDim.x + threadIdx.x;
    if (id >= total) return;
    int lane = id & 63;
    int ctkt = id >> 6;
    int ct = ctkt % CT;
    int kt = ctkt / CT;
    int col = ct * 16 + (lane & 15);
    int k0 = kt * 32 + (lane >> 4) * 8;
#pragma unroll
    for (int i = 0; i < 8; ++i) {
        int k = k0 + i;
        float w = (k < Khalf) ? Wl[(size_t)k * DOUT + col] : Wr[(size_t)(k - Khalf) * DOUT + col];
        out[(size_t)id * 8 + i] = (unsigned short)bf1(w);
    }
}

// ---------------- fold BN into per-column affine: y = A*acc + B ----------------
__global__ void bnprep_kernel(const float* __restrict__ bl, const float* __restrict__ g,
                              const float* __restrict__ b, const float* __restrict__ m,
                              const float* __restrict__ v,
                              float* __restrict__ scaleA, float* __restrict__ biasB, int D) {
    int c = blockIdx.x * blockDim.x + threadIdx.x;
    if (c < D) {
        float A = g[c] * rsqrtf(v[c] + EPS);
        scaleA[c] = A;
        biasB[c] = (bl[c] - m[c]) * A + b[c];
    }
}

// ---------------- XCD-sharded mean aggregation, LDS-staged edges ----------------
// slice = blockIdx % 8 -> round-robin block->XCD pins each 3.2MB slice in one L2.
// Block = 128 nodes x 2 lanes; each lane loads one uint4 (16B) of the 32B slice row.
// Edge loop unrolled x8 -> 8 independent 16B gathers (128 B) in flight per lane.
__global__ __launch_bounds__(256) void aggregate_sliced_kernel(
    const unsigned short* __restrict__ Xs, const int* __restrict__ rowptr,
    const int* __restrict__ csr, const float* __restrict__ degInv,
    unsigned short* __restrict__ As, int n) {
    __shared__ int eidx[ECH];
    int sl = blockIdx.x & 7;
    int chunk = blockIdx.x >> 3;
    int tid = threadIdx.x;
    int v0 = chunk * 128;
    int vend = min(v0 + 128, n);
    int ebeg_b = rowptr[v0];
    int eend_b = rowptr[vend];
    int v = v0 + (tid >> 1);
    int t = tid & 1;
    int beg = 0, end = 0;
    if (v < n) { beg = rowptr[v]; end = rowptr[v + 1]; }
    const uint4* X4 = reinterpret_cast<const uint4*>(Xs + (size_t)sl * n * 16);
    float s0 = 0.f, s1 = 0.f, s2 = 0.f, s3 = 0.f, s4 = 0.f, s5 = 0.f, s6 = 0.f, s7 = 0.f;

    for (int base = ebeg_b; base < eend_b; base += ECH) {
        int cnt = min(ECH, eend_b - base);
        __syncthreads();
        for (int i = tid; i < cnt; i += 256) eidx[i] = csr[base + i];
        __syncthreads();
        int lo = max(beg, base) - base;
        int hi = min(end, base + cnt) - base;
        int e = lo;
        for (; e + 8 <= hi; e += 8) {
            uint4 a0 = X4[(size_t)eidx[e + 0] * 2 + t];
            uint4 a1 = X4[(size_t)eidx[e + 1] * 2 + t];
            uint4 a2 = X4[(size_t)eidx[e + 2] * 2 + t];
            uint4 a3 = X4[(size_t)eidx[e + 3] * 2 + t];
            uint4 a4 = X4[(size_t)eidx[e + 4] * 2 + t];
            uint4 a5 = X4[(size_t)eidx[e + 5] * 2 + t];
            uint4 a6 = X4[(size_t)eidx[e + 6] * 2 + t];
            uint4 a7 = X4[(size_t)eidx[e + 7] * 2 + t];
            s0 += blo(a0.x) + blo(a1.x) + blo(a2.x) + blo(a3.x) + blo(a4.x) + blo(a5.x) + blo(a6.x) + blo(a7.x);
            s1 += bhi(a0.x) + bhi(a1.x) + bhi(a2.x) + bhi(a3.x) + bhi(a4.x) + bhi(a5.x) + bhi(a6.x) + bhi(a7.x);
            s2 += blo(a0.y) + blo(a1.y) + blo(a2.y) + blo(a3.y) + blo(a4.y) + blo(a5.y) + blo(a6.y) + blo(a7.y);
            s3 += bhi(a0.y) + bhi(a1.y) + bhi(a2.y) + bhi(a3.y) + bhi(a4.y) + bhi(a5.y) + bhi(a6.y) + bhi(a7.y);
            s4 += blo(a0.z) + blo(a1.z) + blo(a2.z) + blo(a3.z) + blo(a4.z) + blo(a5.z) + blo(a6.z) + blo(a7.z);
            s5 += bhi(a0.z) + bhi(a1.z) + bhi(a2.z) + bhi(a3.z) + bhi(a4.z) + bhi(a5.z) + bhi(a6.z) + bhi(a7.z);
            s6 += blo(a0.w) + blo(a1.w) + blo(a2.w) + blo(a3.w) + blo(a4.w) + blo(a5.w) + blo(a6.w) + blo(a7.w);
            s7 += bhi(a0.w) + bhi(a1.w) + bhi(a2.w) + bhi(a3.w) + bhi(a4.w) + bhi(a5.w) + bhi(a6.w) + bhi(a7.w);
        }
        if (e + 4 <= hi) {
            uint4 a0 = X4[(size_t)eidx[e + 0] * 2 + t];
            uint4 a1 = X4[(size_t)eidx[e + 1] * 2 + t];
            uint4 a2 = X4[(size_t)eidx[e + 2] * 2 + t];
            uint4 a3 = X4[(size_t)eidx[e + 3] * 2 + t];
            s0 += blo(a0.x) + blo(a1.x) + blo(a2.x) + blo(a3.x);
            s1 += bhi(a0.x) + bhi(a1.x) + bhi(a2.x) + bhi(a3.x);
            s2 += blo(a0.y) + blo(a1.y) + blo(a2.y) + blo(a3.y);
            s3 += bhi(a0.y) + bhi(a1.y) + bhi(a2.y) + bhi(a3.y);
            s4 += blo(a0.z) + blo(a1.z) + blo(a2.z) + blo(a3.z);
            s5 += bhi(a0.z) + bhi(a1.z) + bhi(a2.z) + bhi(a3.z);
            s6 += blo(a0.w) + blo(a1.w) + blo(a2.w) + blo(a3.w);
            s7 += bhi(a0.w) + bhi(a1.w) + bhi(a2.w) + bhi(a3.w);
            e += 4;
        }
        for (; e < hi; ++e) {
            uint4 a = X4[(size_t)eidx[e] * 2 + t];
            s0 += blo(a.x); s1 += bhi(a.x);
            s2 += blo(a.y); s3 += bhi(a.y);
            s4 += blo(a.z); s5 += bhi(a.z);
            s6 += blo(a.w); s7 += bhi(a.w);
        }
    }

    if (v < n) {
        float di = degInv[v];
        uint4 o;
        o.x = pack2(s0 * di, s1 * di);
        o.y = pack2(s2 * di, s3 * di);
        o.z = pack2(s4 * di, s5 * di);
        o.w = pack2(s6 * di, s7 * di);
        reinterpret_cast<uint4*>(As + (size_t)sl * n * 16)[(size_t)v * 2 + t] = o;
    }
}

// ---------------- MFMA dual-GEMM + affine-BN + ReLU, DOUT=128, K=256 ----------------
__global__ __launch_bounds__(256) void gemm128_kernel(
    const unsigned short* __restrict__ A0, const unsigned short* __restrict__ A1,
    const unsigned short* __restrict__ Wsw,
    const float* __restrict__ scaleA, const float* __restrict__ biasB,
    unsigned short* __restrict__ OUT, int n) {
    int tid = threadIdx.x;
    int lane = tid & 63;
    int wave = tid >> 6;
    int wr = wave >> 1, wc = wave & 1;
    int row0 = blockIdx.x * 64 + wr * 32;
    int rlo = lane & 15, kq = lane >> 4;

    f32x4 acc[2][4];
#pragma unroll
    for (int rt = 0; rt < 2; ++rt)
#pragma unroll
        for (int c4 = 0; c4 < 4; ++c4)
#pragma unroll
            for (int k = 0; k < 4; ++k) acc[rt][c4][k] = 0.f;

    int r0 = row0 + rlo;
    int r1 = row0 + 16 + rlo;

    for (int kt = 0; kt < 8; ++kt) {
        const unsigned short* Aarr = (kt < 4) ? A0 : A1;
        int kb = (kt & 3) * 32 + kq * 8;
        int sl = kb >> 4;
        int rem = kb & 8;
        const unsigned short* base = Aarr + (size_t)sl * n * 16 + rem;
        bf16x8 a0, a1;
#pragma unroll
        for (int i = 0; i < 8; ++i) { a0[i] = (__bf16)0.f; a1[i] = (__bf16)0.f; }
        if (r0 < n) a0 = *reinterpret_cast<const bf16x8*>(base + (size_t)r0 * 16);
        if (r1 < n) a1 = *reinterpret_cast<const bf16x8*>(base + (size_t)r1 * 16);
#pragma unroll
        for (int c4 = 0; c4 < 4; ++c4) {
            int ct = wc * 4 + c4;
            bf16x8 b = *reinterpret_cast<const bf16x8*>(Wsw + ((size_t)(kt * 8 + ct) * 64 + lane) * 8);
            acc[0][c4] = __builtin_amdgcn_mfma_f32_16x16x32_bf16(a0, b, acc[0][c4], 0, 0, 0);
            acc[1][c4] = __builtin_amdgcn_mfma_f32_16x16x32_bf16(a1, b, acc[1][c4], 0, 0, 0);
        }
    }

#pragma unroll
    for (int rt = 0; rt < 2; ++rt)
#pragma unroll
        for (int c4 = 0; c4 < 4; ++c4) {
            int col = wc * 64 + c4 * 16 + rlo;
            int sl = col >> 4;
            float sA = scaleA[col];
            float sB = biasB[col];
#pragma unroll
            for (int i = 0; i < 4; ++i) {
                int r = row0 + rt * 16 + kq * 4 + i;
                if (r < n) {
                    float y = fmaxf(acc[rt][c4][i] * sA + sB, 0.f);
                    OUT[(size_t)sl * n * 16 + (size_t)r * 16 + rlo] = (unsigned short)bf1(y);
                }
            }
        }
}

// ---------------- layer 2: H@Wl2 -> tmpL (bf16 row-major), H@Wr2 + bl2 -> tmpR (f32) ----------------
__global__ __launch_bounds__(256) void dual64_kernel(
    const unsigned short* __restrict__ H,
    const unsigned short* __restrict__ WswL, const unsigned short* __restrict__ WswR,
    const float* __restrict__ bl,
    unsigned short* __restrict__ tmpL, float* __restrict__ tmpR, int n) {
    int tid = threadIdx.x;
    int lane = tid & 63;
    int wave = tid >> 6;
    int wr = wave >> 1, wc = wave & 1;
    int row0 = blockIdx.x * 64 + wr * 32;
    int rlo = lane & 15, kq = lane >> 4;

    f32x4 aL[2][2], aR[2][2];
#pragma unroll
    for (int rt = 0; rt < 2; ++rt)
#pragma unroll
        for (int c2 = 0; c2 < 2; ++c2)
#pragma unroll
            for (int k = 0; k < 4; ++k) { aL[rt][c2][k] = 0.f; aR[rt][c2][k] = 0.f; }

    int r0 = row0 + rlo;
    int r1 = row0 + 16 + rlo;

    for (int kt = 0; kt < 4; ++kt) {
        int kb = kt * 32 + kq * 8;
        int sl = kb >> 4;
        int rem = kb & 8;
        const unsigned short* base = H + (size_t)sl * n * 16 + rem;
        bf16x8 a0, a1;
#pragma unroll
        for (int i = 0; i < 8; ++i) { a0[i] = (__bf16)0.f; a1[i] = (__bf16)0.f; }
        if (r0 < n) a0 = *reinterpret_cast<const bf16x8*>(base + (size_t)r0 * 16);
        if (r1 < n) a1 = *reinterpret_cast<const bf16x8*>(base + (size_t)r1 * 16);
#pragma unroll
        for (int c2 = 0; c2 < 2; ++c2) {
            int ct = wc * 2 + c2;
            bf16x8 bL = *reinterpret_cast<const bf16x8*>(WswL + ((size_t)(kt * 4 + ct) * 64 + lane) * 8);
            bf16x8 bR = *reinterpret_cast<const bf16x8*>(WswR + ((size_t)(kt * 4 + ct) * 64 + lane) * 8);
            aL[0][c2] = __builtin_amdgcn_mfma_f32_16x16x32_bf16(a0, bL, aL[0][c2], 0, 0, 0);
            aL[1][c2] = __builtin_amdgcn_mfma_f32_16x16x32_bf16(a1, bL, aL[1][c2], 0, 0, 0);
            aR[0][c2] = __builtin_amdgcn_mfma_f32_16x16x32_bf16(a0, bR, aR[0][c2], 0, 0, 0);
            aR[1][c2] = __builtin_amdgcn_mfma_f32_16x16x32_bf16(a1, bR, aR[1][c2], 0, 0, 0);
        }
    }

#pragma unroll
    for (int rt = 0; rt < 2; ++rt)
#pragma unroll
        for (int c2 = 0; c2 < 2; ++c2) {
            int col = wc * 32 + c2 * 16 + rlo;
            float bv = bl[col];
#pragma unroll
            for (int i = 0; i < 4; ++i) {
                int r = row0 + rt * 16 + kq * 4 + i;
                if (r < n) {
                    tmpL[(size_t)r * 64 + col] = (unsigned short)bf1(aL[rt][c2][i]);
                    tmpR[(size_t)r * 64 + col] = aR[rt][c2][i] + bv;
                }
            }
        }
}

// ---------------- final: out = log_softmax( mean-agg(tmpL) + tmpR ) ----------------
// 8 lanes/node, 16 B (uint4 = 8 bf16 cols) per lane; x4 unrolled gathers.
__global__ void agg64_lsm_kernel(const unsigned short* __restrict__ tmpL,
                                 const float* __restrict__ tmpR,
                                 const int* __restrict__ rowptr, const int* __restrict__ csr,
                                 const float* __restrict__ degInv,
                                 float* __restrict__ out, int n) {
    int idx = blockIdx.x * blockDim.x + threadIdx.x;
    int v = idx >> 3;
    int t = idx & 7;
    if (v >= n) return;
    int beg = rowptr[v], end = rowptr[v + 1];
    const uint4* L4 = reinterpret_cast<const uint4*>(tmpL);
    float s0 = 0.f, s1 = 0.f, s2 = 0.f, s3 = 0.f, s4 = 0.f, s5 = 0.f, s6 = 0.f, s7 = 0.f;
    int e = beg;
    for (; e + 4 <= end; e += 4) {
        uint4 a0 = L4[(size_t)csr[e + 0] * 8 + t];
        uint4 a1 = L4[(size_t)csr[e + 1] * 8 + t];
        uint4 a2 = L4[(size_t)csr[e + 2] * 8 + t];
        uint4 a3 = L4[(size_t)csr[e + 3] * 8 + t];
        s0 += blo(a0.x) + blo(a1.x) + blo(a2.x) + blo(a3.x);
        s1 += bhi(a0.x) + bhi(a1.x) + bhi(a2.x) + bhi(a3.x);
        s2 += blo(a0.y) + blo(a1.y) + blo(a2.y) + blo(a3.y);
        s3 += bhi(a0.y) + bhi(a1.y) + bhi(a2.y) + bhi(a3.y);
        s4 += blo(a0.z) + blo(a1.z) + blo(a2.z) + blo(a3.z);
        s5 += bhi(a0.z) + bhi(a1.z) + bhi(a2.z) + bhi(a3.z);
        s6 += blo(a0.w) + blo(a1.w) + blo(a2.w) + blo(a3.w);
        s7 += bhi(a0.w) + bhi(a1.w) + bhi(a2.w) + bhi(a3.w);
    }
    for (; e < end; ++e) {
        uint4 a = L4[(size_t)csr[e] * 8 + t];
        s0 += blo(a.x); s1 += bhi(a.x);
        s2 += blo(a.y); s3 += bhi(a.y);
        s4 += blo(a.z); s5 += bhi(a.z);
        s6 += blo(a.w); s7 += bhi(a.w);
    }
    float di = degInv[v];
    const float4* R4 = reinterpret_cast<const float4*>(tmpR + (size_t)v * 64 + t * 8);
    float4 rA = R4[0], rB = R4[1];
    float y0 = s0 * di + rA.x;
    float y1 = s1 * di + rA.y;
    float y2 = s2 * di + rA.z;
    float y3 = s3 * di + rA.w;
    float y4 = s4 * di + rB.x;
    float y5 = s5 * di + rB.y;
    float y6 = s6 * di + rB.z;
    float y7 = s7 * di + rB.w;

    float mx = fmaxf(fmaxf(fmaxf(y0, y1), fmaxf(y2, y3)),
                     fmaxf(fmaxf(y4, y5), fmaxf(y6, y7)));
#pragma unroll
    for (int o = 1; o < 8; o <<= 1) mx = fmaxf(mx, __shfl_xor(mx, o));
    float s = __expf(y0 - mx) + __expf(y1 - mx) + __expf(y2 - mx) + __expf(y3 - mx)
            + __expf(y4 - mx) + __expf(y5 - mx) + __expf(y6 - mx) + __expf(y7 - mx);
#pragma unroll
    for (int o = 1; o < 8; o <<= 1) s += __shfl_xor(s, o);
    float lse = mx + __logf(s);

    float4 oA, oB;
    oA.x = y0 - lse; oA.y = y1 - lse; oA.z = y2 - lse; oA.w = y3 - lse;
    oB.x = y4 - lse; oB.y = y5 - lse; oB.z = y6 - lse; oB.w = y7 - lse;
    float4* O4 = reinterpret_cast<float4*>(out + (size_t)v * 64 + t * 8);
    O4[0] = oA;
    O4[1] = oB;
}

// ---------------- launch ----------------

extern "C" void kernel_launch(void* const* d_in, const int* in_sizes, int n_in,
                              void* d_out, int out_size, void* d_ws, size_t ws_size,
                              hipStream_t stream) {
    const float* x   = (const float*)d_in[0];
    const int*   ei  = (const int*)d_in[1];
    const float* Wl0 = (const float*)d_in[2];
    const float* bl0 = (const float*)d_in[3];
    const float* Wr0 = (const float*)d_in[4];
    const float* g0  = (const float*)d_in[5];
    const float* b0  = (const float*)d_in[6];
    const float* m0  = (const float*)d_in[7];
    const float* v0  = (const float*)d_in[8];
    const float* Wl1 = (const float*)d_in[9];
    const float* bl1 = (const float*)d_in[10];
    const float* Wr1 = (const float*)d_in[11];
    const float* g1  = (const float*)d_in[12];
    const float* b1  = (const float*)d_in[13];
    const float* m1  = (const float*)d_in[14];
    const float* v1  = (const float*)d_in[15];
    const float* Wl2 = (const float*)d_in[16];
    const float* bl2 = (const float*)d_in[17];
    const float* Wr2 = (const float*)d_in[18];
    float* out = (float*)d_out;

    const int N = in_sizes[0] / 128;
    const int E = in_sizes[1] / 2;
    const int B = (N + NPB - 1) >> NPB_LOG;
    const int* src = ei;
    const int* dst = ei + E;

    char* ws = (char*)d_ws;
    size_t off = 0;
    auto alloc = [&](size_t bytes) -> void* {
        void* p = ws + off;
        off += (bytes + 255) & ~(size_t)255;
        return p;
    };
    int*   bcnt    = (int*)alloc(256 * 4);
    int*   bstart  = (int*)alloc(257 * 4);
    int*   cursorB = (int*)alloc(256 * 4);
    int*   rowptr  = (int*)alloc((size_t)(N + 1) * 4);
    float* degInv  = (float*)alloc((size_t)N * 4);
    int*   csr     = (int*)alloc((size_t)E * 4);
    unsigned* ebuf = (unsigned*)alloc((size_t)E * 4);
    unsigned short* x16   = (unsigned short*)alloc((size_t)N * 128 * 2);  // [8][N][16]
    unsigned short* agg16 = (unsigned short*)alloc((size_t)N * 128 * 2);  // [8][N][16]
    unsigned short* hA16  = (unsigned short*)alloc((size_t)N * 128 * 2);  // [8][N][16]
    unsigned short* hB16  = (unsigned short*)alloc((size_t)N * 128 * 2);  // [8][N][16]
    unsigned short* tmpL  = (unsigned short*)alloc((size_t)N * 64 * 2);   // row-major
    float* tmpR  = (float*)alloc((size_t)N * 64 * 4);                     // row-major
    unsigned short* Wsw0  = (unsigned short*)alloc(8 * 8 * 64 * 8 * 2);
    unsigned short* Wsw1  = (unsigned short*)alloc(8 * 8 * 64 * 8 * 2);
    unsigned short* WswL2 = (unsigned short*)alloc(4 * 4 * 64 * 8 * 2);
    unsigned short* WswR2 = (unsigned short*)alloc(4 * 4 * 64 * 8 * 2);
    float* bnA0 = (float*)alloc(128 * 4);
    float* bnB0 = (float*)alloc(128 * 4);
    float* bnA1 = (float*)alloc(128 * 4);
    float* bnB1 = (float*)alloc(128 * 4);

    hipMemsetAsync(bcnt, 0, 256 * 4, stream);

    // CSR build
    bucket_hist_kernel<<<512, 256, 0, stream>>>(dst, bcnt, E, B);
    bucket_scan_kernel<<<1, 256, 0, stream>>>(bcnt, bstart, cursorB, B, E);
    partition_kernel<<<(E + 4095) / 4096, 256, 0, stream>>>(src, dst, cursorB, ebuf, E, B);
    build_csr_kernel<<<B, 256, 0, stream>>>(ebuf, bstart, rowptr, degInv, csr, N, B);

    // prep: x -> bf16 slice-major, weight swizzles, BN folds
    cvt_slices_kernel<<<(N * 8 + 255) / 256, 256, 0, stream>>>(x, x16, N);
    swizzleW_kernel<<<16, 256, 0, stream>>>(Wl0, Wr0, Wsw0, 128, 256, 128);
    swizzleW_kernel<<<16, 256, 0, stream>>>(Wl1, Wr1, Wsw1, 128, 256, 128);
    swizzleW_kernel<<<4, 256, 0, stream>>>(Wl2, nullptr, WswL2, 128, 128, 64);
    swizzleW_kernel<<<4, 256, 0, stream>>>(Wr2, nullptr, WswR2, 128, 128, 64);
    bnprep_kernel<<<1, 128, 0, stream>>>(bl0, g0, b0, m0, v0, bnA0, bnB0, 128);
    bnprep_kernel<<<1, 128, 0, stream>>>(bl1, g1, b1, m1, v1, bnA1, bnB1, 128);

    int aggGridS = 8 * ((N + 127) / 128);
    int gemmGrid = (N + 63) / 64;

    // layer 0
    aggregate_sliced_kernel<<<aggGridS, 256, 0, stream>>>(x16, rowptr, csr, degInv, agg16, N);
    gemm128_kernel<<<gemmGrid, 256, 0, stream>>>(agg16, x16, Wsw0, bnA0, bnB0, hA16, N);
    // layer 1
    aggregate_sliced_kernel<<<aggGridS, 256, 0, stream>>>(hA16, rowptr, csr, degInv, agg16, N);
    gemm128_kernel<<<gemmGrid, 256, 0, stream>>>(agg16, hA16, Wsw1, bnA1, bnB1, hB16, N);
    // layer 2: transform-then-aggregate + fused log_softmax
    dual64_kernel<<<gemmGrid, 256, 0, stream>>>(hB16, WswL2, WswR2, bl2, tmpL, tmpR, N);
    agg64_lsm_kernel<<<(int)(((size_t)N * 8 + 255) / 256), 256, 0, stream>>>(
        tmpL, tmpR, rowptr, csr, degInv, out, N);
}

// Round 8
// 301.067 us; speedup vs baseline: 1.2959x; 1.1262x over previous
//
#include <hip/hip_runtime.h>

constexpr float EPS = 1e-5f;

#define NPB_LOG 9
#define NPB 512

typedef __attribute__((ext_vector_type(8))) __bf16 bf16x8;
typedef __attribute__((ext_vector_type(4))) float f32x4;
typedef __attribute__((ext_vector_type(2))) float f32x2;

// ---------- bf16 helpers ----------
__device__ __forceinline__ float blo(unsigned u) { return __uint_as_float(u << 16); }
__device__ __forceinline__ float bhi(unsigned u) { return __uint_as_float(u & 0xffff0000u); }
__device__ __forceinline__ unsigned bf1(float f) {
    unsigned u = __float_as_uint(f);
    return (u + 0x7fffu + ((u >> 16) & 1u)) >> 16;
}
__device__ __forceinline__ unsigned pack2(float a, float b) { return bf1(a) | (bf1(b) << 16); }

// ---------- fp8 helpers (HW cvt, self-consistent encode/decode) ----------
__device__ __forceinline__ f32x2 fp8lo(unsigned w) {
    return __builtin_amdgcn_cvt_pk_f32_fp8(w, false);
}
__device__ __forceinline__ f32x2 fp8hi(unsigned w) {
    return __builtin_amdgcn_cvt_pk_f32_fp8(w, true);
}

// ---------------- CSR build (locality-aware) ----------------

__global__ void bucket_hist_kernel(const int* __restrict__ dst, int* __restrict__ bcnt,
                                   int E, int B) {
    __shared__ int h[256];
    int t = threadIdx.x;
    h[t] = 0;
    __syncthreads();
    for (int e = blockIdx.x * blockDim.x + t; e < E; e += gridDim.x * blockDim.x)
        atomicAdd(&h[dst[e] >> NPB_LOG], 1);
    __syncthreads();
    if (t < B && h[t]) atomicAdd(&bcnt[t], h[t]);
}

__global__ void bucket_scan_kernel(const int* __restrict__ bcnt, int* __restrict__ bstart,
                                   int* __restrict__ cursorB, int B, int E) {
    __shared__ int tmp[256];
    int t = threadIdx.x;
    int v = (t < B) ? bcnt[t] : 0;
    tmp[t] = v;
    __syncthreads();
    for (int off = 1; off < 256; off <<= 1) {
        int x = tmp[t];
        if (t >= off) x += tmp[t - off];
        __syncthreads();
        tmp[t] = x;
        __syncthreads();
    }
    if (t < B) {
        int ex = tmp[t] - v;
        bstart[t] = ex;
        cursorB[t] = ex;
    }
    if (t == 0) bstart[B] = E;
}

__global__ __launch_bounds__(256) void partition_kernel(
    const int* __restrict__ src, const int* __restrict__ dst,
    int* __restrict__ cursorB, unsigned* __restrict__ ebuf, int E, int B) {
    __shared__ int hist[256];
    __shared__ int base[256];
    int t = threadIdx.x;
    hist[t] = 0;
    __syncthreads();
    int e0 = blockIdx.x * 4096;
    int e1 = min(e0 + 4096, E);
    for (int e = e0 + t; e < e1; e += 256)
        atomicAdd(&hist[dst[e] >> NPB_LOG], 1);
    __syncthreads();
    int h = hist[t];
    if (t < B && h) base[t] = atomicAdd(&cursorB[t], h);
    __syncthreads();
    hist[t] = 0;
    __syncthreads();
    for (int e = e0 + t; e < e1; e += 256) {
        int d = dst[e];
        int b = d >> NPB_LOG;
        int off = atomicAdd(&hist[b], 1);
        ebuf[base[b] + off] = ((unsigned)src[e] << NPB_LOG) | (unsigned)(d & (NPB - 1));
    }
}

__global__ __launch_bounds__(256) void build_csr_kernel(
    const unsigned* __restrict__ ebuf, const int* __restrict__ bstart,
    int* __restrict__ rowptr, float* __restrict__ degInv, int* __restrict__ csr,
    int N, int B) {
    __shared__ int cnt[NPB];
    __shared__ int cur[NPB];
    __shared__ int ps[256];
    int b = blockIdx.x;
    int t = threadIdx.x;
    int nbase = b << NPB_LOG;
    int nn = min(NPB, N - nbase);
    cnt[t] = 0;
    cnt[t + 256] = 0;
    __syncthreads();
    int ebeg = bstart[b], eend = bstart[b + 1];
    for (int e = ebeg + t; e < eend; e += 256)
        atomicAdd(&cnt[ebuf[e] & (NPB - 1)], 1);
    __syncthreads();
    int c0 = cnt[2 * t], c1 = cnt[2 * t + 1];
    int pair = c0 + c1;
    ps[t] = pair;
    __syncthreads();
    for (int off = 1; off < 256; off <<= 1) {
        int x = ps[t];
        if (t >= off) x += ps[t - off];
        __syncthreads();
        ps[t] = x;
        __syncthreads();
    }
    int exPair = ps[t] - pair;
    int g0 = ebeg + exPair;
    int g1 = g0 + c0;
    cur[2 * t] = g0;
    cur[2 * t + 1] = g1;
    if (2 * t < nn) {
        rowptr[nbase + 2 * t] = g0;
        degInv[nbase + 2 * t] = 1.0f / (float)max(c0, 1);
    }
    if (2 * t + 1 < nn) {
        rowptr[nbase + 2 * t + 1] = g1;
        degInv[nbase + 2 * t + 1] = 1.0f / (float)max(c1, 1);
    }
    if (b == B - 1 && t == 0) rowptr[N] = eend;
    __syncthreads();
    for (int e = ebeg + t; e < eend; e += 256) {
        unsigned p = ebuf[e];
        int pos = atomicAdd(&cur[p & (NPB - 1)], 1);
        csr[pos] = (int)(p >> NPB_LOG);
    }
}

// ---------------- f32 -> bf16 row-major conversion ----------------
__global__ void cvt_bf16_kernel(const float* __restrict__ in, unsigned short* __restrict__ out,
                                int n4) {
    int i = blockIdx.x * blockDim.x + threadIdx.x;
    if (i < n4) {
        float4 v = reinterpret_cast<const float4*>(in)[i];
        uint2 o;
        o.x = pack2(v.x, v.y);
        o.y = pack2(v.z, v.w);
        reinterpret_cast<uint2*>(out)[i] = o;
    }
}

// ---------------- weight swizzle: [Wl | Wr] horizontal concat, MFMA frag order ----------------
// out[kt][ct][lane][8]; k = kt*32 + (lane>>4)*8 + i; col = ct*16 + (lane&15).
__global__ void swizzleWcat_kernel(const float* __restrict__ Wl, const float* __restrict__ Wr,
                                   unsigned short* __restrict__ out, int K, int CL, int CR) {
    int C = CL + CR;
    int CT = C >> 4;
    int total = (K >> 5) * CT * 64;
    int id = blockIdx.x * blockDim.x + threadIdx.x;
    if (id >= total) return;
    int lane = id & 63;
    int ctkt = id >> 6;
    int ct = ctkt % CT;
    int kt = ctkt / CT;
    int col = ct * 16 + (lane & 15);
    int k0 = kt * 32 + (lane >> 4) * 8;
#pragma unroll
    for (int i = 0; i < 8; ++i) {
        int k = k0 + i;
        float w = (col < CL) ? Wl[(size_t)k * CL + col] : Wr[(size_t)k * CR + (col - CL)];
        out[(size_t)id * 8 + i] = (unsigned short)bf1(w);
    }
}

// ---------------- BN fold: h = bnA*z + bnB (z = agg + tR; bl lives in tR) ----------------
__global__ void bnprep_kernel(const float* __restrict__ g, const float* __restrict__ b,
                              const float* __restrict__ m, const float* __restrict__ v,
                              float* __restrict__ bnA, float* __restrict__ bnB, int D) {
    int c = blockIdx.x * blockDim.x + threadIdx.x;
    if (c < D) {
        float A = g[c] * rsqrtf(v[c] + EPS);
        bnA[c] = A;
        bnB[c] = b[c] - m[c] * A;
    }
}

// ---------------- MFMA GEMM: [tL | tR] = A @ [Wl | Wr]; tL -> fp8, tR -> (+bl) bf16/f32 ----------------
// A bf16 row-major [n][128], K=128. Block = 64 rows x 2*CHALF cols, 4 waves 2x2.
// wc=0 waves produce tL (fp8), wc=1 produce tR.
template <int CHALF, bool R32>
__global__ __launch_bounds__(256) void gemmT_kernel(
    const unsigned short* __restrict__ A, const unsigned short* __restrict__ Wsw,
    const float* __restrict__ bl,
    unsigned char* __restrict__ tL, void* __restrict__ tRv, int n) {
    constexpr int CT = CHALF / 16;
    int tid = threadIdx.x;
    int lane = tid & 63;
    int wave = tid >> 6;
    int wr = wave >> 1, wc = wave & 1;
    int row0 = blockIdx.x * 64 + wr * 32;
    int rlo = lane & 15, kq = lane >> 4;

    f32x4 acc[2][CT];
#pragma unroll
    for (int rt = 0; rt < 2; ++rt)
#pragma unroll
        for (int c = 0; c < CT; ++c)
#pragma unroll
            for (int k = 0; k < 4; ++k) acc[rt][c][k] = 0.f;

    int r0 = row0 + rlo;
    int r1 = row0 + 16 + rlo;

    for (int kt = 0; kt < 4; ++kt) {
        int kb = kt * 32 + kq * 8;
        bf16x8 a0, a1;
#pragma unroll
        for (int i = 0; i < 8; ++i) { a0[i] = (__bf16)0.f; a1[i] = (__bf16)0.f; }
        if (r0 < n) a0 = *reinterpret_cast<const bf16x8*>(A + (size_t)r0 * 128 + kb);
        if (r1 < n) a1 = *reinterpret_cast<const bf16x8*>(A + (size_t)r1 * 128 + kb);
#pragma unroll
        for (int c = 0; c < CT; ++c) {
            int ct_g = wc * CT + c;
            bf16x8 b = *reinterpret_cast<const bf16x8*>(Wsw + ((size_t)(kt * 2 * CT + ct_g) * 64 + lane) * 8);
            acc[0][c] = __builtin_amdgcn_mfma_f32_16x16x32_bf16(a0, b, acc[0][c], 0, 0, 0);
            acc[1][c] = __builtin_amdgcn_mfma_f32_16x16x32_bf16(a1, b, acc[1][c], 0, 0, 0);
        }
    }

#pragma unroll
    for (int rt = 0; rt < 2; ++rt)
#pragma unroll
        for (int c = 0; c < CT; ++c) {
            int col = c * 16 + rlo;   // within half
            if (wc == 0) {
                // rows i=0..3 -> bytes 0..3 of one packed word
                unsigned w = __builtin_amdgcn_cvt_pk_fp8_f32(acc[rt][c][0], acc[rt][c][1], 0, false);
                w = __builtin_amdgcn_cvt_pk_fp8_f32(acc[rt][c][2], acc[rt][c][3], w, true);
#pragma unroll
                for (int i = 0; i < 4; ++i) {
                    int r = row0 + rt * 16 + kq * 4 + i;
                    if (r < n) tL[(size_t)r * CHALF + col] = (unsigned char)((w >> (8 * i)) & 0xffu);
                }
            } else {
                float bv = bl[col];
#pragma unroll
                for (int i = 0; i < 4; ++i) {
                    int r = row0 + rt * 16 + kq * 4 + i;
                    if (r < n) {
                        float y = acc[rt][c][i] + bv;
                        if (R32) reinterpret_cast<float*>(tRv)[(size_t)r * CHALF + col] = y;
                        else reinterpret_cast<unsigned short*>(tRv)[(size_t)r * CHALF + col] = (unsigned short)bf1(y);
                    }
                }
            }
        }
}

// ---------------- aggregate fp8 tL (128-B rows) + tR + BN + ReLU -> h bf16 ----------------
// 16 lanes/node, 8 B (8 fp8 cols) per lane, x4 unrolled independent gathers.
__global__ void aggbn_kernel(const unsigned char* __restrict__ tL,
                             const unsigned short* __restrict__ tR,
                             const float* __restrict__ bnA, const float* __restrict__ bnB,
                             const int* __restrict__ rowptr, const int* __restrict__ csr,
                             const float* __restrict__ degInv,
                             unsigned short* __restrict__ h, int n) {
    int idx = blockIdx.x * blockDim.x + threadIdx.x;
    int v = idx >> 4;
    int t = idx & 15;
    if (v >= n) return;
    int beg = rowptr[v], end = rowptr[v + 1];
    const uint2* T2 = reinterpret_cast<const uint2*>(tL);
    float s0 = 0.f, s1 = 0.f, s2 = 0.f, s3 = 0.f, s4 = 0.f, s5 = 0.f, s6 = 0.f, s7 = 0.f;
    int e = beg;
    for (; e + 4 <= end; e += 4) {
        uint2 w0 = T2[(size_t)csr[e + 0] * 16 + t];
        uint2 w1 = T2[(size_t)csr[e + 1] * 16 + t];
        uint2 w2 = T2[(size_t)csr[e + 2] * 16 + t];
        uint2 w3 = T2[(size_t)csr[e + 3] * 16 + t];
        f32x2 p;
        p = fp8lo(w0.x); s0 += p[0]; s1 += p[1];
        p = fp8hi(w0.x); s2 += p[0]; s3 += p[1];
        p = fp8lo(w0.y); s4 += p[0]; s5 += p[1];
        p = fp8hi(w0.y); s6 += p[0]; s7 += p[1];
        p = fp8lo(w1.x); s0 += p[0]; s1 += p[1];
        p = fp8hi(w1.x); s2 += p[0]; s3 += p[1];
        p = fp8lo(w1.y); s4 += p[0]; s5 += p[1];
        p = fp8hi(w1.y); s6 += p[0]; s7 += p[1];
        p = fp8lo(w2.x); s0 += p[0]; s1 += p[1];
        p = fp8hi(w2.x); s2 += p[0]; s3 += p[1];
        p = fp8lo(w2.y); s4 += p[0]; s5 += p[1];
        p = fp8hi(w2.y); s6 += p[0]; s7 += p[1];
        p = fp8lo(w3.x); s0 += p[0]; s1 += p[1];
        p = fp8hi(w3.x); s2 += p[0]; s3 += p[1];
        p = fp8lo(w3.y); s4 += p[0]; s5 += p[1];
        p = fp8hi(w3.y); s6 += p[0]; s7 += p[1];
    }
    for (; e < end; ++e) {
        uint2 w = T2[(size_t)csr[e] * 16 + t];
        f32x2 p;
        p = fp8lo(w.x); s0 += p[0]; s1 += p[1];
        p = fp8hi(w.x); s2 += p[0]; s3 += p[1];
        p = fp8lo(w.y); s4 += p[0]; s5 += p[1];
        p = fp8hi(w.y); s6 += p[0]; s7 += p[1];
    }
    float di = degInv[v];
    uint4 rw = reinterpret_cast<const uint4*>(tR)[(size_t)v * 16 + t];
    float4 A0 = reinterpret_cast<const float4*>(bnA + t * 8)[0];
    float4 A1 = reinterpret_cast<const float4*>(bnA + t * 8)[1];
    float4 B0 = reinterpret_cast<const float4*>(bnB + t * 8)[0];
    float4 B1 = reinterpret_cast<const float4*>(bnB + t * 8)[1];
    float h0 = fmaxf(A0.x * (s0 * di + blo(rw.x)) + B0.x, 0.f);
    float h1 = fmaxf(A0.y * (s1 * di + bhi(rw.x)) + B0.y, 0.f);
    float h2 = fmaxf(A0.z * (s2 * di + blo(rw.y)) + B0.z, 0.f);
    float h3 = fmaxf(A0.w * (s3 * di + bhi(rw.y)) + B0.w, 0.f);
    float h4 = fmaxf(A1.x * (s4 * di + blo(rw.z)) + B1.x, 0.f);
    float h5 = fmaxf(A1.y * (s5 * di + bhi(rw.z)) + B1.y, 0.f);
    float h6 = fmaxf(A1.z * (s6 * di + blo(rw.w)) + B1.z, 0.f);
    float h7 = fmaxf(A1.w * (s7 * di + bhi(rw.w)) + B1.w, 0.f);
    uint4 o;
    o.x = pack2(h0, h1);
    o.y = pack2(h2, h3);
    o.z = pack2(h4, h5);
    o.w = pack2(h6, h7);
    reinterpret_cast<uint4*>(h)[(size_t)v * 16 + t] = o;
}

// ---------------- final: out = log_softmax( mean-agg(tL2 fp8) + tR2 ) ----------------
// 8 lanes/node, 8 B (8 fp8 cols) per lane, x4 unrolled.
__global__ void agg64_lsm_kernel(const unsigned char* __restrict__ tL2,
                                 const float* __restrict__ tR2,
                                 const int* __restrict__ rowptr, const int* __restrict__ csr,
                                 const float* __restrict__ degInv,
                                 float* __restrict__ out, int n) {
    int idx = blockIdx.x * blockDim.x + threadIdx.x;
    int v = idx >> 3;
    int t = idx & 7;
    if (v >= n) return;
    int beg = rowptr[v], end = rowptr[v + 1];
    const uint2* T2 = reinterpret_cast<const uint2*>(tL2);
    float s0 = 0.f, s1 = 0.f, s2 = 0.f, s3 = 0.f, s4 = 0.f, s5 = 0.f, s6 = 0.f, s7 = 0.f;
    int e = beg;
    for (; e + 4 <= end; e += 4) {
        uint2 w0 = T2[(size_t)csr[e + 0] * 8 + t];
        uint2 w1 = T2[(size_t)csr[e + 1] * 8 + t];
        uint2 w2 = T2[(size_t)csr[e + 2] * 8 + t];
        uint2 w3 = T2[(size_t)csr[e + 3] * 8 + t];
        f32x2 p;
        p = fp8lo(w0.x); s0 += p[0]; s1 += p[1];
        p = fp8hi(w0.x); s2 += p[0]; s3 += p[1];
        p = fp8lo(w0.y); s4 += p[0]; s5 += p[1];
        p = fp8hi(w0.y); s6 += p[0]; s7 += p[1];
        p = fp8lo(w1.x); s0 += p[0]; s1 += p[1];
        p = fp8hi(w1.x); s2 += p[0]; s3 += p[1];
        p = fp8lo(w1.y); s4 += p[0]; s5 += p[1];
        p = fp8hi(w1.y); s6 += p[0]; s7 += p[1];
        p = fp8lo(w2.x); s0 += p[0]; s1 += p[1];
        p = fp8hi(w2.x); s2 += p[0]; s3 += p[1];
        p = fp8lo(w2.y); s4 += p[0]; s5 += p[1];
        p = fp8hi(w2.y); s6 += p[0]; s7 += p[1];
        p = fp8lo(w3.x); s0 += p[0]; s1 += p[1];
        p = fp8hi(w3.x); s2 += p[0]; s3 += p[1];
        p = fp8lo(w3.y); s4 += p[0]; s5 += p[1];
        p = fp8hi(w3.y); s6 += p[0]; s7 += p[1];
    }
    for (; e < end; ++e) {
        uint2 w = T2[(size_t)csr[e] * 8 + t];
        f32x2 p;
        p = fp8lo(w.x); s0 += p[0]; s1 += p[1];
        p = fp8hi(w.x); s2 += p[0]; s3 += p[1];
        p = fp8lo(w.y); s4 += p[0]; s5 += p[1];
        p = fp8hi(w.y); s6 += p[0]; s7 += p[1];
    }
    float di = degInv[v];
    float4 rA = reinterpret_cast<const float4*>(tR2 + (size_t)v * 64 + t * 8)[0];
    float4 rB = reinterpret_cast<const float4*>(tR2 + (size_t)v * 64 + t * 8)[1];
    float y0 = s0 * di + rA.x;
    float y1 = s1 * di + rA.y;
    float y2 = s2 * di + rA.z;
    float y3 = s3 * di + rA.w;
    float y4 = s4 * di + rB.x;
    float y5 = s5 * di + rB.y;
    float y6 = s6 * di + rB.z;
    float y7 = s7 * di + rB.w;

    float mx = fmaxf(fmaxf(fmaxf(y0, y1), fmaxf(y2, y3)),
                     fmaxf(fmaxf(y4, y5), fmaxf(y6, y7)));
#pragma unroll
    for (int o = 1; o < 8; o <<= 1) mx = fmaxf(mx, __shfl_xor(mx, o));
    float s = __expf(y0 - mx) + __expf(y1 - mx) + __expf(y2 - mx) + __expf(y3 - mx)
            + __expf(y4 - mx) + __expf(y5 - mx) + __expf(y6 - mx) + __expf(y7 - mx);
#pragma unroll
    for (int o = 1; o < 8; o <<= 1) s += __shfl_xor(s, o);
    float lse = mx + __logf(s);

    float4 oA, oB;
    oA.x = y0 - lse; oA.y = y1 - lse; oA.z = y2 - lse; oA.w = y3 - lse;
    oB.x = y4 - lse; oB.y = y5 - lse; oB.z = y6 - lse; oB.w = y7 - lse;
    float4* O4 = reinterpret_cast<float4*>(out + (size_t)v * 64 + t * 8);
    O4[0] = oA;
    O4[1] = oB;
}

// ---------------- launch ----------------

extern "C" void kernel_launch(void* const* d_in, const int* in_sizes, int n_in,
                              void* d_out, int out_size, void* d_ws, size_t ws_size,
                              hipStream_t stream) {
    const float* x   = (const float*)d_in[0];
    const int*   ei  = (const int*)d_in[1];
    const float* Wl0 = (const float*)d_in[2];
    const float* bl0 = (const float*)d_in[3];
    const float* Wr0 = (const float*)d_in[4];
    const float* g0  = (const float*)d_in[5];
    const float* b0  = (const float*)d_in[6];
    const float* m0  = (const float*)d_in[7];
    const float* v0  = (const float*)d_in[8];
    const float* Wl1 = (const float*)d_in[9];
    const float* bl1 = (const float*)d_in[10];
    const float* Wr1 = (const float*)d_in[11];
    const float* g1  = (const float*)d_in[12];
    const float* b1  = (const float*)d_in[13];
    const float* m1  = (const float*)d_in[14];
    const float* v1  = (const float*)d_in[15];
    const float* Wl2 = (const float*)d_in[16];
    const float* bl2 = (const float*)d_in[17];
    const float* Wr2 = (const float*)d_in[18];
    float* out = (float*)d_out;

    const int N = in_sizes[0] / 128;
    const int E = in_sizes[1] / 2;
    const int B = (N + NPB - 1) >> NPB_LOG;
    const int* src = ei;
    const int* dst = ei + E;

    char* ws = (char*)d_ws;
    size_t off = 0;
    auto alloc = [&](size_t bytes) -> void* {
        void* p = ws + off;
        off += (bytes + 255) & ~(size_t)255;
        return p;
    };
    int*   bcnt    = (int*)alloc(256 * 4);
    int*   bstart  = (int*)alloc(257 * 4);
    int*   cursorB = (int*)alloc(256 * 4);
    int*   rowptr  = (int*)alloc((size_t)(N + 1) * 4);
    float* degInv  = (float*)alloc((size_t)N * 4);
    int*   csr     = (int*)alloc((size_t)E * 4);
    unsigned* ebuf = (unsigned*)alloc((size_t)E * 4);
    unsigned short* x16 = (unsigned short*)alloc((size_t)N * 128 * 2);   // bf16 [N][128]
    unsigned short* hA  = (unsigned short*)alloc((size_t)N * 128 * 2);   // bf16 [N][128]
    unsigned short* hB  = (unsigned short*)alloc((size_t)N * 128 * 2);   // bf16 [N][128]
    unsigned char*  tL  = (unsigned char*)alloc((size_t)N * 128);       // fp8 [N][128]
    unsigned short* tR  = (unsigned short*)alloc((size_t)N * 128 * 2);  // bf16 [N][128]
    float* tR2 = (float*)alloc((size_t)N * 64 * 4);                     // f32 [N][64]
    unsigned short* Wsw0 = (unsigned short*)alloc(4 * 16 * 64 * 8 * 2);
    unsigned short* Wsw1 = (unsigned short*)alloc(4 * 16 * 64 * 8 * 2);
    unsigned short* Wsw2 = (unsigned short*)alloc(4 * 8 * 64 * 8 * 2);
    float* bnA0 = (float*)alloc(128 * 4);
    float* bnB0 = (float*)alloc(128 * 4);
    float* bnA1 = (float*)alloc(128 * 4);
    float* bnB1 = (float*)alloc(128 * 4);
    unsigned char* tL2 = tL;   // fp8 [N][64] overlays tL (lifetimes disjoint)

    hipMemsetAsync(bcnt, 0, 256 * 4, stream);

    // CSR build
    bucket_hist_kernel<<<512, 256, 0, stream>>>(dst, bcnt, E, B);
    bucket_scan_kernel<<<1, 256, 0, stream>>>(bcnt, bstart, cursorB, B, E);
    partition_kernel<<<(E + 4095) / 4096, 256, 0, stream>>>(src, dst, cursorB, ebuf, E, B);
    build_csr_kernel<<<B, 256, 0, stream>>>(ebuf, bstart, rowptr, degInv, csr, N, B);

    // prep
    int n4 = N * 32;
    cvt_bf16_kernel<<<(n4 + 255) / 256, 256, 0, stream>>>(x, x16, n4);
    swizzleWcat_kernel<<<16, 256, 0, stream>>>(Wl0, Wr0, Wsw0, 128, 128, 128);
    swizzleWcat_kernel<<<16, 256, 0, stream>>>(Wl1, Wr1, Wsw1, 128, 128, 128);
    swizzleWcat_kernel<<<8, 256, 0, stream>>>(Wl2, Wr2, Wsw2, 128, 64, 64);
    bnprep_kernel<<<1, 128, 0, stream>>>(g0, b0, m0, v0, bnA0, bnB0, 128);
    bnprep_kernel<<<1, 128, 0, stream>>>(g1, b1, m1, v1, bnA1, bnB1, 128);

    int gemmGrid = (N + 63) / 64;
    int aggGrid = (int)(((size_t)N * 16 + 255) / 256);
    int lsmGrid = (int)(((size_t)N * 8 + 255) / 256);

    // layer 0: tL = x@Wl0 (fp8), tR = x@Wr0 + bl0 (bf16); h = ReLU(BN(agg(tL) + tR))
    gemmT_kernel<128, false><<<gemmGrid, 256, 0, stream>>>(x16, Wsw0, bl0, tL, tR, N);
    aggbn_kernel<<<aggGrid, 256, 0, stream>>>(tL, tR, bnA0, bnB0, rowptr, csr, degInv, hA, N);
    // layer 1
    gemmT_kernel<128, false><<<gemmGrid, 256, 0, stream>>>(hA, Wsw1, bl1, tL, tR, N);
    aggbn_kernel<<<aggGrid, 256, 0, stream>>>(tL, tR, bnA1, bnB1, rowptr, csr, degInv, hB, N);
    // layer 2: tL2 = h@Wl2 (fp8), tR2 = h@Wr2 + bl2 (f32); out = lsm(agg(tL2) + tR2)
    gemmT_kernel<64, true><<<gemmGrid, 256, 0, stream>>>(hB, Wsw2, bl2, tL2, tR2, N);
    agg64_lsm_kernel<<<lsmGrid, 256, 0, stream>>>(tL2, tR2, rowptr, csr, degInv, out, N);
}

// Round 9
// 285.771 us; speedup vs baseline: 1.3653x; 1.0535x over previous
//
#include <hip/hip_runtime.h>

constexpr float EPS = 1e-5f;

#define NPB_LOG 9
#define NPB 512

typedef __attribute__((ext_vector_type(8))) __bf16 bf16x8;
typedef __attribute__((ext_vector_type(4))) float f32x4;
typedef __attribute__((ext_vector_type(2))) float f32x2;

// ---------- bf16 helpers ----------
__device__ __forceinline__ float blo(unsigned u) { return __uint_as_float(u << 16); }
__device__ __forceinline__ float bhi(unsigned u) { return __uint_as_float(u & 0xffff0000u); }
__device__ __forceinline__ unsigned bf1(float f) {
    unsigned u = __float_as_uint(f);
    return (u + 0x7fffu + ((u >> 16) & 1u)) >> 16;
}
__device__ __forceinline__ unsigned pack2(float a, float b) { return bf1(a) | (bf1(b) << 16); }

// ---------- fp8 helpers (HW cvt, self-consistent encode/decode) ----------
__device__ __forceinline__ f32x2 fp8lo(unsigned w) {
    return __builtin_amdgcn_cvt_pk_f32_fp8(w, false);
}
__device__ __forceinline__ f32x2 fp8hi(unsigned w) {
    return __builtin_amdgcn_cvt_pk_f32_fp8(w, true);
}

// ---------------- CSR build (locality-aware) ----------------

__global__ void bucket_hist_kernel(const int* __restrict__ dst, int* __restrict__ bcnt,
                                   int E, int B) {
    __shared__ int h[256];
    int t = threadIdx.x;
    h[t] = 0;
    __syncthreads();
    for (int e = blockIdx.x * blockDim.x + t; e < E; e += gridDim.x * blockDim.x)
        atomicAdd(&h[dst[e] >> NPB_LOG], 1);
    __syncthreads();
    if (t < B && h[t]) atomicAdd(&bcnt[t], h[t]);
}

__global__ void bucket_scan_kernel(const int* __restrict__ bcnt, int* __restrict__ bstart,
                                   int* __restrict__ cursorB, int B, int E) {
    __shared__ int tmp[256];
    int t = threadIdx.x;
    int v = (t < B) ? bcnt[t] : 0;
    tmp[t] = v;
    __syncthreads();
    for (int off = 1; off < 256; off <<= 1) {
        int x = tmp[t];
        if (t >= off) x += tmp[t - off];
        __syncthreads();
        tmp[t] = x;
        __syncthreads();
    }
    if (t < B) {
        int ex = tmp[t] - v;
        bstart[t] = ex;
        cursorB[t] = ex;
    }
    if (t == 0) bstart[B] = E;
}

__global__ __launch_bounds__(256) void partition_kernel(
    const int* __restrict__ src, const int* __restrict__ dst,
    int* __restrict__ cursorB, unsigned* __restrict__ ebuf, int E, int B) {
    __shared__ int hist[256];
    __shared__ int base[256];
    int t = threadIdx.x;
    hist[t] = 0;
    __syncthreads();
    int e0 = blockIdx.x * 4096;
    int e1 = min(e0 + 4096, E);
    for (int e = e0 + t; e < e1; e += 256)
        atomicAdd(&hist[dst[e] >> NPB_LOG], 1);
    __syncthreads();
    int h = hist[t];
    if (t < B && h) base[t] = atomicAdd(&cursorB[t], h);
    __syncthreads();
    hist[t] = 0;
    __syncthreads();
    for (int e = e0 + t; e < e1; e += 256) {
        int d = dst[e];
        int b = d >> NPB_LOG;
        int off = atomicAdd(&hist[b], 1);
        ebuf[base[b] + off] = ((unsigned)src[e] << NPB_LOG) | (unsigned)(d & (NPB - 1));
    }
}

__global__ __launch_bounds__(256) void build_csr_kernel(
    const unsigned* __restrict__ ebuf, const int* __restrict__ bstart,
    int* __restrict__ rowptr, float* __restrict__ degInv, int* __restrict__ csr,
    int N, int B) {
    __shared__ int cnt[NPB];
    __shared__ int cur[NPB];
    __shared__ int ps[256];
    int b = blockIdx.x;
    int t = threadIdx.x;
    int nbase = b << NPB_LOG;
    int nn = min(NPB, N - nbase);
    cnt[t] = 0;
    cnt[t + 256] = 0;
    __syncthreads();
    int ebeg = bstart[b], eend = bstart[b + 1];
    for (int e = ebeg + t; e < eend; e += 256)
        atomicAdd(&cnt[ebuf[e] & (NPB - 1)], 1);
    __syncthreads();
    int c0 = cnt[2 * t], c1 = cnt[2 * t + 1];
    int pair = c0 + c1;
    ps[t] = pair;
    __syncthreads();
    for (int off = 1; off < 256; off <<= 1) {
        int x = ps[t];
        if (t >= off) x += ps[t - off];
        __syncthreads();
        ps[t] = x;
        __syncthreads();
    }
    int exPair = ps[t] - pair;
    int g0 = ebeg + exPair;
    int g1 = g0 + c0;
    cur[2 * t] = g0;
    cur[2 * t + 1] = g1;
    if (2 * t < nn) {
        rowptr[nbase + 2 * t] = g0;
        degInv[nbase + 2 * t] = 1.0f / (float)max(c0, 1);
    }
    if (2 * t + 1 < nn) {
        rowptr[nbase + 2 * t + 1] = g1;
        degInv[nbase + 2 * t + 1] = 1.0f / (float)max(c1, 1);
    }
    if (b == B - 1 && t == 0) rowptr[N] = eend;
    __syncthreads();
    for (int e = ebeg + t; e < eend; e += 256) {
        unsigned p = ebuf[e];
        int pos = atomicAdd(&cur[p & (NPB - 1)], 1);
        csr[pos] = (int)(p >> NPB_LOG);
    }
}

// ---------------- f32 -> bf16 row-major conversion ----------------
__global__ void cvt_bf16_kernel(const float* __restrict__ in, unsigned short* __restrict__ out,
                                int n4) {
    int i = blockIdx.x * blockDim.x + threadIdx.x;
    if (i < n4) {
        float4 v = reinterpret_cast<const float4*>(in)[i];
        uint2 o;
        o.x = pack2(v.x, v.y);
        o.y = pack2(v.z, v.w);
        reinterpret_cast<uint2*>(out)[i] = o;
    }
}

// ---------------- weight swizzle: [Wl | Wr] horizontal concat, MFMA frag order ----------------
// out[kt][ct][lane][8]; k = kt*32 + (lane>>4)*8 + i; col = ct*16 + (lane&15).
__global__ void swizzleWcat_kernel(const float* __restrict__ Wl, const float* __restrict__ Wr,
                                   unsigned short* __restrict__ out, int K, int CL, int CR) {
    int C = CL + CR;
    int CT = C >> 4;
    int total = (K >> 5) * CT * 64;
    int id = blockIdx.x * blockDim.x + threadIdx.x;
    if (id >= total) return;
    int lane = id & 63;
    int ctkt = id >> 6;
    int ct = ctkt % CT;
    int kt = ctkt / CT;
    int col = ct * 16 + (lane & 15);
    int k0 = kt * 32 + (lane >> 4) * 8;
#pragma unroll
    for (int i = 0; i < 8; ++i) {
        int k = k0 + i;
        float w = (col < CL) ? Wl[(size_t)k * CL + col] : Wr[(size_t)k * CR + (col - CL)];
        out[(size_t)id * 8 + i] = (unsigned short)bf1(w);
    }
}

// ---------------- BN fold: h = bnA*z + bnB (z = agg + tR; bl lives in tR) ----------------
__global__ void bnprep_kernel(const float* __restrict__ g, const float* __restrict__ b,
                              const float* __restrict__ m, const float* __restrict__ v,
                              float* __restrict__ bnA, float* __restrict__ bnB, int D) {
    int c = blockIdx.x * blockDim.x + threadIdx.x;
    if (c < D) {
        float A = g[c] * rsqrtf(v[c] + EPS);
        bnA[c] = A;
        bnB[c] = b[c] - m[c] * A;
    }
}

// ---------------- MFMA GEMM: [tL | tR] = A @ [Wl | Wr]; tL -> fp8, tR -> (+bl) bf16 ----------------
// OPERAND-SWAPPED: mfma(W_frag, row_frag, acc) so D has n=lane&15=node row,
// m=kq*4+i = 4 consecutive weight cols -> per-lane dword/uint2 stores (coalescable).
// Block = 64 rows x 2*CHALF cols, 4 waves 2x2; wc=0 -> tL (fp8), wc=1 -> tR (bf16).
template <int CHALF>
__global__ __launch_bounds__(256) void gemmT_kernel(
    const unsigned short* __restrict__ A, const unsigned short* __restrict__ Wsw,
    const float* __restrict__ bl,
    unsigned char* __restrict__ tL, unsigned short* __restrict__ tR, int n) {
    constexpr int CT = CHALF / 16;
    int tid = threadIdx.x;
    int lane = tid & 63;
    int wave = tid >> 6;
    int wr = wave >> 1, wc = wave & 1;
    int row0 = blockIdx.x * 64 + wr * 32;
    int rlo = lane & 15, kq = lane >> 4;

    f32x4 acc[2][CT];   // [node-row tile][weight-col tile]
#pragma unroll
    for (int nt = 0; nt < 2; ++nt)
#pragma unroll
        for (int c = 0; c < CT; ++c)
#pragma unroll
            for (int k = 0; k < 4; ++k) acc[nt][c][k] = 0.f;

    int r0 = row0 + rlo;
    int r1 = row0 + 16 + rlo;

    for (int kt = 0; kt < 4; ++kt) {
        int kb = kt * 32 + kq * 8;
        bf16x8 a0, a1;
#pragma unroll
        for (int i = 0; i < 8; ++i) { a0[i] = (__bf16)0.f; a1[i] = (__bf16)0.f; }
        if (r0 < n) a0 = *reinterpret_cast<const bf16x8*>(A + (size_t)r0 * 128 + kb);
        if (r1 < n) a1 = *reinterpret_cast<const bf16x8*>(A + (size_t)r1 * 128 + kb);
#pragma unroll
        for (int c = 0; c < CT; ++c) {
            int ct_g = wc * CT + c;
            bf16x8 w = *reinterpret_cast<const bf16x8*>(Wsw + ((size_t)(kt * 2 * CT + ct_g) * 64 + lane) * 8);
            acc[0][c] = __builtin_amdgcn_mfma_f32_16x16x32_bf16(w, a0, acc[0][c], 0, 0, 0);
            acc[1][c] = __builtin_amdgcn_mfma_f32_16x16x32_bf16(w, a1, acc[1][c], 0, 0, 0);
        }
    }

#pragma unroll
    for (int nt = 0; nt < 2; ++nt) {
        int r = row0 + nt * 16 + rlo;
        if (r >= n) continue;
#pragma unroll
        for (int c = 0; c < CT; ++c) {
            int colbase = c * 16 + kq * 4;   // within half, 4 consecutive cols
            if (wc == 0) {
                unsigned w = __builtin_amdgcn_cvt_pk_fp8_f32(acc[nt][c][0], acc[nt][c][1], 0, false);
                w = __builtin_amdgcn_cvt_pk_fp8_f32(acc[nt][c][2], acc[nt][c][3], w, true);
                *reinterpret_cast<unsigned*>(tL + (size_t)r * CHALF + colbase) = w;
            } else {
                float4 bv = *reinterpret_cast<const float4*>(bl + colbase);
                uint2 o;
                o.x = pack2(acc[nt][c][0] + bv.x, acc[nt][c][1] + bv.y);
                o.y = pack2(acc[nt][c][2] + bv.z, acc[nt][c][3] + bv.w);
                *reinterpret_cast<uint2*>(tR + (size_t)r * CHALF + colbase) = o;
            }
        }
    }
}

// ---------------- aggregate fp8 tL (128-B rows) + tR + BN + ReLU -> h bf16 ----------------
// 16 lanes/node, 8 B (8 fp8 cols) per lane, x4 unrolled independent gathers.
__global__ void aggbn_kernel(const unsigned char* __restrict__ tL,
                             const unsigned short* __restrict__ tR,
                             const float* __restrict__ bnA, const float* __restrict__ bnB,
                             const int* __restrict__ rowptr, const int* __restrict__ csr,
                             const float* __restrict__ degInv,
                             unsigned short* __restrict__ h, int n) {
    int idx = blockIdx.x * blockDim.x + threadIdx.x;
    int v = idx >> 4;
    int t = idx & 15;
    if (v >= n) return;
    int beg = rowptr[v], end = rowptr[v + 1];
    const uint2* T2 = reinterpret_cast<const uint2*>(tL);
    float s0 = 0.f, s1 = 0.f, s2 = 0.f, s3 = 0.f, s4 = 0.f, s5 = 0.f, s6 = 0.f, s7 = 0.f;
    int e = beg;
    for (; e + 4 <= end; e += 4) {
        uint2 w0 = T2[(size_t)csr[e + 0] * 16 + t];
        uint2 w1 = T2[(size_t)csr[e + 1] * 16 + t];
        uint2 w2 = T2[(size_t)csr[e + 2] * 16 + t];
        uint2 w3 = T2[(size_t)csr[e + 3] * 16 + t];
        f32x2 p;
        p = fp8lo(w0.x); s0 += p[0]; s1 += p[1];
        p = fp8hi(w0.x); s2 += p[0]; s3 += p[1];
        p = fp8lo(w0.y); s4 += p[0]; s5 += p[1];
        p = fp8hi(w0.y); s6 += p[0]; s7 += p[1];
        p = fp8lo(w1.x); s0 += p[0]; s1 += p[1];
        p = fp8hi(w1.x); s2 += p[0]; s3 += p[1];
        p = fp8lo(w1.y); s4 += p[0]; s5 += p[1];
        p = fp8hi(w1.y); s6 += p[0]; s7 += p[1];
        p = fp8lo(w2.x); s0 += p[0]; s1 += p[1];
        p = fp8hi(w2.x); s2 += p[0]; s3 += p[1];
        p = fp8lo(w2.y); s4 += p[0]; s5 += p[1];
        p = fp8hi(w2.y); s6 += p[0]; s7 += p[1];
        p = fp8lo(w3.x); s0 += p[0]; s1 += p[1];
        p = fp8hi(w3.x); s2 += p[0]; s3 += p[1];
        p = fp8lo(w3.y); s4 += p[0]; s5 += p[1];
        p = fp8hi(w3.y); s6 += p[0]; s7 += p[1];
    }
    for (; e < end; ++e) {
        uint2 w = T2[(size_t)csr[e] * 16 + t];
        f32x2 p;
        p = fp8lo(w.x); s0 += p[0]; s1 += p[1];
        p = fp8hi(w.x); s2 += p[0]; s3 += p[1];
        p = fp8lo(w.y); s4 += p[0]; s5 += p[1];
        p = fp8hi(w.y); s6 += p[0]; s7 += p[1];
    }
    float di = degInv[v];
    uint4 rw = reinterpret_cast<const uint4*>(tR)[(size_t)v * 16 + t];
    float4 A0 = reinterpret_cast<const float4*>(bnA + t * 8)[0];
    float4 A1 = reinterpret_cast<const float4*>(bnA + t * 8)[1];
    float4 B0 = reinterpret_cast<const float4*>(bnB + t * 8)[0];
    float4 B1 = reinterpret_cast<const float4*>(bnB + t * 8)[1];
    float h0 = fmaxf(A0.x * (s0 * di + blo(rw.x)) + B0.x, 0.f);
    float h1 = fmaxf(A0.y * (s1 * di + bhi(rw.x)) + B0.y, 0.f);
    float h2 = fmaxf(A0.z * (s2 * di + blo(rw.y)) + B0.z, 0.f);
    float h3 = fmaxf(A0.w * (s3 * di + bhi(rw.y)) + B0.w, 0.f);
    float h4 = fmaxf(A1.x * (s4 * di + blo(rw.z)) + B1.x, 0.f);
    float h5 = fmaxf(A1.y * (s5 * di + bhi(rw.z)) + B1.y, 0.f);
    float h6 = fmaxf(A1.z * (s6 * di + blo(rw.w)) + B1.z, 0.f);
    float h7 = fmaxf(A1.w * (s7 * di + bhi(rw.w)) + B1.w, 0.f);
    uint4 o;
    o.x = pack2(h0, h1);
    o.y = pack2(h2, h3);
    o.z = pack2(h4, h5);
    o.w = pack2(h6, h7);
    reinterpret_cast<uint4*>(h)[(size_t)v * 16 + t] = o;
}

// ---------------- final: out = log_softmax( mean-agg(tL2 fp8) + tR2 bf16 ) ----------------
// 8 lanes/node, 8 B (8 fp8 cols) per lane, x4 unrolled.
__global__ void agg64_lsm_kernel(const unsigned char* __restrict__ tL2,
                                 const unsigned short* __restrict__ tR2,
                                 const int* __restrict__ rowptr, const int* __restrict__ csr,
                                 const float* __restrict__ degInv,
                                 float* __restrict__ out, int n) {
    int idx = blockIdx.x * blockDim.x + threadIdx.x;
    int v = idx >> 3;
    int t = idx & 7;
    if (v >= n) return;
    int beg = rowptr[v], end = rowptr[v + 1];
    const uint2* T2 = reinterpret_cast<const uint2*>(tL2);
    float s0 = 0.f, s1 = 0.f, s2 = 0.f, s3 = 0.f, s4 = 0.f, s5 = 0.f, s6 = 0.f, s7 = 0.f;
    int e = beg;
    for (; e + 4 <= end; e += 4) {
        uint2 w0 = T2[(size_t)csr[e + 0] * 8 + t];
        uint2 w1 = T2[(size_t)csr[e + 1] * 8 + t];
        uint2 w2 = T2[(size_t)csr[e + 2] * 8 + t];
        uint2 w3 = T2[(size_t)csr[e + 3] * 8 + t];
        f32x2 p;
        p = fp8lo(w0.x); s0 += p[0]; s1 += p[1];
        p = fp8hi(w0.x); s2 += p[0]; s3 += p[1];
        p = fp8lo(w0.y); s4 += p[0]; s5 += p[1];
        p = fp8hi(w0.y); s6 += p[0]; s7 += p[1];
        p = fp8lo(w1.x); s0 += p[0]; s1 += p[1];
        p = fp8hi(w1.x); s2 += p[0]; s3 += p[1];
        p = fp8lo(w1.y); s4 += p[0]; s5 += p[1];
        p = fp8hi(w1.y); s6 += p[0]; s7 += p[1];
        p = fp8lo(w2.x); s0 += p[0]; s1 += p[1];
        p = fp8hi(w2.x); s2 += p[0]; s3 += p[1];
        p = fp8lo(w2.y); s4 += p[0]; s5 += p[1];
        p = fp8hi(w2.y); s6 += p[0]; s7 += p[1];
        p = fp8lo(w3.x); s0 += p[0]; s1 += p[1];
        p = fp8hi(w3.x); s2 += p[0]; s3 += p[1];
        p = fp8lo(w3.y); s4 += p[0]; s5 += p[1];
        p = fp8hi(w3.y); s6 += p[0]; s7 += p[1];
    }
    for (; e < end; ++e) {
        uint2 w = T2[(size_t)csr[e] * 8 + t];
        f32x2 p;
        p = fp8lo(w.x); s0 += p[0]; s1 += p[1];
        p = fp8hi(w.x); s2 += p[0]; s3 += p[1];
        p = fp8lo(w.y); s4 += p[0]; s5 += p[1];
        p = fp8hi(w.y); s6 += p[0]; s7 += p[1];
    }
    float di = degInv[v];
    uint4 rw = reinterpret_cast<const uint4*>(tR2)[(size_t)v * 8 + t];
    float y0 = s0 * di + blo(rw.x);
    float y1 = s1 * di + bhi(rw.x);
    float y2 = s2 * di + blo(rw.y);
    float y3 = s3 * di + bhi(rw.y);
    float y4 = s4 * di + blo(rw.z);
    float y5 = s5 * di + bhi(rw.z);
    float y6 = s6 * di + blo(rw.w);
    float y7 = s7 * di + bhi(rw.w);

    float mx = fmaxf(fmaxf(fmaxf(y0, y1), fmaxf(y2, y3)),
                     fmaxf(fmaxf(y4, y5), fmaxf(y6, y7)));
#pragma unroll
    for (int o = 1; o < 8; o <<= 1) mx = fmaxf(mx, __shfl_xor(mx, o));
    float s = __expf(y0 - mx) + __expf(y1 - mx) + __expf(y2 - mx) + __expf(y3 - mx)
            + __expf(y4 - mx) + __expf(y5 - mx) + __expf(y6 - mx) + __expf(y7 - mx);
#pragma unroll
    for (int o = 1; o < 8; o <<= 1) s += __shfl_xor(s, o);
    float lse = mx + __logf(s);

    float4 oA, oB;
    oA.x = y0 - lse; oA.y = y1 - lse; oA.z = y2 - lse; oA.w = y3 - lse;
    oB.x = y4 - lse; oB.y = y5 - lse; oB.z = y6 - lse; oB.w = y7 - lse;
    float4* O4 = reinterpret_cast<float4*>(out + (size_t)v * 64 + t * 8);
    O4[0] = oA;
    O4[1] = oB;
}

// ---------------- launch ----------------

extern "C" void kernel_launch(void* const* d_in, const int* in_sizes, int n_in,
                              void* d_out, int out_size, void* d_ws, size_t ws_size,
                              hipStream_t stream) {
    const float* x   = (const float*)d_in[0];
    const int*   ei  = (const int*)d_in[1];
    const float* Wl0 = (const float*)d_in[2];
    const float* bl0 = (const float*)d_in[3];
    const float* Wr0 = (const float*)d_in[4];
    const float* g0  = (const float*)d_in[5];
    const float* b0  = (const float*)d_in[6];
    const float* m0  = (const float*)d_in[7];
    const float* v0  = (const float*)d_in[8];
    const float* Wl1 = (const float*)d_in[9];
    const float* bl1 = (const float*)d_in[10];
    const float* Wr1 = (const float*)d_in[11];
    const float* g1  = (const float*)d_in[12];
    const float* b1  = (const float*)d_in[13];
    const float* m1  = (const float*)d_in[14];
    const float* v1  = (const float*)d_in[15];
    const float* Wl2 = (const float*)d_in[16];
    const float* bl2 = (const float*)d_in[17];
    const float* Wr2 = (const float*)d_in[18];
    float* out = (float*)d_out;

    const int N = in_sizes[0] / 128;
    const int E = in_sizes[1] / 2;
    const int B = (N + NPB - 1) >> NPB_LOG;
    const int* src = ei;
    const int* dst = ei + E;

    char* ws = (char*)d_ws;
    size_t off = 0;
    auto alloc = [&](size_t bytes) -> void* {
        void* p = ws + off;
        off += (bytes + 255) & ~(size_t)255;
        return p;
    };
    int*   bcnt    = (int*)alloc(256 * 4);
    int*   bstart  = (int*)alloc(257 * 4);
    int*   cursorB = (int*)alloc(256 * 4);
    int*   rowptr  = (int*)alloc((size_t)(N + 1) * 4);
    float* degInv  = (float*)alloc((size_t)N * 4);
    int*   csr     = (int*)alloc((size_t)E * 4);
    unsigned* ebuf = (unsigned*)alloc((size_t)E * 4);
    unsigned short* x16 = (unsigned short*)alloc((size_t)N * 128 * 2);   // bf16 [N][128]
    unsigned short* hA  = (unsigned short*)alloc((size_t)N * 128 * 2);   // bf16 [N][128]
    unsigned short* hB  = (unsigned short*)alloc((size_t)N * 128 * 2);   // bf16 [N][128]
    unsigned char*  tL  = (unsigned char*)alloc((size_t)N * 128);       // fp8 [N][128]
    unsigned short* tR  = (unsigned short*)alloc((size_t)N * 128 * 2);  // bf16 [N][128]
    unsigned short* Wsw0 = (unsigned short*)alloc(4 * 16 * 64 * 8 * 2);
    unsigned short* Wsw1 = (unsigned short*)alloc(4 * 16 * 64 * 8 * 2);
    unsigned short* Wsw2 = (unsigned short*)alloc(4 * 8 * 64 * 8 * 2);
    float* bnA0 = (float*)alloc(128 * 4);
    float* bnB0 = (float*)alloc(128 * 4);
    float* bnA1 = (float*)alloc(128 * 4);
    float* bnB1 = (float*)alloc(128 * 4);
    unsigned char*  tL2 = tL;   // fp8  [N][64] overlays tL (lifetimes disjoint)
    unsigned short* tR2 = tR;   // bf16 [N][64] overlays tR

    hipMemsetAsync(bcnt, 0, 256 * 4, stream);

    // CSR build
    bucket_hist_kernel<<<512, 256, 0, stream>>>(dst, bcnt, E, B);
    bucket_scan_kernel<<<1, 256, 0, stream>>>(bcnt, bstart, cursorB, B, E);
    partition_kernel<<<(E + 4095) / 4096, 256, 0, stream>>>(src, dst, cursorB, ebuf, E, B);
    build_csr_kernel<<<B, 256, 0, stream>>>(ebuf, bstart, rowptr, degInv, csr, N, B);

    // prep
    int n4 = N * 32;
    cvt_bf16_kernel<<<(n4 + 255) / 256, 256, 0, stream>>>(x, x16, n4);
    swizzleWcat_kernel<<<16, 256, 0, stream>>>(Wl0, Wr0, Wsw0, 128, 128, 128);
    swizzleWcat_kernel<<<16, 256, 0, stream>>>(Wl1, Wr1, Wsw1, 128, 128, 128);
    swizzleWcat_kernel<<<8, 256, 0, stream>>>(Wl2, Wr2, Wsw2, 128, 64, 64);
    bnprep_kernel<<<1, 128, 0, stream>>>(g0, b0, m0, v0, bnA0, bnB0, 128);
    bnprep_kernel<<<1, 128, 0, stream>>>(g1, b1, m1, v1, bnA1, bnB1, 128);

    int gemmGrid = (N + 63) / 64;
    int aggGrid = (int)(((size_t)N * 16 + 255) / 256);
    int lsmGrid = (int)(((size_t)N * 8 + 255) / 256);

    // layer 0: tL = x@Wl0 (fp8), tR = x@Wr0 + bl0 (bf16); h = ReLU(BN(agg(tL) + tR))
    gemmT_kernel<128><<<gemmGrid, 256, 0, stream>>>(x16, Wsw0, bl0, tL, tR, N);
    aggbn_kernel<<<aggGrid, 256, 0, stream>>>(tL, tR, bnA0, bnB0, rowptr, csr, degInv, hA, N);
    // layer 1
    gemmT_kernel<128><<<gemmGrid, 256, 0, stream>>>(hA, Wsw1, bl1, tL, tR, N);
    aggbn_kernel<<<aggGrid, 256, 0, stream>>>(tL, tR, bnA1, bnB1, rowptr, csr, degInv, hB, N);
    // layer 2: tL2 = h@Wl2 (fp8), tR2 = h@Wr2 + bl2 (bf16); out = lsm(agg(tL2) + tR2)
    gemmT_kernel<64><<<gemmGrid, 256, 0, stream>>>(hB, Wsw2, bl2, tL2, tR2, N);
    agg64_lsm_kernel<<<lsmGrid, 256, 0, stream>>>(tL2, tR2, rowptr, csr, degInv, out, N);
}

// Round 10
// 260.164 us; speedup vs baseline: 1.4997x; 1.0984x over previous
//
#include <hip/hip_runtime.h>

constexpr float EPS = 1e-5f;

#define NPB_LOG 9
#define NPB 512

typedef __attribute__((ext_vector_type(8))) __bf16 bf16x8;
typedef __attribute__((ext_vector_type(4))) float f32x4;
typedef __attribute__((ext_vector_type(2))) float f32x2;

// ---------- bf16 helpers ----------
__device__ __forceinline__ float blo(unsigned u) { return __uint_as_float(u << 16); }
__device__ __forceinline__ float bhi(unsigned u) { return __uint_as_float(u & 0xffff0000u); }
__device__ __forceinline__ unsigned bf1(float f) {
    unsigned u = __float_as_uint(f);
    return (u + 0x7fffu + ((u >> 16) & 1u)) >> 16;
}
__device__ __forceinline__ unsigned pack2(float a, float b) { return bf1(a) | (bf1(b) << 16); }

// ---------- fp8 helpers ----------
__device__ __forceinline__ f32x2 fp8lo(unsigned w) {
    return __builtin_amdgcn_cvt_pk_f32_fp8(w, false);
}
__device__ __forceinline__ f32x2 fp8hi(unsigned w) {
    return __builtin_amdgcn_cvt_pk_f32_fp8(w, true);
}

// ---------------- CSR build (locality-aware, uint4-vectorized edge reads) ----------------

__global__ void bucket_hist_kernel(const int* __restrict__ dst, int* __restrict__ bcnt,
                                   int E, int B) {
    __shared__ int h[256];
    int t = threadIdx.x;
    h[t] = 0;
    __syncthreads();
    int E4 = E >> 2;
    const uint4* d4 = reinterpret_cast<const uint4*>(dst);
    for (int i = blockIdx.x * blockDim.x + t; i < E4; i += gridDim.x * blockDim.x) {
        uint4 d = d4[i];
        atomicAdd(&h[d.x >> NPB_LOG], 1);
        atomicAdd(&h[d.y >> NPB_LOG], 1);
        atomicAdd(&h[d.z >> NPB_LOG], 1);
        atomicAdd(&h[d.w >> NPB_LOG], 1);
    }
    if (blockIdx.x == 0 && t < (E & 3))
        atomicAdd(&h[dst[E4 * 4 + t] >> NPB_LOG], 1);
    __syncthreads();
    if (t < B && h[t]) atomicAdd(&bcnt[t], h[t]);
}

__global__ void bucket_scan_kernel(const int* __restrict__ bcnt, int* __restrict__ bstart,
                                   int* __restrict__ cursorB, int B, int E) {
    __shared__ int tmp[256];
    int t = threadIdx.x;
    int v = (t < B) ? bcnt[t] : 0;
    tmp[t] = v;
    __syncthreads();
    for (int off = 1; off < 256; off <<= 1) {
        int x = tmp[t];
        if (t >= off) x += tmp[t - off];
        __syncthreads();
        tmp[t] = x;
        __syncthreads();
    }
    if (t < B) {
        int ex = tmp[t] - v;
        bstart[t] = ex;
        cursorB[t] = ex;
    }
    if (t == 0) bstart[B] = E;
}

// 4096 edges per block; vectorized dst/src reads; packed word = (src<<9)|(dst&511)
__global__ __launch_bounds__(256) void partition_kernel(
    const int* __restrict__ src, const int* __restrict__ dst,
    int* __restrict__ cursorB, unsigned* __restrict__ ebuf, int E, int B) {
    __shared__ int hist[256];
    __shared__ int base[256];
    int t = threadIdx.x;
    hist[t] = 0;
    __syncthreads();
    int e0 = blockIdx.x * 4096;
    int e1 = min(e0 + 4096, E);
    const uint4* d4 = reinterpret_cast<const uint4*>(dst);
    const uint4* s4 = reinterpret_cast<const uint4*>(src);
    int n4 = (e1 - e0) >> 2;       // e0 is 4096-aligned, so e0/4 exact
    int i0 = e0 >> 2;
    for (int i = t; i < n4; i += 256) {
        uint4 d = d4[i0 + i];
        atomicAdd(&hist[d.x >> NPB_LOG], 1);
        atomicAdd(&hist[d.y >> NPB_LOG], 1);
        atomicAdd(&hist[d.z >> NPB_LOG], 1);
        atomicAdd(&hist[d.w >> NPB_LOG], 1);
    }
    for (int e = e0 + n4 * 4 + t; e < e1; e += 256)
        atomicAdd(&hist[dst[e] >> NPB_LOG], 1);
    __syncthreads();
    int h = hist[t];
    if (t < B && h) base[t] = atomicAdd(&cursorB[t], h);
    __syncthreads();
    hist[t] = 0;
    __syncthreads();
    for (int i = t; i < n4; i += 256) {
        uint4 d = d4[i0 + i];
        uint4 s = s4[i0 + i];
        int b0i = d.x >> NPB_LOG, b1i = d.y >> NPB_LOG, b2i = d.z >> NPB_LOG, b3i = d.w >> NPB_LOG;
        int o0 = atomicAdd(&hist[b0i], 1);
        ebuf[base[b0i] + o0] = (s.x << NPB_LOG) | (d.x & (NPB - 1));
        int o1 = atomicAdd(&hist[b1i], 1);
        ebuf[base[b1i] + o1] = (s.y << NPB_LOG) | (d.y & (NPB - 1));
        int o2 = atomicAdd(&hist[b2i], 1);
        ebuf[base[b2i] + o2] = (s.z << NPB_LOG) | (d.z & (NPB - 1));
        int o3 = atomicAdd(&hist[b3i], 1);
        ebuf[base[b3i] + o3] = (s.w << NPB_LOG) | (d.w & (NPB - 1));
    }
    for (int e = e0 + n4 * 4 + t; e < e1; e += 256) {
        int d = dst[e];
        int b = d >> NPB_LOG;
        int off = atomicAdd(&hist[b], 1);
        ebuf[base[b] + off] = ((unsigned)src[e] << NPB_LOG) | (unsigned)(d & (NPB - 1));
    }
}

__global__ __launch_bounds__(256) void build_csr_kernel(
    const unsigned* __restrict__ ebuf, const int* __restrict__ bstart,
    int* __restrict__ rowptr, float* __restrict__ degInv, int* __restrict__ csr,
    int N, int B) {
    __shared__ int cnt[NPB];
    __shared__ int cur[NPB];
    __shared__ int ps[256];
    int b = blockIdx.x;
    int t = threadIdx.x;
    int nbase = b << NPB_LOG;
    int nn = min(NPB, N - nbase);
    cnt[t] = 0;
    cnt[t + 256] = 0;
    __syncthreads();
    int ebeg = bstart[b], eend = bstart[b + 1];
    // vectorized count (ebeg not necessarily 4-aligned: scalar head)
    int eh = min((4 - (ebeg & 3)) & 3, eend - ebeg) + ebeg;
    for (int e = ebeg + t; e < eh; e += 256)
        atomicAdd(&cnt[ebuf[e] & (NPB - 1)], 1);
    int n4 = (eend - eh) >> 2;
    const uint4* p4 = reinterpret_cast<const uint4*>(ebuf + eh);
    for (int i = t; i < n4; i += 256) {
        uint4 p = p4[i];
        atomicAdd(&cnt[p.x & (NPB - 1)], 1);
        atomicAdd(&cnt[p.y & (NPB - 1)], 1);
        atomicAdd(&cnt[p.z & (NPB - 1)], 1);
        atomicAdd(&cnt[p.w & (NPB - 1)], 1);
    }
    for (int e = eh + n4 * 4 + t; e < eend; e += 256)
        atomicAdd(&cnt[ebuf[e] & (NPB - 1)], 1);
    __syncthreads();
    int c0 = cnt[2 * t], c1 = cnt[2 * t + 1];
    int pair = c0 + c1;
    ps[t] = pair;
    __syncthreads();
    for (int off = 1; off < 256; off <<= 1) {
        int x = ps[t];
        if (t >= off) x += ps[t - off];
        __syncthreads();
        ps[t] = x;
        __syncthreads();
    }
    int exPair = ps[t] - pair;
    int g0 = ebeg + exPair;
    int g1 = g0 + c0;
    cur[2 * t] = g0;
    cur[2 * t + 1] = g1;
    if (2 * t < nn) {
        rowptr[nbase + 2 * t] = g0;
        degInv[nbase + 2 * t] = 1.0f / (float)max(c0, 1);
    }
    if (2 * t + 1 < nn) {
        rowptr[nbase + 2 * t + 1] = g1;
        degInv[nbase + 2 * t + 1] = 1.0f / (float)max(c1, 1);
    }
    if (b == B - 1 && t == 0) rowptr[N] = eend;
    __syncthreads();
    for (int e = ebeg + t; e < eh; e += 256) {
        unsigned p = ebuf[e];
        int pos = atomicAdd(&cur[p & (NPB - 1)], 1);
        csr[pos] = (int)(p >> NPB_LOG);
    }
    for (int i = t; i < n4; i += 256) {
        uint4 p = p4[i];
        int pos;
        pos = atomicAdd(&cur[p.x & (NPB - 1)], 1); csr[pos] = (int)(p.x >> NPB_LOG);
        pos = atomicAdd(&cur[p.y & (NPB - 1)], 1); csr[pos] = (int)(p.y >> NPB_LOG);
        pos = atomicAdd(&cur[p.z & (NPB - 1)], 1); csr[pos] = (int)(p.z >> NPB_LOG);
        pos = atomicAdd(&cur[p.w & (NPB - 1)], 1); csr[pos] = (int)(p.w >> NPB_LOG);
    }
    for (int e = eh + n4 * 4 + t; e < eend; e += 256) {
        unsigned p = ebuf[e];
        int pos = atomicAdd(&cur[p & (NPB - 1)], 1);
        csr[pos] = (int)(p >> NPB_LOG);
    }
}

// ---------------- fused prep: weight swizzles + BN folds, one launch ----------------
__device__ __forceinline__ void swz_one(const float* __restrict__ Wl, const float* __restrict__ Wr,
                                        unsigned short* __restrict__ out, int CL, int CR, int id) {
    int C = CL + CR;
    int CT = C >> 4;
    int lane = id & 63;
    int ctkt = id >> 6;
    int ct = ctkt % CT;
    int kt = ctkt / CT;
    int col = ct * 16 + (lane & 15);
    int k0 = kt * 32 + (lane >> 4) * 8;
#pragma unroll
    for (int i = 0; i < 8; ++i) {
        int k = k0 + i;
        float w = (col < CL) ? Wl[(size_t)k * CL + col] : Wr[(size_t)k * CR + (col - CL)];
        out[(size_t)id * 8 + i] = (unsigned short)bf1(w);
    }
}

__global__ void prep_kernel(const float* __restrict__ Wl0, const float* __restrict__ Wr0,
                            const float* __restrict__ Wl1, const float* __restrict__ Wr1,
                            const float* __restrict__ Wl2, const float* __restrict__ Wr2,
                            const float* __restrict__ g0, const float* __restrict__ b0,
                            const float* __restrict__ m0, const float* __restrict__ v0,
                            const float* __restrict__ g1, const float* __restrict__ b1,
                            const float* __restrict__ m1, const float* __restrict__ v1,
                            unsigned short* __restrict__ Wsw0, unsigned short* __restrict__ Wsw1,
                            unsigned short* __restrict__ Wsw2,
                            float* __restrict__ bnA0, float* __restrict__ bnB0,
                            float* __restrict__ bnA1, float* __restrict__ bnB1) {
    int bid = blockIdx.x;
    int t = threadIdx.x;
    if (bid < 16) {
        swz_one(Wl0, Wr0, Wsw0, 128, 128, bid * 256 + t);
    } else if (bid < 32) {
        swz_one(Wl1, Wr1, Wsw1, 128, 128, (bid - 16) * 256 + t);
    } else if (bid < 40) {
        swz_one(Wl2, Wr2, Wsw2, 64, 64, (bid - 32) * 256 + t);
    } else {
        if (t < 128) {
            float A = g0[t] * rsqrtf(v0[t] + EPS);
            bnA0[t] = A;
            bnB0[t] = b0[t] - m0[t] * A;
        } else {
            int c = t - 128;
            float A = g1[c] * rsqrtf(v1[c] + EPS);
            bnA1[c] = A;
            bnB1[c] = b1[c] - m1[c] * A;
        }
    }
}

// ---------------- MFMA GEMM (operand-swapped): [tL|tR] = A @ [Wl|Wr] ----------------
// AF32: A is f32 [n][128] (layer 0 reads x directly); else bf16 [n][128].
// wc=0 waves -> tL (fp8, dword stores), wc=1 -> tR (+bl, bf16 uint2 stores).
template <int CHALF, bool AF32>
__global__ __launch_bounds__(256) void gemmT_kernel(
    const void* __restrict__ Av, const unsigned short* __restrict__ Wsw,
    const float* __restrict__ bl,
    unsigned char* __restrict__ tL, unsigned short* __restrict__ tR, int n) {
    constexpr int CT = CHALF / 16;
    int tid = threadIdx.x;
    int lane = tid & 63;
    int wave = tid >> 6;
    int wr = wave >> 1, wc = wave & 1;
    int row0 = blockIdx.x * 64 + wr * 32;
    int rlo = lane & 15, kq = lane >> 4;

    f32x4 acc[2][CT];
#pragma unroll
    for (int nt = 0; nt < 2; ++nt)
#pragma unroll
        for (int c = 0; c < CT; ++c)
#pragma unroll
            for (int k = 0; k < 4; ++k) acc[nt][c][k] = 0.f;

    int r0 = row0 + rlo;
    int r1 = row0 + 16 + rlo;

    for (int kt = 0; kt < 4; ++kt) {
        int kb = kt * 32 + kq * 8;
        bf16x8 a0, a1;
#pragma unroll
        for (int i = 0; i < 8; ++i) { a0[i] = (__bf16)0.f; a1[i] = (__bf16)0.f; }
        if (AF32) {
            const float* Af = (const float*)Av;
            if (r0 < n) {
                float4 f0 = *reinterpret_cast<const float4*>(Af + (size_t)r0 * 128 + kb);
                float4 f1 = *reinterpret_cast<const float4*>(Af + (size_t)r0 * 128 + kb + 4);
                a0[0] = (__bf16)f0.x; a0[1] = (__bf16)f0.y; a0[2] = (__bf16)f0.z; a0[3] = (__bf16)f0.w;
                a0[4] = (__bf16)f1.x; a0[5] = (__bf16)f1.y; a0[6] = (__bf16)f1.z; a0[7] = (__bf16)f1.w;
            }
            if (r1 < n) {
                float4 f0 = *reinterpret_cast<const float4*>(Af + (size_t)r1 * 128 + kb);
                float4 f1 = *reinterpret_cast<const float4*>(Af + (size_t)r1 * 128 + kb + 4);
                a1[0] = (__bf16)f0.x; a1[1] = (__bf16)f0.y; a1[2] = (__bf16)f0.z; a1[3] = (__bf16)f0.w;
                a1[4] = (__bf16)f1.x; a1[5] = (__bf16)f1.y; a1[6] = (__bf16)f1.z; a1[7] = (__bf16)f1.w;
            }
        } else {
            const unsigned short* A = (const unsigned short*)Av;
            if (r0 < n) a0 = *reinterpret_cast<const bf16x8*>(A + (size_t)r0 * 128 + kb);
            if (r1 < n) a1 = *reinterpret_cast<const bf16x8*>(A + (size_t)r1 * 128 + kb);
        }
#pragma unroll
        for (int c = 0; c < CT; ++c) {
            int ct_g = wc * CT + c;
            bf16x8 w = *reinterpret_cast<const bf16x8*>(Wsw + ((size_t)(kt * 2 * CT + ct_g) * 64 + lane) * 8);
            acc[0][c] = __builtin_amdgcn_mfma_f32_16x16x32_bf16(w, a0, acc[0][c], 0, 0, 0);
            acc[1][c] = __builtin_amdgcn_mfma_f32_16x16x32_bf16(w, a1, acc[1][c], 0, 0, 0);
        }
    }

#pragma unroll
    for (int nt = 0; nt < 2; ++nt) {
        int r = row0 + nt * 16 + rlo;
        if (r >= n) continue;
#pragma unroll
        for (int c = 0; c < CT; ++c) {
            int colbase = c * 16 + kq * 4;
            if (wc == 0) {
                unsigned w = __builtin_amdgcn_cvt_pk_fp8_f32(acc[nt][c][0], acc[nt][c][1], 0, false);
                w = __builtin_amdgcn_cvt_pk_fp8_f32(acc[nt][c][2], acc[nt][c][3], w, true);
                *reinterpret_cast<unsigned*>(tL + (size_t)r * CHALF + colbase) = w;
            } else {
                float4 bv = *reinterpret_cast<const float4*>(bl + colbase);
                uint2 o;
                o.x = pack2(acc[nt][c][0] + bv.x, acc[nt][c][1] + bv.y);
                o.y = pack2(acc[nt][c][2] + bv.z, acc[nt][c][3] + bv.w);
                *reinterpret_cast<uint2*>(tR + (size_t)r * CHALF + colbase) = o;
            }
        }
    }
}

// ---------------- aggregate fp8 tL (128-B rows) + tR + BN + ReLU -> h bf16 ----------------
// 16 lanes/node, 8 B per lane, x8-deep independent gathers.
__global__ void aggbn_kernel(const unsigned char* __restrict__ tL,
                             const unsigned short* __restrict__ tR,
                             const float* __restrict__ bnA, const float* __restrict__ bnB,
                             const int* __restrict__ rowptr, const int* __restrict__ csr,
                             const float* __restrict__ degInv,
                             unsigned short* __restrict__ h, int n) {
    int idx = blockIdx.x * blockDim.x + threadIdx.x;
    int v = idx >> 4;
    int t = idx & 15;
    if (v >= n) return;
    int beg = rowptr[v], end = rowptr[v + 1];
    const uint2* T2 = reinterpret_cast<const uint2*>(tL);
    float s0 = 0.f, s1 = 0.f, s2 = 0.f, s3 = 0.f, s4 = 0.f, s5 = 0.f, s6 = 0.f, s7 = 0.f;
    int e = beg;
    for (; e + 8 <= end; e += 8) {
        uint2 w0 = T2[(size_t)csr[e + 0] * 16 + t];
        uint2 w1 = T2[(size_t)csr[e + 1] * 16 + t];
        uint2 w2 = T2[(size_t)csr[e + 2] * 16 + t];
        uint2 w3 = T2[(size_t)csr[e + 3] * 16 + t];
        uint2 w4 = T2[(size_t)csr[e + 4] * 16 + t];
        uint2 w5 = T2[(size_t)csr[e + 5] * 16 + t];
        uint2 w6 = T2[(size_t)csr[e + 6] * 16 + t];
        uint2 w7 = T2[(size_t)csr[e + 7] * 16 + t];
        f32x2 p;
        p = fp8lo(w0.x); s0 += p[0]; s1 += p[1];
        p = fp8hi(w0.x); s2 += p[0]; s3 += p[1];
        p = fp8lo(w0.y); s4 += p[0]; s5 += p[1];
        p = fp8hi(w0.y); s6 += p[0]; s7 += p[1];
        p = fp8lo(w1.x); s0 += p[0]; s1 += p[1];
        p = fp8hi(w1.x); s2 += p[0]; s3 += p[1];
        p = fp8lo(w1.y); s4 += p[0]; s5 += p[1];
        p = fp8hi(w1.y); s6 += p[0]; s7 += p[1];
        p = fp8lo(w2.x); s0 += p[0]; s1 += p[1];
        p = fp8hi(w2.x); s2 += p[0]; s3 += p[1];
        p = fp8lo(w2.y); s4 += p[0]; s5 += p[1];
        p = fp8hi(w2.y); s6 += p[0]; s7 += p[1];
        p = fp8lo(w3.x); s0 += p[0]; s1 += p[1];
        p = fp8hi(w3.x); s2 += p[0]; s3 += p[1];
        p = fp8lo(w3.y); s4 += p[0]; s5 += p[1];
        p = fp8hi(w3.y); s6 += p[0]; s7 += p[1];
        p = fp8lo(w4.x); s0 += p[0]; s1 += p[1];
        p = fp8hi(w4.x); s2 += p[0]; s3 += p[1];
        p = fp8lo(w4.y); s4 += p[0]; s5 += p[1];
        p = fp8hi(w4.y); s6 += p[0]; s7 += p[1];
        p = fp8lo(w5.x); s0 += p[0]; s1 += p[1];
        p = fp8hi(w5.x); s2 += p[0]; s3 += p[1];
        p = fp8lo(w5.y); s4 += p[0]; s5 += p[1];
        p = fp8hi(w5.y); s6 += p[0]; s7 += p[1];
        p = fp8lo(w6.x); s0 += p[0]; s1 += p[1];
        p = fp8hi(w6.x); s2 += p[0]; s3 += p[1];
        p = fp8lo(w6.y); s4 += p[0]; s5 += p[1];
        p = fp8hi(w6.y); s6 += p[0]; s7 += p[1];
        p = fp8lo(w7.x); s0 += p[0]; s1 += p[1];
        p = fp8hi(w7.x); s2 += p[0]; s3 += p[1];
        p = fp8lo(w7.y); s4 += p[0]; s5 += p[1];
        p = fp8hi(w7.y); s6 += p[0]; s7 += p[1];
    }
    for (; e < end; ++e) {
        uint2 w = T2[(size_t)csr[e] * 16 + t];
        f32x2 p;
        p = fp8lo(w.x); s0 += p[0]; s1 += p[1];
        p = fp8hi(w.x); s2 += p[0]; s3 += p[1];
        p = fp8lo(w.y); s4 += p[0]; s5 += p[1];
        p = fp8hi(w.y); s6 += p[0]; s7 += p[1];
    }
    float di = degInv[v];
    uint4 rw = reinterpret_cast<const uint4*>(tR)[(size_t)v * 16 + t];
    float4 A0 = reinterpret_cast<const float4*>(bnA + t * 8)[0];
    float4 A1 = reinterpret_cast<const float4*>(bnA + t * 8)[1];
    float4 B0 = reinterpret_cast<const float4*>(bnB + t * 8)[0];
    float4 B1 = reinterpret_cast<const float4*>(bnB + t * 8)[1];
    float h0 = fmaxf(A0.x * (s0 * di + blo(rw.x)) + B0.x, 0.f);
    float h1 = fmaxf(A0.y * (s1 * di + bhi(rw.x)) + B0.y, 0.f);
    float h2 = fmaxf(A0.z * (s2 * di + blo(rw.y)) + B0.z, 0.f);
    float h3 = fmaxf(A0.w * (s3 * di + bhi(rw.y)) + B0.w, 0.f);
    float h4 = fmaxf(A1.x * (s4 * di + blo(rw.z)) + B1.x, 0.f);
    float h5 = fmaxf(A1.y * (s5 * di + bhi(rw.z)) + B1.y, 0.f);
    float h6 = fmaxf(A1.z * (s6 * di + blo(rw.w)) + B1.z, 0.f);
    float h7 = fmaxf(A1.w * (s7 * di + bhi(rw.w)) + B1.w, 0.f);
    uint4 o;
    o.x = pack2(h0, h1);
    o.y = pack2(h2, h3);
    o.z = pack2(h4, h5);
    o.w = pack2(h6, h7);
    reinterpret_cast<uint4*>(h)[(size_t)v * 16 + t] = o;
}

// ---------------- final: out = log_softmax( mean-agg(tL2 fp8) + tR2 bf16 ) ----------------
// 8 lanes/node, 8 B per lane, x8-deep gathers.
__global__ void agg64_lsm_kernel(const unsigned char* __restrict__ tL2,
                                 const unsigned short* __restrict__ tR2,
                                 const int* __restrict__ rowptr, const int* __restrict__ csr,
                                 const float* __restrict__ degInv,
                                 float* __restrict__ out, int n) {
    int idx = blockIdx.x * blockDim.x + threadIdx.x;
    int v = idx >> 3;
    int t = idx & 7;
    if (v >= n) return;
    int beg = rowptr[v], end = rowptr[v + 1];
    const uint2* T2 = reinterpret_cast<const uint2*>(tL2);
    float s0 = 0.f, s1 = 0.f, s2 = 0.f, s3 = 0.f, s4 = 0.f, s5 = 0.f, s6 = 0.f, s7 = 0.f;
    int e = beg;
    for (; e + 8 <= end; e += 8) {
        uint2 w0 = T2[(size_t)csr[e + 0] * 8 + t];
        uint2 w1 = T2[(size_t)csr[e + 1] * 8 + t];
        uint2 w2 = T2[(size_t)csr[e + 2] * 8 + t];
        uint2 w3 = T2[(size_t)csr[e + 3] * 8 + t];
        uint2 w4 = T2[(size_t)csr[e + 4] * 8 + t];
        uint2 w5 = T2[(size_t)csr[e + 5] * 8 + t];
        uint2 w6 = T2[(size_t)csr[e + 6] * 8 + t];
        uint2 w7 = T2[(size_t)csr[e + 7] * 8 + t];
        f32x2 p;
        p = fp8lo(w0.x); s0 += p[0]; s1 += p[1];
        p = fp8hi(w0.x); s2 += p[0]; s3 += p[1];
        p = fp8lo(w0.y); s4 += p[0]; s5 += p[1];
        p = fp8hi(w0.y); s6 += p[0]; s7 += p[1];
        p = fp8lo(w1.x); s0 += p[0]; s1 += p[1];
        p = fp8hi(w1.x); s2 += p[0]; s3 += p[1];
        p = fp8lo(w1.y); s4 += p[0]; s5 += p[1];
        p = fp8hi(w1.y); s6 += p[0]; s7 += p[1];
        p = fp8lo(w2.x); s0 += p[0]; s1 += p[1];
        p = fp8hi(w2.x); s2 += p[0]; s3 += p[1];
        p = fp8lo(w2.y); s4 += p[0]; s5 += p[1];
        p = fp8hi(w2.y); s6 += p[0]; s7 += p[1];
        p = fp8lo(w3.x); s0 += p[0]; s1 += p[1];
        p = fp8hi(w3.x); s2 += p[0]; s3 += p[1];
        p = fp8lo(w3.y); s4 += p[0]; s5 += p[1];
        p = fp8hi(w3.y); s6 += p[0]; s7 += p[1];
        p = fp8lo(w4.x); s0 += p[0]; s1 += p[1];
        p = fp8hi(w4.x); s2 += p[0]; s3 += p[1];
        p = fp8lo(w4.y); s4 += p[0]; s5 += p[1];
        p = fp8hi(w4.y); s6 += p[0]; s7 += p[1];
        p = fp8lo(w5.x); s0 += p[0]; s1 += p[1];
        p = fp8hi(w5.x); s2 += p[0]; s3 += p[1];
        p = fp8lo(w5.y); s4 += p[0]; s5 += p[1];
        p = fp8hi(w5.y); s6 += p[0]; s7 += p[1];
        p = fp8lo(w6.x); s0 += p[0]; s1 += p[1];
        p = fp8hi(w6.x); s2 += p[0]; s3 += p[1];
        p = fp8lo(w6.y); s4 += p[0]; s5 += p[1];
        p = fp8hi(w6.y); s6 += p[0]; s7 += p[1];
        p = fp8lo(w7.x); s0 += p[0]; s1 += p[1];
        p = fp8hi(w7.x); s2 += p[0]; s3 += p[1];
        p = fp8lo(w7.y); s4 += p[0]; s5 += p[1];
        p = fp8hi(w7.y); s6 += p[0]; s7 += p[1];
    }
    for (; e < end; ++e) {
        uint2 w = T2[(size_t)csr[e] * 8 + t];
        f32x2 p;
        p = fp8lo(w.x); s0 += p[0]; s1 += p[1];
        p = fp8hi(w.x); s2 += p[0]; s3 += p[1];
        p = fp8lo(w.y); s4 += p[0]; s5 += p[1];
        p = fp8hi(w.y); s6 += p[0]; s7 += p[1];
    }
    float di = degInv[v];
    uint4 rw = reinterpret_cast<const uint4*>(tR2)[(size_t)v * 8 + t];
    float y0 = s0 * di + blo(rw.x);
    float y1 = s1 * di + bhi(rw.x);
    float y2 = s2 * di + blo(rw.y);
    float y3 = s3 * di + bhi(rw.y);
    float y4 = s4 * di + blo(rw.z);
    float y5 = s5 * di + bhi(rw.z);
    float y6 = s6 * di + blo(rw.w);
    float y7 = s7 * di + bhi(rw.w);

    float mx = fmaxf(fmaxf(fmaxf(y0, y1), fmaxf(y2, y3)),
                     fmaxf(fmaxf(y4, y5), fmaxf(y6, y7)));
#pragma unroll
    for (int o = 1; o < 8; o <<= 1) mx = fmaxf(mx, __shfl_xor(mx, o));
    float s = __expf(y0 - mx) + __expf(y1 - mx) + __expf(y2 - mx) + __expf(y3 - mx)
            + __expf(y4 - mx) + __expf(y5 - mx) + __expf(y6 - mx) + __expf(y7 - mx);
#pragma unroll
    for (int o = 1; o < 8; o <<= 1) s += __shfl_xor(s, o);
    float lse = mx + __logf(s);

    float4 oA, oB;
    oA.x = y0 - lse; oA.y = y1 - lse; oA.z = y2 - lse; oA.w = y3 - lse;
    oB.x = y4 - lse; oB.y = y5 - lse; oB.z = y6 - lse; oB.w = y7 - lse;
    float4* O4 = reinterpret_cast<float4*>(out + (size_t)v * 64 + t * 8);
    O4[0] = oA;
    O4[1] = oB;
}

// ---------------- launch ----------------

extern "C" void kernel_launch(void* const* d_in, const int* in_sizes, int n_in,
                              void* d_out, int out_size, void* d_ws, size_t ws_size,
                              hipStream_t stream) {
    const float* x   = (const float*)d_in[0];
    const int*   ei  = (const int*)d_in[1];
    const float* Wl0 = (const float*)d_in[2];
    const float* bl0 = (const float*)d_in[3];
    const float* Wr0 = (const float*)d_in[4];
    const float* g0  = (const float*)d_in[5];
    const float* b0  = (const float*)d_in[6];
    const float* m0  = (const float*)d_in[7];
    const float* v0  = (const float*)d_in[8];
    const float* Wl1 = (const float*)d_in[9];
    const float* bl1 = (const float*)d_in[10];
    const float* Wr1 = (const float*)d_in[11];
    const float* g1  = (const float*)d_in[12];
    const float* b1  = (const float*)d_in[13];
    const float* m1  = (const float*)d_in[14];
    const float* v1  = (const float*)d_in[15];
    const float* Wl2 = (const float*)d_in[16];
    const float* bl2 = (const float*)d_in[17];
    const float* Wr2 = (const float*)d_in[18];
    float* out = (float*)d_out;

    const int N = in_sizes[0] / 128;
    const int E = in_sizes[1] / 2;
    const int B = (N + NPB - 1) >> NPB_LOG;
    const int* src = ei;
    const int* dst = ei + E;

    char* ws = (char*)d_ws;
    size_t off = 0;
    auto alloc = [&](size_t bytes) -> void* {
        void* p = ws + off;
        off += (bytes + 255) & ~(size_t)255;
        return p;
    };
    int*   bcnt    = (int*)alloc(256 * 4);
    int*   bstart  = (int*)alloc(257 * 4);
    int*   cursorB = (int*)alloc(256 * 4);
    int*   rowptr  = (int*)alloc((size_t)(N + 1) * 4);
    float* degInv  = (float*)alloc((size_t)N * 4);
    int*   csr     = (int*)alloc((size_t)E * 4);
    unsigned* ebuf = (unsigned*)alloc((size_t)E * 4);
    unsigned short* hA  = (unsigned short*)alloc((size_t)N * 128 * 2);   // bf16 [N][128]
    unsigned short* hB  = (unsigned short*)alloc((size_t)N * 128 * 2);   // bf16 [N][128]
    unsigned char*  tL  = (unsigned char*)alloc((size_t)N * 128);       // fp8 [N][128]
    unsigned short* tR  = (unsigned short*)alloc((size_t)N * 128 * 2);  // bf16 [N][128]
    unsigned short* Wsw0 = (unsigned short*)alloc(4 * 16 * 64 * 8 * 2);
    unsigned short* Wsw1 = (unsigned short*)alloc(4 * 16 * 64 * 8 * 2);
    unsigned short* Wsw2 = (unsigned short*)alloc(4 * 8 * 64 * 8 * 2);
    float* bnA0 = (float*)alloc(128 * 4);
    float* bnB0 = (float*)alloc(128 * 4);
    float* bnA1 = (float*)alloc(128 * 4);
    float* bnB1 = (float*)alloc(128 * 4);
    unsigned char*  tL2 = tL;   // fp8  [N][64] overlays tL (lifetimes disjoint)
    unsigned short* tR2 = tR;   // bf16 [N][64] overlays tR

    hipMemsetAsync(bcnt, 0, 256 * 4, stream);

    // CSR build + prep
    bucket_hist_kernel<<<512, 256, 0, stream>>>(dst, bcnt, E, B);
    bucket_scan_kernel<<<1, 256, 0, stream>>>(bcnt, bstart, cursorB, B, E);
    partition_kernel<<<(E + 4095) / 4096, 256, 0, stream>>>(src, dst, cursorB, ebuf, E, B);
    build_csr_kernel<<<B, 256, 0, stream>>>(ebuf, bstart, rowptr, degInv, csr, N, B);
    prep_kernel<<<41, 256, 0, stream>>>(Wl0, Wr0, Wl1, Wr1, Wl2, Wr2,
                                        g0, b0, m0, v0, g1, b1, m1, v1,
                                        Wsw0, Wsw1, Wsw2, bnA0, bnB0, bnA1, bnB1);

    int gemmGrid = (N + 63) / 64;
    int aggGrid = (int)(((size_t)N * 16 + 255) / 256);
    int lsmGrid = (int)(((size_t)N * 8 + 255) / 256);

    // layer 0: tL = x@Wl0 (fp8), tR = x@Wr0 + bl0 (bf16); h = ReLU(BN(agg(tL) + tR))
    gemmT_kernel<128, true><<<gemmGrid, 256, 0, stream>>>(x, Wsw0, bl0, tL, tR, N);
    aggbn_kernel<<<aggGrid, 256, 0, stream>>>(tL, tR, bnA0, bnB0, rowptr, csr, degInv, hA, N);
    // layer 1
    gemmT_kernel<128, false><<<gemmGrid, 256, 0, stream>>>(hA, Wsw1, bl1, tL, tR, N);
    aggbn_kernel<<<aggGrid, 256, 0, stream>>>(tL, tR, bnA1, bnB1, rowptr, csr, degInv, hB, N);
    // layer 2: tL2 = h@Wl2 (fp8), tR2 = h@Wr2 + bl2 (bf16); out = lsm(agg(tL2) + tR2)
    gemmT_kernel<64, false><<<gemmGrid, 256, 0, stream>>>(hB, Wsw2, bl2, tL2, tR2, N);
    agg64_lsm_kernel<<<lsmGrid, 256, 0, stream>>>(tL2, tR2, rowptr, csr, degInv, out, N);
}

// Round 11
// 247.081 us; speedup vs baseline: 1.5791x; 1.0530x over previous
//
#include <hip/hip_runtime.h>

constexpr float EPS = 1e-5f;

#define NPB_LOG 9
#define NPB 512

typedef __attribute__((ext_vector_type(8))) __bf16 bf16x8;
typedef __attribute__((ext_vector_type(4))) float f32x4;
typedef __attribute__((ext_vector_type(2))) float f32x2;

// ---------- bf16 helpers ----------
__device__ __forceinline__ float blo(unsigned u) { return __uint_as_float(u << 16); }
__device__ __forceinline__ float bhi(unsigned u) { return __uint_as_float(u & 0xffff0000u); }
__device__ __forceinline__ unsigned bf1(float f) {
    unsigned u = __float_as_uint(f);
    return (u + 0x7fffu + ((u >> 16) & 1u)) >> 16;
}
__device__ __forceinline__ unsigned pack2(float a, float b) { return bf1(a) | (bf1(b) << 16); }

// ---------- fp8 helpers ----------
__device__ __forceinline__ f32x2 fp8lo(unsigned w) {
    return __builtin_amdgcn_cvt_pk_f32_fp8(w, false);
}
__device__ __forceinline__ f32x2 fp8hi(unsigned w) {
    return __builtin_amdgcn_cvt_pk_f32_fp8(w, true);
}

// ---------------- CSR build (locality-aware, uint4-vectorized edge reads) ----------------

__global__ void bucket_hist_kernel(const int* __restrict__ dst, int* __restrict__ bcnt,
                                   int E, int B) {
    __shared__ int h[256];
    int t = threadIdx.x;
    h[t] = 0;
    __syncthreads();
    int E4 = E >> 2;
    const uint4* d4 = reinterpret_cast<const uint4*>(dst);
    for (int i = blockIdx.x * blockDim.x + t; i < E4; i += gridDim.x * blockDim.x) {
        uint4 d = d4[i];
        atomicAdd(&h[d.x >> NPB_LOG], 1);
        atomicAdd(&h[d.y >> NPB_LOG], 1);
        atomicAdd(&h[d.z >> NPB_LOG], 1);
        atomicAdd(&h[d.w >> NPB_LOG], 1);
    }
    if (blockIdx.x == 0 && t < (E & 3))
        atomicAdd(&h[dst[E4 * 4 + t] >> NPB_LOG], 1);
    __syncthreads();
    if (t < B && h[t]) atomicAdd(&bcnt[t], h[t]);
}

__global__ void bucket_scan_kernel(const int* __restrict__ bcnt, int* __restrict__ bstart,
                                   int* __restrict__ cursorB, int B, int E) {
    __shared__ int tmp[256];
    int t = threadIdx.x;
    int v = (t < B) ? bcnt[t] : 0;
    tmp[t] = v;
    __syncthreads();
    for (int off = 1; off < 256; off <<= 1) {
        int x = tmp[t];
        if (t >= off) x += tmp[t - off];
        __syncthreads();
        tmp[t] = x;
        __syncthreads();
    }
    if (t < B) {
        int ex = tmp[t] - v;
        bstart[t] = ex;
        cursorB[t] = ex;
    }
    if (t == 0) bstart[B] = E;
}

__global__ __launch_bounds__(256) void partition_kernel(
    const int* __restrict__ src, const int* __restrict__ dst,
    int* __restrict__ cursorB, unsigned* __restrict__ ebuf, int E, int B) {
    __shared__ int hist[256];
    __shared__ int base[256];
    int t = threadIdx.x;
    hist[t] = 0;
    __syncthreads();
    int e0 = blockIdx.x * 4096;
    int e1 = min(e0 + 4096, E);
    const uint4* d4 = reinterpret_cast<const uint4*>(dst);
    const uint4* s4 = reinterpret_cast<const uint4*>(src);
    int n4 = (e1 - e0) >> 2;
    int i0 = e0 >> 2;
    for (int i = t; i < n4; i += 256) {
        uint4 d = d4[i0 + i];
        atomicAdd(&hist[d.x >> NPB_LOG], 1);
        atomicAdd(&hist[d.y >> NPB_LOG], 1);
        atomicAdd(&hist[d.z >> NPB_LOG], 1);
        atomicAdd(&hist[d.w >> NPB_LOG], 1);
    }
    for (int e = e0 + n4 * 4 + t; e < e1; e += 256)
        atomicAdd(&hist[dst[e] >> NPB_LOG], 1);
    __syncthreads();
    int h = hist[t];
    if (t < B && h) base[t] = atomicAdd(&cursorB[t], h);
    __syncthreads();
    hist[t] = 0;
    __syncthreads();
    for (int i = t; i < n4; i += 256) {
        uint4 d = d4[i0 + i];
        uint4 s = s4[i0 + i];
        int b0i = d.x >> NPB_LOG, b1i = d.y >> NPB_LOG, b2i = d.z >> NPB_LOG, b3i = d.w >> NPB_LOG;
        int o0 = atomicAdd(&hist[b0i], 1);
        ebuf[base[b0i] + o0] = (s.x << NPB_LOG) | (d.x & (NPB - 1));
        int o1 = atomicAdd(&hist[b1i], 1);
        ebuf[base[b1i] + o1] = (s.y << NPB_LOG) | (d.y & (NPB - 1));
        int o2 = atomicAdd(&hist[b2i], 1);
        ebuf[base[b2i] + o2] = (s.z << NPB_LOG) | (d.z & (NPB - 1));
        int o3 = atomicAdd(&hist[b3i], 1);
        ebuf[base[b3i] + o3] = (s.w << NPB_LOG) | (d.w & (NPB - 1));
    }
    for (int e = e0 + n4 * 4 + t; e < e1; e += 256) {
        int d = dst[e];
        int b = d >> NPB_LOG;
        int off = atomicAdd(&hist[b], 1);
        ebuf[base[b] + off] = ((unsigned)src[e] << NPB_LOG) | (unsigned)(d & (NPB - 1));
    }
}

__global__ __launch_bounds__(256) void build_csr_kernel(
    const unsigned* __restrict__ ebuf, const int* __restrict__ bstart,
    int* __restrict__ rowptr, float* __restrict__ degInv, int* __restrict__ csr,
    int N, int B) {
    __shared__ int cnt[NPB];
    __shared__ int cur[NPB];
    __shared__ int ps[256];
    int b = blockIdx.x;
    int t = threadIdx.x;
    int nbase = b << NPB_LOG;
    int nn = min(NPB, N - nbase);
    cnt[t] = 0;
    cnt[t + 256] = 0;
    __syncthreads();
    int ebeg = bstart[b], eend = bstart[b + 1];
    int eh = min((4 - (ebeg & 3)) & 3, eend - ebeg) + ebeg;
    for (int e = ebeg + t; e < eh; e += 256)
        atomicAdd(&cnt[ebuf[e] & (NPB - 1)], 1);
    int n4 = (eend - eh) >> 2;
    const uint4* p4 = reinterpret_cast<const uint4*>(ebuf + eh);
    for (int i = t; i < n4; i += 256) {
        uint4 p = p4[i];
        atomicAdd(&cnt[p.x & (NPB - 1)], 1);
        atomicAdd(&cnt[p.y & (NPB - 1)], 1);
        atomicAdd(&cnt[p.z & (NPB - 1)], 1);
        atomicAdd(&cnt[p.w & (NPB - 1)], 1);
    }
    for (int e = eh + n4 * 4 + t; e < eend; e += 256)
        atomicAdd(&cnt[ebuf[e] & (NPB - 1)], 1);
    __syncthreads();
    int c0 = cnt[2 * t], c1 = cnt[2 * t + 1];
    int pair = c0 + c1;
    ps[t] = pair;
    __syncthreads();
    for (int off = 1; off < 256; off <<= 1) {
        int x = ps[t];
        if (t >= off) x += ps[t - off];
        __syncthreads();
        ps[t] = x;
        __syncthreads();
    }
    int exPair = ps[t] - pair;
    int g0 = ebeg + exPair;
    int g1 = g0 + c0;
    cur[2 * t] = g0;
    cur[2 * t + 1] = g1;
    if (2 * t < nn) {
        rowptr[nbase + 2 * t] = g0;
        degInv[nbase + 2 * t] = 1.0f / (float)max(c0, 1);
    }
    if (2 * t + 1 < nn) {
        rowptr[nbase + 2 * t + 1] = g1;
        degInv[nbase + 2 * t + 1] = 1.0f / (float)max(c1, 1);
    }
    if (b == B - 1 && t == 0) rowptr[N] = eend;
    __syncthreads();
    for (int e = ebeg + t; e < eh; e += 256) {
        unsigned p = ebuf[e];
        int pos = atomicAdd(&cur[p & (NPB - 1)], 1);
        csr[pos] = (int)(p >> NPB_LOG);
    }
    for (int i = t; i < n4; i += 256) {
        uint4 p = p4[i];
        int pos;
        pos = atomicAdd(&cur[p.x & (NPB - 1)], 1); csr[pos] = (int)(p.x >> NPB_LOG);
        pos = atomicAdd(&cur[p.y & (NPB - 1)], 1); csr[pos] = (int)(p.y >> NPB_LOG);
        pos = atomicAdd(&cur[p.z & (NPB - 1)], 1); csr[pos] = (int)(p.z >> NPB_LOG);
        pos = atomicAdd(&cur[p.w & (NPB - 1)], 1); csr[pos] = (int)(p.w >> NPB_LOG);
    }
    for (int e = eh + n4 * 4 + t; e < eend; e += 256) {
        unsigned p = ebuf[e];
        int pos = atomicAdd(&cur[p & (NPB - 1)], 1);
        csr[pos] = (int)(p >> NPB_LOG);
    }
}

// ---------------- fused prep: weight swizzles + BN folds, one launch ----------------
__device__ __forceinline__ void swz_one(const float* __restrict__ Wl, const float* __restrict__ Wr,
                                        unsigned short* __restrict__ out, int CL, int CR, int id) {
    int C = CL + CR;
    int CT = C >> 4;
    int lane = id & 63;
    int ctkt = id >> 6;
    int ct = ctkt % CT;
    int kt = ctkt / CT;
    int col = ct * 16 + (lane & 15);
    int k0 = kt * 32 + (lane >> 4) * 8;
#pragma unroll
    for (int i = 0; i < 8; ++i) {
        int k = k0 + i;
        float w = (col < CL) ? Wl[(size_t)k * CL + col] : Wr[(size_t)k * CR + (col - CL)];
        out[(size_t)id * 8 + i] = (unsigned short)bf1(w);
    }
}

__global__ void prep_kernel(const float* __restrict__ Wl0, const float* __restrict__ Wr0,
                            const float* __restrict__ Wl1, const float* __restrict__ Wr1,
                            const float* __restrict__ Wl2, const float* __restrict__ Wr2,
                            const float* __restrict__ g0, const float* __restrict__ b0,
                            const float* __restrict__ m0, const float* __restrict__ v0,
                            const float* __restrict__ g1, const float* __restrict__ b1,
                            const float* __restrict__ m1, const float* __restrict__ v1,
                            unsigned short* __restrict__ Wsw0, unsigned short* __restrict__ Wsw1,
                            unsigned short* __restrict__ Wsw2,
                            float* __restrict__ bnA0, float* __restrict__ bnB0,
                            float* __restrict__ bnA1, float* __restrict__ bnB1) {
    int bid = blockIdx.x;
    int t = threadIdx.x;
    if (bid < 16) {
        swz_one(Wl0, Wr0, Wsw0, 128, 128, bid * 256 + t);
    } else if (bid < 32) {
        swz_one(Wl1, Wr1, Wsw1, 128, 128, (bid - 16) * 256 + t);
    } else if (bid < 40) {
        swz_one(Wl2, Wr2, Wsw2, 64, 64, (bid - 32) * 256 + t);
    } else {
        if (t < 128) {
            float A = g0[t] * rsqrtf(v0[t] + EPS);
            bnA0[t] = A;
            bnB0[t] = b0[t] - m0[t] * A;
        } else {
            int c = t - 128;
            float A = g1[c] * rsqrtf(v1[c] + EPS);
            bnA1[c] = A;
            bnB1[c] = b1[c] - m1[c] * A;
        }
    }
}

// ---------------- MFMA GEMM (operand-swapped, LDS-staged A): [tL|tR] = A @ [Wl|Wr] ----------------
// A-tile (64 rows x 128 cols) staged once per block via coalesced 64B/thread loads;
// +8-element row pad makes ds_read_b128 fragments <=2-way bank aliased (free).
// wc=0 waves -> tL (fp8, dword stores), wc=1 -> tR (+bl, bf16 uint2 stores).
template <int CHALF, bool AF32>
__global__ __launch_bounds__(256, 4) void gemmT_kernel(
    const void* __restrict__ Av, const unsigned short* __restrict__ Wsw,
    const float* __restrict__ bl,
    unsigned char* __restrict__ tL, unsigned short* __restrict__ tR, int n) {
    constexpr int CT = CHALF / 16;
    __shared__ unsigned short As[64][136];   // 272-B row stride (16B-aligned, pad kills conflicts)

    int tid = threadIdx.x;
    int lane = tid & 63;
    int wave = tid >> 6;
    int wr = wave >> 1, wc = wave & 1;
    int blk0 = blockIdx.x * 64;
    int rlo = lane & 15, kq = lane >> 4;

    // ---- stage A tile (rows >= n zero-filled) ----
    {
        int srow = tid >> 2;          // 0..63
        int schunk = tid & 3;         // 0..3, 32 elements each
        int grow = blk0 + srow;
        uint4 w0 = make_uint4(0, 0, 0, 0), w1 = w0, w2 = w0, w3 = w0;
        if (grow < n) {
            if (AF32) {
                const float* Af = (const float*)Av;
                const float4* p = reinterpret_cast<const float4*>(Af + (size_t)grow * 128 + schunk * 32);
                float4 f0 = p[0], f1 = p[1], f2 = p[2], f3 = p[3];
                float4 f4 = p[4], f5 = p[5], f6 = p[6], f7 = p[7];
                w0 = make_uint4(pack2(f0.x, f0.y), pack2(f0.z, f0.w), pack2(f1.x, f1.y), pack2(f1.z, f1.w));
                w1 = make_uint4(pack2(f2.x, f2.y), pack2(f2.z, f2.w), pack2(f3.x, f3.y), pack2(f3.z, f3.w));
                w2 = make_uint4(pack2(f4.x, f4.y), pack2(f4.z, f4.w), pack2(f5.x, f5.y), pack2(f5.z, f5.w));
                w3 = make_uint4(pack2(f6.x, f6.y), pack2(f6.z, f6.w), pack2(f7.x, f7.y), pack2(f7.z, f7.w));
            } else {
                const unsigned short* A = (const unsigned short*)Av;
                const uint4* p = reinterpret_cast<const uint4*>(A + (size_t)grow * 128 + schunk * 32);
                w0 = p[0]; w1 = p[1]; w2 = p[2]; w3 = p[3];
            }
        }
        uint4* d = reinterpret_cast<uint4*>(&As[srow][schunk * 32]);
        d[0] = w0; d[1] = w1; d[2] = w2; d[3] = w3;
    }
    __syncthreads();

    f32x4 acc[2][CT];
#pragma unroll
    for (int nt = 0; nt < 2; ++nt)
#pragma unroll
        for (int c = 0; c < CT; ++c)
#pragma unroll
            for (int k = 0; k < 4; ++k) acc[nt][c][k] = 0.f;

    int lr0 = wr * 32 + rlo;
    int lr1 = wr * 32 + 16 + rlo;

    for (int kt = 0; kt < 4; ++kt) {
        int kb = kt * 32 + kq * 8;
        bf16x8 a0 = *reinterpret_cast<const bf16x8*>(&As[lr0][kb]);
        bf16x8 a1 = *reinterpret_cast<const bf16x8*>(&As[lr1][kb]);
#pragma unroll
        for (int c = 0; c < CT; ++c) {
            int ct_g = wc * CT + c;
            bf16x8 w = *reinterpret_cast<const bf16x8*>(Wsw + ((size_t)(kt * 2 * CT + ct_g) * 64 + lane) * 8);
            acc[0][c] = __builtin_amdgcn_mfma_f32_16x16x32_bf16(w, a0, acc[0][c], 0, 0, 0);
            acc[1][c] = __builtin_amdgcn_mfma_f32_16x16x32_bf16(w, a1, acc[1][c], 0, 0, 0);
        }
    }

#pragma unroll
    for (int nt = 0; nt < 2; ++nt) {
        int r = blk0 + wr * 32 + nt * 16 + rlo;
        if (r >= n) continue;
#pragma unroll
        for (int c = 0; c < CT; ++c) {
            int colbase = c * 16 + kq * 4;
            if (wc == 0) {
                unsigned w = __builtin_amdgcn_cvt_pk_fp8_f32(acc[nt][c][0], acc[nt][c][1], 0, false);
                w = __builtin_amdgcn_cvt_pk_fp8_f32(acc[nt][c][2], acc[nt][c][3], w, true);
                *reinterpret_cast<unsigned*>(tL + (size_t)r * CHALF + colbase) = w;
            } else {
                float4 bv = *reinterpret_cast<const float4*>(bl + colbase);
                uint2 o;
                o.x = pack2(acc[nt][c][0] + bv.x, acc[nt][c][1] + bv.y);
                o.y = pack2(acc[nt][c][2] + bv.z, acc[nt][c][3] + bv.w);
                *reinterpret_cast<uint2*>(tR + (size_t)r * CHALF + colbase) = o;
            }
        }
    }
}

// ---------------- aggregate fp8 tL (128-B rows) + tR + BN + ReLU -> h bf16 ----------------
__global__ void aggbn_kernel(const unsigned char* __restrict__ tL,
                             const unsigned short* __restrict__ tR,
                             const float* __restrict__ bnA, const float* __restrict__ bnB,
                             const int* __restrict__ rowptr, const int* __restrict__ csr,
                             const float* __restrict__ degInv,
                             unsigned short* __restrict__ h, int n) {
    int idx = blockIdx.x * blockDim.x + threadIdx.x;
    int v = idx >> 4;
    int t = idx & 15;
    if (v >= n) return;
    int beg = rowptr[v], end = rowptr[v + 1];
    const uint2* T2 = reinterpret_cast<const uint2*>(tL);
    float s0 = 0.f, s1 = 0.f, s2 = 0.f, s3 = 0.f, s4 = 0.f, s5 = 0.f, s6 = 0.f, s7 = 0.f;
    int e = beg;
    for (; e + 8 <= end; e += 8) {
        uint2 w0 = T2[(size_t)csr[e + 0] * 16 + t];
        uint2 w1 = T2[(size_t)csr[e + 1] * 16 + t];
        uint2 w2 = T2[(size_t)csr[e + 2] * 16 + t];
        uint2 w3 = T2[(size_t)csr[e + 3] * 16 + t];
        uint2 w4 = T2[(size_t)csr[e + 4] * 16 + t];
        uint2 w5 = T2[(size_t)csr[e + 5] * 16 + t];
        uint2 w6 = T2[(size_t)csr[e + 6] * 16 + t];
        uint2 w7 = T2[(size_t)csr[e + 7] * 16 + t];
        f32x2 p;
        p = fp8lo(w0.x); s0 += p[0]; s1 += p[1];
        p = fp8hi(w0.x); s2 += p[0]; s3 += p[1];
        p = fp8lo(w0.y); s4 += p[0]; s5 += p[1];
        p = fp8hi(w0.y); s6 += p[0]; s7 += p[1];
        p = fp8lo(w1.x); s0 += p[0]; s1 += p[1];
        p = fp8hi(w1.x); s2 += p[0]; s3 += p[1];
        p = fp8lo(w1.y); s4 += p[0]; s5 += p[1];
        p = fp8hi(w1.y); s6 += p[0]; s7 += p[1];
        p = fp8lo(w2.x); s0 += p[0]; s1 += p[1];
        p = fp8hi(w2.x); s2 += p[0]; s3 += p[1];
        p = fp8lo(w2.y); s4 += p[0]; s5 += p[1];
        p = fp8hi(w2.y); s6 += p[0]; s7 += p[1];
        p = fp8lo(w3.x); s0 += p[0]; s1 += p[1];
        p = fp8hi(w3.x); s2 += p[0]; s3 += p[1];
        p = fp8lo(w3.y); s4 += p[0]; s5 += p[1];
        p = fp8hi(w3.y); s6 += p[0]; s7 += p[1];
        p = fp8lo(w4.x); s0 += p[0]; s1 += p[1];
        p = fp8hi(w4.x); s2 += p[0]; s3 += p[1];
        p = fp8lo(w4.y); s4 += p[0]; s5 += p[1];
        p = fp8hi(w4.y); s6 += p[0]; s7 += p[1];
        p = fp8lo(w5.x); s0 += p[0]; s1 += p[1];
        p = fp8hi(w5.x); s2 += p[0]; s3 += p[1];
        p = fp8lo(w5.y); s4 += p[0]; s5 += p[1];
        p = fp8hi(w5.y); s6 += p[0]; s7 += p[1];
        p = fp8lo(w6.x); s0 += p[0]; s1 += p[1];
        p = fp8hi(w6.x); s2 += p[0]; s3 += p[1];
        p = fp8lo(w6.y); s4 += p[0]; s5 += p[1];
        p = fp8hi(w6.y); s6 += p[0]; s7 += p[1];
        p = fp8lo(w7.x); s0 += p[0]; s1 += p[1];
        p = fp8hi(w7.x); s2 += p[0]; s3 += p[1];
        p = fp8lo(w7.y); s4 += p[0]; s5 += p[1];
        p = fp8hi(w7.y); s6 += p[0]; s7 += p[1];
    }
    for (; e < end; ++e) {
        uint2 w = T2[(size_t)csr[e] * 16 + t];
        f32x2 p;
        p = fp8lo(w.x); s0 += p[0]; s1 += p[1];
        p = fp8hi(w.x); s2 += p[0]; s3 += p[1];
        p = fp8lo(w.y); s4 += p[0]; s5 += p[1];
        p = fp8hi(w.y); s6 += p[0]; s7 += p[1];
    }
    float di = degInv[v];
    uint4 rw = reinterpret_cast<const uint4*>(tR)[(size_t)v * 16 + t];
    float4 A0 = reinterpret_cast<const float4*>(bnA + t * 8)[0];
    float4 A1 = reinterpret_cast<const float4*>(bnA + t * 8)[1];
    float4 B0 = reinterpret_cast<const float4*>(bnB + t * 8)[0];
    float4 B1 = reinterpret_cast<const float4*>(bnB + t * 8)[1];
    float h0 = fmaxf(A0.x * (s0 * di + blo(rw.x)) + B0.x, 0.f);
    float h1 = fmaxf(A0.y * (s1 * di + bhi(rw.x)) + B0.y, 0.f);
    float h2 = fmaxf(A0.z * (s2 * di + blo(rw.y)) + B0.z, 0.f);
    float h3 = fmaxf(A0.w * (s3 * di + bhi(rw.y)) + B0.w, 0.f);
    float h4 = fmaxf(A1.x * (s4 * di + blo(rw.z)) + B1.x, 0.f);
    float h5 = fmaxf(A1.y * (s5 * di + bhi(rw.z)) + B1.y, 0.f);
    float h6 = fmaxf(A1.z * (s6 * di + blo(rw.w)) + B1.z, 0.f);
    float h7 = fmaxf(A1.w * (s7 * di + bhi(rw.w)) + B1.w, 0.f);
    uint4 o;
    o.x = pack2(h0, h1);
    o.y = pack2(h2, h3);
    o.z = pack2(h4, h5);
    o.w = pack2(h6, h7);
    reinterpret_cast<uint4*>(h)[(size_t)v * 16 + t] = o;
}

// ---------------- final: out = log_softmax( mean-agg(tL2 fp8) + tR2 bf16 ) ----------------
__global__ void agg64_lsm_kernel(const unsigned char* __restrict__ tL2,
                                 const unsigned short* __restrict__ tR2,
                                 const int* __restrict__ rowptr, const int* __restrict__ csr,
                                 const float* __restrict__ degInv,
                                 float* __restrict__ out, int n) {
    int idx = blockIdx.x * blockDim.x + threadIdx.x;
    int v = idx >> 3;
    int t = idx & 7;
    if (v >= n) return;
    int beg = rowptr[v], end = rowptr[v + 1];
    const uint2* T2 = reinterpret_cast<const uint2*>(tL2);
    float s0 = 0.f, s1 = 0.f, s2 = 0.f, s3 = 0.f, s4 = 0.f, s5 = 0.f, s6 = 0.f, s7 = 0.f;
    int e = beg;
    for (; e + 8 <= end; e += 8) {
        uint2 w0 = T2[(size_t)csr[e + 0] * 8 + t];
        uint2 w1 = T2[(size_t)csr[e + 1] * 8 + t];
        uint2 w2 = T2[(size_t)csr[e + 2] * 8 + t];
        uint2 w3 = T2[(size_t)csr[e + 3] * 8 + t];
        uint2 w4 = T2[(size_t)csr[e + 4] * 8 + t];
        uint2 w5 = T2[(size_t)csr[e + 5] * 8 + t];
        uint2 w6 = T2[(size_t)csr[e + 6] * 8 + t];
        uint2 w7 = T2[(size_t)csr[e + 7] * 8 + t];
        f32x2 p;
        p = fp8lo(w0.x); s0 += p[0]; s1 += p[1];
        p = fp8hi(w0.x); s2 += p[0]; s3 += p[1];
        p = fp8lo(w0.y); s4 += p[0]; s5 += p[1];
        p = fp8hi(w0.y); s6 += p[0]; s7 += p[1];
        p = fp8lo(w1.x); s0 += p[0]; s1 += p[1];
        p = fp8hi(w1.x); s2 += p[0]; s3 += p[1];
        p = fp8lo(w1.y); s4 += p[0]; s5 += p[1];
        p = fp8hi(w1.y); s6 += p[0]; s7 += p[1];
        p = fp8lo(w2.x); s0 += p[0]; s1 += p[1];
        p = fp8hi(w2.x); s2 += p[0]; s3 += p[1];
        p = fp8lo(w2.y); s4 += p[0]; s5 += p[1];
        p = fp8hi(w2.y); s6 += p[0]; s7 += p[1];
        p = fp8lo(w3.x); s0 += p[0]; s1 += p[1];
        p = fp8hi(w3.x); s2 += p[0]; s3 += p[1];
        p = fp8lo(w3.y); s4 += p[0]; s5 += p[1];
        p = fp8hi(w3.y); s6 += p[0]; s7 += p[1];
        p = fp8lo(w4.x); s0 += p[0]; s1 += p[1];
        p = fp8hi(w4.x); s2 += p[0]; s3 += p[1];
        p = fp8lo(w4.y); s4 += p[0]; s5 += p[1];
        p = fp8hi(w4.y); s6 += p[0]; s7 += p[1];
        p = fp8lo(w5.x); s0 += p[0]; s1 += p[1];
        p = fp8hi(w5.x); s2 += p[0]; s3 += p[1];
        p = fp8lo(w5.y); s4 += p[0]; s5 += p[1];
        p = fp8hi(w5.y); s6 += p[0]; s7 += p[1];
        p = fp8lo(w6.x); s0 += p[0]; s1 += p[1];
        p = fp8hi(w6.x); s2 += p[0]; s3 += p[1];
        p = fp8lo(w6.y); s4 += p[0]; s5 += p[1];
        p = fp8hi(w6.y); s6 += p[0]; s7 += p[1];
        p = fp8lo(w7.x); s0 += p[0]; s1 += p[1];
        p = fp8hi(w7.x); s2 += p[0]; s3 += p[1];
        p = fp8lo(w7.y); s4 += p[0]; s5 += p[1];
        p = fp8hi(w7.y); s6 += p[0]; s7 += p[1];
    }
    for (; e < end; ++e) {
        uint2 w = T2[(size_t)csr[e] * 8 + t];
        f32x2 p;
        p = fp8lo(w.x); s0 += p[0]; s1 += p[1];
        p = fp8hi(w.x); s2 += p[0]; s3 += p[1];
        p = fp8lo(w.y); s4 += p[0]; s5 += p[1];
        p = fp8hi(w.y); s6 += p[0]; s7 += p[1];
    }
    float di = degInv[v];
    uint4 rw = reinterpret_cast<const uint4*>(tR2)[(size_t)v * 8 + t];
    float y0 = s0 * di + blo(rw.x);
    float y1 = s1 * di + bhi(rw.x);
    float y2 = s2 * di + blo(rw.y);
    float y3 = s3 * di + bhi(rw.y);
    float y4 = s4 * di + blo(rw.z);
    float y5 = s5 * di + bhi(rw.z);
    float y6 = s6 * di + blo(rw.w);
    float y7 = s7 * di + bhi(rw.w);

    float mx = fmaxf(fmaxf(fmaxf(y0, y1), fmaxf(y2, y3)),
                     fmaxf(fmaxf(y4, y5), fmaxf(y6, y7)));
#pragma unroll
    for (int o = 1; o < 8; o <<= 1) mx = fmaxf(mx, __shfl_xor(mx, o));
    float s = __expf(y0 - mx) + __expf(y1 - mx) + __expf(y2 - mx) + __expf(y3 - mx)
            + __expf(y4 - mx) + __expf(y5 - mx) + __expf(y6 - mx) + __expf(y7 - mx);
#pragma unroll
    for (int o = 1; o < 8; o <<= 1) s += __shfl_xor(s, o);
    float lse = mx + __logf(s);

    float4 oA, oB;
    oA.x = y0 - lse; oA.y = y1 - lse; oA.z = y2 - lse; oA.w = y3 - lse;
    oB.x = y4 - lse; oB.y = y5 - lse; oB.z = y6 - lse; oB.w = y7 - lse;
    float4* O4 = reinterpret_cast<float4*>(out + (size_t)v * 64 + t * 8);
    O4[0] = oA;
    O4[1] = oB;
}

// ---------------- launch ----------------

extern "C" void kernel_launch(void* const* d_in, const int* in_sizes, int n_in,
                              void* d_out, int out_size, void* d_ws, size_t ws_size,
                              hipStream_t stream) {
    const float* x   = (const float*)d_in[0];
    const int*   ei  = (const int*)d_in[1];
    const float* Wl0 = (const float*)d_in[2];
    const float* bl0 = (const float*)d_in[3];
    const float* Wr0 = (const float*)d_in[4];
    const float* g0  = (const float*)d_in[5];
    const float* b0  = (const float*)d_in[6];
    const float* m0  = (const float*)d_in[7];
    const float* v0  = (const float*)d_in[8];
    const float* Wl1 = (const float*)d_in[9];
    const float* bl1 = (const float*)d_in[10];
    const float* Wr1 = (const float*)d_in[11];
    const float* g1  = (const float*)d_in[12];
    const float* b1  = (const float*)d_in[13];
    const float* m1  = (const float*)d_in[14];
    const float* v1  = (const float*)d_in[15];
    const float* Wl2 = (const float*)d_in[16];
    const float* bl2 = (const float*)d_in[17];
    const float* Wr2 = (const float*)d_in[18];
    float* out = (float*)d_out;

    const int N = in_sizes[0] / 128;
    const int E = in_sizes[1] / 2;
    const int B = (N + NPB - 1) >> NPB_LOG;
    const int* src = ei;
    const int* dst = ei + E;

    char* ws = (char*)d_ws;
    size_t off = 0;
    auto alloc = [&](size_t bytes) -> void* {
        void* p = ws + off;
        off += (bytes + 255) & ~(size_t)255;
        return p;
    };
    int*   bcnt    = (int*)alloc(256 * 4);
    int*   bstart  = (int*)alloc(257 * 4);
    int*   cursorB = (int*)alloc(256 * 4);
    int*   rowptr  = (int*)alloc((size_t)(N + 1) * 4);
    float* degInv  = (float*)alloc((size_t)N * 4);
    int*   csr     = (int*)alloc((size_t)E * 4);
    unsigned* ebuf = (unsigned*)alloc((size_t)E * 4);
    unsigned short* hA  = (unsigned short*)alloc((size_t)N * 128 * 2);   // bf16 [N][128]
    unsigned short* hB  = (unsigned short*)alloc((size_t)N * 128 * 2);   // bf16 [N][128]
    unsigned char*  tL  = (unsigned char*)alloc((size_t)N * 128);       // fp8 [N][128]
    unsigned short* tR  = (unsigned short*)alloc((size_t)N * 128 * 2);  // bf16 [N][128]
    unsigned short* Wsw0 = (unsigned short*)alloc(4 * 16 * 64 * 8 * 2);
    unsigned short* Wsw1 = (unsigned short*)alloc(4 * 16 * 64 * 8 * 2);
    unsigned short* Wsw2 = (unsigned short*)alloc(4 * 8 * 64 * 8 * 2);
    float* bnA0 = (float*)alloc(128 * 4);
    float* bnB0 = (float*)alloc(128 * 4);
    float* bnA1 = (float*)alloc(128 * 4);
    float* bnB1 = (float*)alloc(128 * 4);
    unsigned char*  tL2 = tL;   // fp8  [N][64] overlays tL (lifetimes disjoint)
    unsigned short* tR2 = tR;   // bf16 [N][64] overlays tR

    hipMemsetAsync(bcnt, 0, 256 * 4, stream);

    // CSR build + prep
    bucket_hist_kernel<<<512, 256, 0, stream>>>(dst, bcnt, E, B);
    bucket_scan_kernel<<<1, 256, 0, stream>>>(bcnt, bstart, cursorB, B, E);
    partition_kernel<<<(E + 4095) / 4096, 256, 0, stream>>>(src, dst, cursorB, ebuf, E, B);
    build_csr_kernel<<<B, 256, 0, stream>>>(ebuf, bstart, rowptr, degInv, csr, N, B);
    prep_kernel<<<41, 256, 0, stream>>>(Wl0, Wr0, Wl1, Wr1, Wl2, Wr2,
                                        g0, b0, m0, v0, g1, b1, m1, v1,
                                        Wsw0, Wsw1, Wsw2, bnA0, bnB0, bnA1, bnB1);

    int gemmGrid = (N + 63) / 64;
    int aggGrid = (int)(((size_t)N * 16 + 255) / 256);
    int lsmGrid = (int)(((size_t)N * 8 + 255) / 256);

    // layer 0: tL = x@Wl0 (fp8), tR = x@Wr0 + bl0 (bf16); h = ReLU(BN(agg(tL) + tR))
    gemmT_kernel<128, true><<<gemmGrid, 256, 0, stream>>>(x, Wsw0, bl0, tL, tR, N);
    aggbn_kernel<<<aggGrid, 256, 0, stream>>>(tL, tR, bnA0, bnB0, rowptr, csr, degInv, hA, N);
    // layer 1
    gemmT_kernel<128, false><<<gemmGrid, 256, 0, stream>>>(hA, Wsw1, bl1, tL, tR, N);
    aggbn_kernel<<<aggGrid, 256, 0, stream>>>(tL, tR, bnA1, bnB1, rowptr, csr, degInv, hB, N);
    // layer 2: tL2 = h@Wl2 (fp8), tR2 = h@Wr2 + bl2 (bf16); out = lsm(agg(tL2) + tR2)
    gemmT_kernel<64, false><<<gemmGrid, 256, 0, stream>>>(hB, Wsw2, bl2, tL2, tR2, N);
    agg64_lsm_kernel<<<lsmGrid, 256, 0, stream>>>(tL2, tR2, rowptr, csr, degInv, out, N);
}